// Round 2
// baseline (3154.329 us; speedup 1.0000x reference)
//
#include <hip/hip_runtime.h>
#include <stdint.h>

typedef unsigned short u16;
typedef unsigned int   u32;

#define NS      63
#define NSEQ    1024
#define DDIM    256
#define NHEAD   4
#define DHEAD   64
#define UPDIM   384
#define PREDN   96
#define LLEN    512
#define CCH     32
#define PSIZE   16
#define PSTRIDE 8

__device__ __forceinline__ float bf2f(u32 lo16){
  union { u32 i; float f; } v; v.i = lo16 << 16; return v.f;
}
__device__ __forceinline__ float bf2f_hi(u32 u){
  union { u32 i; float f; } v; v.i = u & 0xffff0000u; return v.f;
}
__device__ __forceinline__ u16 f2bf(float f){
  union { u32 i; float f; } v; v.f = f;
  u32 u = v.i; u += 0x7fffu + ((u >> 16) & 1u);
  return (u16)(u >> 16);
}

// ---------------- patch embedding (chunk-local h) ----------------------------------
__global__ __launch_bounds__(256) void patch_embed(
    const float* __restrict__ x, const float* __restrict__ Wemb,
    const float* __restrict__ bemb, float* __restrict__ h, int t_base){
  int bid = blockIdx.x, d = threadIdx.x;
  int tg = t_base + bid;
  int n = tg / NS, s = tg - n*NS;
  int b = n >> 5, c = n & 31;
  int l0 = s * PSTRIDE;
  float acc = bemb[d];
  #pragma unroll
  for (int p = 0; p < PSIZE; ++p){
    float xv = x[((size_t)b*LLEN + l0 + p)*CCH + c];
    acc += xv * Wemb[p*DDIM + d];
  }
  h[(size_t)bid*DDIM + d] = acc;
}

// ---------------- layernorm over D=256, fp32 in -> bf16 out ------------------------
__global__ __launch_bounds__(256) void layernorm_bf16(
    const float* __restrict__ in, const float* __restrict__ w,
    const float* __restrict__ b, u16* __restrict__ out){
  int t = blockIdx.x, d = threadIdx.x;
  float v = in[(size_t)t*DDIM + d];
  float s1 = v, s2 = v*v;
  #pragma unroll
  for (int o = 1; o < 64; o <<= 1){ s1 += __shfl_xor(s1, o, 64); s2 += __shfl_xor(s2, o, 64); }
  __shared__ float ws1[4], ws2[4];
  int wid = d >> 6, lane = d & 63;
  if (lane == 0){ ws1[wid] = s1; ws2[wid] = s2; }
  __syncthreads();
  s1 = ws1[0]+ws1[1]+ws1[2]+ws1[3];
  s2 = ws2[0]+ws2[1]+ws2[2]+ws2[3];
  float mu = s1 * (1.f/DDIM);
  float var = s2 * (1.f/DDIM) - mu*mu;
  float rstd = rsqrtf(var + 1e-5f);
  out[(size_t)t*DDIM + d] = f2bf((v - mu)*rstd*w[d] + b[d]);
}

// ---------------- causal depthwise conv K=4 + SiLU, bf16 -> bf16 -------------------
__global__ __launch_bounds__(256) void conv_silu(
    const u16* __restrict__ xln, const float* __restrict__ cw,
    const float* __restrict__ cb, u16* __restrict__ xc, int t_base){
  int bid = blockIdx.x, d = threadIdx.x;
  int tg = t_base + bid;
  int n = tg / NS, s = tg - n*NS;
  float acc = cb[d];
  #pragma unroll
  for (int k = 0; k < 4; ++k){
    int ss = s + k - 3;
    if (ss >= 0) acc += bf2f(xln[(size_t)(bid + k - 3)*DDIM + d]) * cw[k*DDIM + d];
  }
  float sig = 1.f/(1.f + expf(-acc));
  xc[(size_t)bid*DDIM + d] = f2bf(acc*sig);
}

// ---------------- gate preactivation GEMM: per (token-tile, head, gate) ------------
__global__ __launch_bounds__(256) void gate_gemm(
    const u16* __restrict__ xc, const u16* __restrict__ xh,
    const float* __restrict__ Wg, const float* __restrict__ gb,
    u16* __restrict__ gates, size_t GSTRIDE){
  __shared__ float Af[64][68];   // [k][row]
  __shared__ float Wf[64][68];   // [k][col]
  int tid = threadIdx.x;
  int g = blockIdx.z, hd = blockIdx.y;
  int t0 = blockIdx.x * 64;
  const u16* A = (g < 2) ? xc : xh;
  const float* W = Wg + (size_t)(g*NHEAD + hd)*DHEAD*DHEAD;
  {
    int row = tid >> 2, seg = tid & 3;
    const u16* src = A + (size_t)(t0 + row)*DDIM + hd*DHEAD + seg*16;
    uint4 ua = *(const uint4*)src;
    uint4 ub = *(const uint4*)(src + 8);
    float f[16];
    f[0]=bf2f(ua.x&0xffffu); f[1]=bf2f_hi(ua.x); f[2]=bf2f(ua.y&0xffffu); f[3]=bf2f_hi(ua.y);
    f[4]=bf2f(ua.z&0xffffu); f[5]=bf2f_hi(ua.z); f[6]=bf2f(ua.w&0xffffu); f[7]=bf2f_hi(ua.w);
    f[8]=bf2f(ub.x&0xffffu); f[9]=bf2f_hi(ub.x); f[10]=bf2f(ub.y&0xffffu); f[11]=bf2f_hi(ub.y);
    f[12]=bf2f(ub.z&0xffffu); f[13]=bf2f_hi(ub.z); f[14]=bf2f(ub.w&0xffffu); f[15]=bf2f_hi(ub.w);
    #pragma unroll
    for (int q = 0; q < 16; ++q) Af[seg*16+q][row] = f[q];
  }
  {
    int row = tid >> 2, seg = tid & 3;
    const float* src = W + row*DHEAD + seg*16;
    #pragma unroll
    for (int q = 0; q < 4; ++q)
      *(float4*)&Wf[row][seg*16 + q*4] = *(const float4*)(src + q*4);
  }
  __syncthreads();
  int r0 = (tid >> 4)*4, c0 = (tid & 15)*4;
  float acc[4][4] = {};
  #pragma unroll
  for (int k = 0; k < 64; ++k){
    float4 av = *(float4*)&Af[k][r0];
    float4 bv = *(float4*)&Wf[k][c0];
    acc[0][0]+=av.x*bv.x; acc[0][1]+=av.x*bv.y; acc[0][2]+=av.x*bv.z; acc[0][3]+=av.x*bv.w;
    acc[1][0]+=av.y*bv.x; acc[1][1]+=av.y*bv.y; acc[1][2]+=av.y*bv.z; acc[1][3]+=av.y*bv.w;
    acc[2][0]+=av.z*bv.x; acc[2][1]+=av.z*bv.y; acc[2][2]+=av.z*bv.z; acc[2][3]+=av.z*bv.w;
    acc[3][0]+=av.w*bv.x; acc[3][1]+=av.w*bv.y; acc[3][2]+=av.w*bv.z; acc[3][3]+=av.w*bv.w;
  }
  const float* gbp = gb + g*DDIM + hd*DHEAD + c0;
  float b0 = gbp[0], b1 = gbp[1], b2 = gbp[2], b3 = gbp[3];
  #pragma unroll
  for (int i = 0; i < 4; ++i){
    u16* dst = gates + (size_t)g*GSTRIDE + (size_t)(t0 + r0 + i)*DDIM + hd*DHEAD + c0;
    dst[0] = f2bf(acc[i][0] + b0);
    dst[1] = f2bf(acc[i][1] + b1);
    dst[2] = f2bf(acc[i][2] + b2);
    dst[3] = f2bf(acc[i][3] + b3);
  }
}

// ---------------- sLSTM scan: wave = one (seq, head); no barriers in loop ----------
__global__ __launch_bounds__(256) void slstm_scan(
    const u16* __restrict__ gates, const float* __restrict__ Rg,
    u16* __restrict__ y, size_t GSTRIDE){
  __shared__ u32 RgP[2][64][64];
  int tid = threadIdx.x;
  int si = tid >> 6, e = tid & 63;
  int hd = blockIdx.y;
  int n = blockIdx.x * 4 + si;       // chunk-local sequence
  for (int idx = tid; idx < 2*64*64; idx += 256){
    int g2 = idx >> 12;
    int d  = (idx >> 6) & 63;
    int ee = idx & 63;
    float v0 = Rg[(((size_t)(2*g2  )*NHEAD + hd)*DHEAD + d)*DHEAD + ee];
    float v1 = Rg[(((size_t)(2*g2+1)*NHEAD + hd)*DHEAD + d)*DHEAD + ee];
    RgP[g2][d][ee] = (u32)f2bf(v0) | ((u32)f2bf(v1) << 16);
  }
  __syncthreads();
  float c = 0.f, nst = 0.f, m = 0.f, hreg = 0.f;
  const u16* gbase = gates + (size_t)n*NS*DDIM + hd*DHEAD + e;
  u16* ybase = y + (size_t)n*NS*DDIM + hd*DHEAD + e;
  for (int s = 0; s < NS; ++s){
    float r0=0.f, r1=0.f, r2=0.f, r3=0.f;
    #pragma unroll
    for (int d = 0; d < 64; ++d){
      float hv = __shfl(hreg, d, 64);
      u32 u01 = RgP[0][d][e];
      u32 u23 = RgP[1][d][e];
      r0 += hv * bf2f(u01 & 0xffffu);
      r1 += hv * bf2f_hi(u01);
      r2 += hv * bf2f(u23 & 0xffffu);
      r3 += hv * bf2f_hi(u23);
    }
    size_t off = (size_t)s*DDIM;
    float ip = r0 + bf2f(gbase[off]);
    float fp = r1 + bf2f(gbase[GSTRIDE + off]);
    float zp = r2 + bf2f(gbase[2*GSTRIDE + off]);
    float op = r3 + bf2f(gbase[3*GSTRIDE + off]);
    float lsf = fminf(fp, 0.f) - log1pf(expf(-fabsf(fp)));
    float lg  = m + lsf;
    float mn  = fmaxf(ip, lg);
    float iv  = expf(ip - mn);
    float fv  = expf(lg - mn);
    float cn  = fv*c + iv*tanhf(zp);
    float nn2 = fv*nst + iv;
    float hn  = cn / nn2 * (1.f/(1.f + expf(-op)));
    c = cn; nst = nn2; m = mn; hreg = hn;
    ybase[off] = f2bf(hn);
  }
}

// ---------------- per-head groupnorm (over 64) * gn_w + residual into h ------------
__global__ __launch_bounds__(256) void gn_residual(
    const u16* __restrict__ y, const float* __restrict__ gnw,
    float* __restrict__ h){
  int t = blockIdx.x, d = threadIdx.x;
  float v = bf2f(y[(size_t)t*DDIM + d]);
  float s1 = v, s2 = v*v;
  #pragma unroll
  for (int o = 1; o < 64; o <<= 1){ s1 += __shfl_xor(s1, o, 64); s2 += __shfl_xor(s2, o, 64); }
  float mu = s1 * (1.f/64.f);
  float var = s2 * (1.f/64.f) - mu*mu;
  float outv = (v - mu)*rsqrtf(var + 1e-5f)*gnw[d];
  h[(size_t)t*DDIM + d] += outv;
}

// ---------------- generic 64x64-tile GEMM: bf16 A @ fp32 W + bias ------------------
template<int MODE>  // 0: store bf16.  1: accumulate into fp32 out (residual)
__global__ __launch_bounds__(256) void gemm64(
    const u16* __restrict__ A, const float* __restrict__ W,
    const float* __restrict__ bias, void* __restrict__ outv,
    int Kdim, int Ncol){
  __shared__ float Af[16][68];
  __shared__ float Wf[16][68];
  int tid = threadIdx.x;
  int m0 = blockIdx.x*64, n0 = blockIdx.y*64;
  int r0 = (tid >> 4)*4, c0 = (tid & 15)*4;
  int arow = tid >> 2, aseg = tid & 3;
  int wrow = tid >> 4, wseg = tid & 15;
  float acc[4][4] = {};
  for (int k0 = 0; k0 < Kdim; k0 += 16){
    uint2 ua = *(const uint2*)(A + (size_t)(m0 + arow)*Kdim + k0 + aseg*4);
    float f0 = bf2f(ua.x & 0xffffu), f1 = bf2f_hi(ua.x);
    float f2 = bf2f(ua.y & 0xffffu), f3 = bf2f_hi(ua.y);
    float4 wv = *(const float4*)(W + (size_t)(k0 + wrow)*Ncol + n0 + wseg*4);
    __syncthreads();
    Af[aseg*4+0][arow] = f0; Af[aseg*4+1][arow] = f1;
    Af[aseg*4+2][arow] = f2; Af[aseg*4+3][arow] = f3;
    *(float4*)&Wf[wrow][wseg*4] = wv;
    __syncthreads();
    #pragma unroll
    for (int kk = 0; kk < 16; ++kk){
      float4 av = *(float4*)&Af[kk][r0];
      float4 bv = *(float4*)&Wf[kk][c0];
      acc[0][0]+=av.x*bv.x; acc[0][1]+=av.x*bv.y; acc[0][2]+=av.x*bv.z; acc[0][3]+=av.x*bv.w;
      acc[1][0]+=av.y*bv.x; acc[1][1]+=av.y*bv.y; acc[1][2]+=av.y*bv.z; acc[1][3]+=av.y*bv.w;
      acc[2][0]+=av.z*bv.x; acc[2][1]+=av.z*bv.y; acc[2][2]+=av.z*bv.z; acc[2][3]+=av.z*bv.w;
      acc[3][0]+=av.w*bv.x; acc[3][1]+=av.w*bv.y; acc[3][2]+=av.w*bv.z; acc[3][3]+=av.w*bv.w;
    }
  }
  #pragma unroll
  for (int i = 0; i < 4; ++i){
    if (MODE == 0){
      u16* dst = (u16*)outv + (size_t)(m0 + r0 + i)*Ncol + n0 + c0;
      dst[0] = f2bf(acc[i][0] + bias[n0+c0+0]);
      dst[1] = f2bf(acc[i][1] + bias[n0+c0+1]);
      dst[2] = f2bf(acc[i][2] + bias[n0+c0+2]);
      dst[3] = f2bf(acc[i][3] + bias[n0+c0+3]);
    } else {
      float* dst = (float*)outv + (size_t)(m0 + r0 + i)*Ncol + n0 + c0;
      dst[0] += acc[i][0] + bias[n0+c0+0];
      dst[1] += acc[i][1] + bias[n0+c0+1];
      dst[2] += acc[i][2] + bias[n0+c0+2];
      dst[3] += acc[i][3] + bias[n0+c0+3];
    }
  }
}

// ---------------- gelu(g1)*g2 elementwise ------------------------------------------
__global__ __launch_bounds__(256) void gelu_mul(
    const u16* __restrict__ u, u16* __restrict__ gp, int total){
  int gid = blockIdx.x*256 + threadIdx.x;
  if (gid >= total) return;
  int t = gid / UPDIM, j = gid - t*UPDIM;
  float g1 = bf2f(u[(size_t)t*(2*UPDIM) + j]);
  float g2 = bf2f(u[(size_t)t*(2*UPDIM) + UPDIM + j]);
  float x3 = g1*g1*g1;
  float tv = tanhf(0.7978845608028654f*(g1 + 0.044715f*x3));
  float ge = 0.5f*g1*(1.f + tv);
  gp[gid] = f2bf(ge*g2);
}

// ---------------- final projection, K-split into per-chunk slices ------------------
__global__ __launch_bounds__(256) void proj_split(
    const u16* __restrict__ A, const float* __restrict__ W,
    float* __restrict__ ptmp, int Nc){
  __shared__ float Af[16][68];
  __shared__ float Wf[16][100];
  int tid = threadIdx.x;
  int m0 = blockIdx.x * 64;        // chunk-local sequence row
  int kc = blockIdx.y;             // 0..27, 576 K each
  int r0 = (tid >> 4)*4, c0 = (tid & 15)*6;
  int arow = tid >> 2, aseg = tid & 3;
  int wrow = tid >> 4, wcol = (tid & 15)*6;
  float acc[4][6] = {};
  int kbeg = kc*576;
  for (int k0 = kbeg; k0 < kbeg + 576; k0 += 16){
    uint2 ua = *(const uint2*)(A + (size_t)(m0 + arow)*16128 + k0 + aseg*4);
    float f0 = bf2f(ua.x & 0xffffu), f1 = bf2f_hi(ua.x);
    float f2 = bf2f(ua.y & 0xffffu), f3 = bf2f_hi(ua.y);
    float wl[6];
    const float* wsrc = W + (size_t)(k0 + wrow)*PREDN + wcol;
    #pragma unroll
    for (int q = 0; q < 6; ++q) wl[q] = wsrc[q];
    __syncthreads();
    Af[aseg*4+0][arow] = f0; Af[aseg*4+1][arow] = f1;
    Af[aseg*4+2][arow] = f2; Af[aseg*4+3][arow] = f3;
    #pragma unroll
    for (int q = 0; q < 6; ++q) Wf[wrow][wcol+q] = wl[q];
    __syncthreads();
    #pragma unroll
    for (int kk = 0; kk < 16; ++kk){
      float4 av = *(float4*)&Af[kk][r0];
      #pragma unroll
      for (int j = 0; j < 6; ++j){
        float b = Wf[kk][c0+j];
        acc[0][j]+=av.x*b; acc[1][j]+=av.y*b; acc[2][j]+=av.z*b; acc[3][j]+=av.w*b;
      }
    }
  }
  #pragma unroll
  for (int i = 0; i < 4; ++i)
    #pragma unroll
    for (int j = 0; j < 6; ++j)
      ptmp[((size_t)kc*Nc + m0 + r0 + i)*PREDN + c0 + j] = acc[i][j];
}

__global__ __launch_bounds__(256) void proj_out(
    const float* __restrict__ ptmp, const float* __restrict__ bproj,
    float* __restrict__ out, int Nc, int n0glob){
  int gid = blockIdx.x*256 + threadIdx.x;
  if (gid >= Nc*PREDN) return;
  float acc = 0.f;
  #pragma unroll
  for (int kc = 0; kc < 28; ++kc) acc += ptmp[(size_t)kc*Nc*PREDN + gid];
  int nl = gid / PREDN, j = gid - nl*PREDN;
  int n = n0glob + nl;
  out[((size_t)(n >> 5)*PREDN + j)*CCH + (n & 31)] = acc + bproj[j];
}

extern "C" void kernel_launch(void* const* d_in, const int* in_sizes, int n_in,
                              void* d_out, int out_size, void* d_ws, size_t ws_size,
                              hipStream_t stream) {
  const float* x      = (const float*)d_in[0];
  const float* W_emb  = (const float*)d_in[1];
  const float* b_emb  = (const float*)d_in[2];
  const float* ln1_w  = (const float*)d_in[3];
  const float* ln1_b  = (const float*)d_in[4];
  const float* conv_w = (const float*)d_in[5];
  const float* conv_b = (const float*)d_in[6];
  const float* Wg     = (const float*)d_in[7];
  const float* Rg     = (const float*)d_in[8];
  const float* gb     = (const float*)d_in[9];
  const float* gn_w   = (const float*)d_in[10];
  const float* ln2_w  = (const float*)d_in[11];
  const float* ln2_b  = (const float*)d_in[12];
  const float* up_w   = (const float*)d_in[13];
  const float* up_b   = (const float*)d_in[14];
  const float* dn_w   = (const float*)d_in[15];
  const float* dn_b   = (const float*)d_in[16];
  const float* post_w = (const float*)d_in[17];
  const float* post_b = (const float*)d_in[18];
  const float* W_proj = (const float*)d_in[19];
  const float* b_proj = (const float*)d_in[20];
  float* out = (float*)d_out;

  // adaptive chunking over sequences: per-seq footprint
  //   h fp32 63*256*4 = 64512, bufA 63*256*2, bufB 63*256*2, gates 63*1024*2,
  //   ptmp 28*96*4 = 10752  -> total 268800 B/seq
  const size_t per_seq = 268800;
  int Nc = 0;
  const int cands[5] = {1024, 512, 256, 128, 64};
  for (int i = 0; i < 5; ++i)
    if ((size_t)cands[i] * per_seq <= ws_size){ Nc = cands[i]; break; }
  if (Nc == 0) return;  // < 17.2 MB scratch: cannot run

  for (int n0 = 0; n0 < NSEQ; n0 += Nc){
    const int    nc  = Nc;
    const size_t Tc  = (size_t)nc * NS;
    char* wsb = (char*)d_ws;
    float* h_c   = (float*)wsb;                       // Tc*1024 B
    u16*   bufA  = (u16*)(wsb + Tc*1024);             // Tc*512 B
    u16*   bufB  = (u16*)(wsb + Tc*1536);             // Tc*512 B
    u16*   gates = (u16*)(wsb + Tc*2048);             // Tc*2048 B (4 gates / u)
    float* ptmp  = (float*)(wsb + Tc*4096);           // nc*10752 B
    u16*   gp    = bufA;                              // spans bufA+bufB (Tc*768 B)
    const size_t GSTRIDE = Tc*DDIM;
    const int t_base = n0*NS;
    const int Tci = (int)Tc;

    patch_embed<<<Tci, 256, 0, stream>>>(x, W_emb, b_emb, h_c, t_base);

    for (int blk = 0; blk < 2; ++blk){
      layernorm_bf16<<<Tci, 256, 0, stream>>>(h_c, ln1_w + blk*DDIM, ln1_b + blk*DDIM, bufA);
      conv_silu<<<Tci, 256, 0, stream>>>(bufA, conv_w + blk*4*DDIM, conv_b + blk*DDIM, bufB, t_base);
      gate_gemm<<<dim3(Tci/64, NHEAD, 4), 256, 0, stream>>>(
          bufB, bufA, Wg + (size_t)blk*4*NHEAD*DHEAD*DHEAD, gb + blk*4*DDIM, gates, GSTRIDE);
      slstm_scan<<<dim3(nc/4, NHEAD), 256, 0, stream>>>(
          gates, Rg + (size_t)blk*4*NHEAD*DHEAD*DHEAD, bufB, GSTRIDE);
      gn_residual<<<Tci, 256, 0, stream>>>(bufB, gn_w + blk*DDIM, h_c);
      layernorm_bf16<<<Tci, 256, 0, stream>>>(h_c, ln2_w + blk*DDIM, ln2_b + blk*DDIM, bufA);
      gemm64<0><<<dim3(Tci/64, (2*UPDIM)/64), 256, 0, stream>>>(
          bufA, up_w + (size_t)blk*DDIM*2*UPDIM, up_b + blk*2*UPDIM,
          (void*)gates, DDIM, 2*UPDIM);
      gelu_mul<<<(Tci*UPDIM + 255)/256, 256, 0, stream>>>(gates, gp, Tci*UPDIM);
      gemm64<1><<<dim3(Tci/64, DDIM/64), 256, 0, stream>>>(
          gp, dn_w + (size_t)blk*UPDIM*DDIM, dn_b + blk*DDIM,
          (void*)h_c, UPDIM, DDIM);
    }

    layernorm_bf16<<<Tci, 256, 0, stream>>>(h_c, post_w, post_b, bufA);
    proj_split<<<dim3(nc/64, 28), 256, 0, stream>>>(bufA, W_proj, ptmp, nc);
    proj_out<<<(nc*PREDN + 255)/256, 256, 0, stream>>>(ptmp, b_proj, out, nc, n0);
  }
}

// Round 3
// 2525.453 us; speedup vs baseline: 1.2490x; 1.2490x over previous
//
#include <hip/hip_runtime.h>
#include <stdint.h>

typedef unsigned short u16;
typedef unsigned int   u32;
typedef __attribute__((ext_vector_type(8))) short bf16x8;
typedef __attribute__((ext_vector_type(4))) float f32x4;

#define NS      63
#define NSEQ    1024
#define DDIM    256
#define NHEAD   4
#define DHEAD   64
#define UPDIM   384
#define PREDN   96
#define LLEN    512
#define CCH     32
#define PSIZE   16
#define PSTRIDE 8
#define KC_PROJ 8          // proj K-split chunks
#define KCHUNK_PROJ 2016   // 16128 / 8

__device__ __forceinline__ float bf2f(u32 lo16){
  union { u32 i; float f; } v; v.i = lo16 << 16; return v.f;
}
__device__ __forceinline__ float bf2f_hi(u32 u){
  union { u32 i; float f; } v; v.i = u & 0xffff0000u; return v.f;
}
__device__ __forceinline__ u16 f2bf(float f){
  union { u32 i; float f; } v; v.f = f;
  u32 u = v.i; u += 0x7fffu + ((u >> 16) & 1u);
  return (u16)(u >> 16);
}

// ---------------- weight convert + transpose: dst[c][r] = bf16(src[r][c]) ----------
__global__ __launch_bounds__(256) void cvt_transpose(
    const float* __restrict__ src, u16* __restrict__ dst, int R, int C){
  int idx = blockIdx.x*256 + threadIdx.x;
  if (idx >= R*C) return;
  int r = idx / C, c = idx - r*C;
  dst[(size_t)c*R + r] = f2bf(src[idx]);
}

// gate weights: [32][64][64] -> per-matrix transpose
__global__ __launch_bounds__(256) void cvt_gate(
    const float* __restrict__ src, u16* __restrict__ dst){
  int mat = blockIdx.x, t = threadIdx.x;
  const float* s = src + (size_t)mat*4096;
  u16* d = dst + (size_t)mat*4096;
  for (int i = t; i < 4096; i += 256){
    int r = i >> 6, c = i & 63;
    d[c*64 + r] = f2bf(s[i]);
  }
}

// ---------------- patch embedding (chunk-local h) ----------------------------------
__global__ __launch_bounds__(256) void patch_embed(
    const float* __restrict__ x, const float* __restrict__ Wemb,
    const float* __restrict__ bemb, float* __restrict__ h, int t_base){
  int bid = blockIdx.x, d = threadIdx.x;
  int tg = t_base + bid;
  int n = tg / NS, s = tg - n*NS;
  int b = n >> 5, c = n & 31;
  int l0 = s * PSTRIDE;
  float acc = bemb[d];
  #pragma unroll
  for (int p = 0; p < PSIZE; ++p){
    float xv = x[((size_t)b*LLEN + l0 + p)*CCH + c];
    acc += xv * Wemb[p*DDIM + d];
  }
  h[(size_t)bid*DDIM + d] = acc;
}

// ---------------- layernorm over D=256, fp32 in -> bf16 out ------------------------
__global__ __launch_bounds__(256) void layernorm_bf16(
    const float* __restrict__ in, const float* __restrict__ w,
    const float* __restrict__ b, u16* __restrict__ out){
  int t = blockIdx.x, d = threadIdx.x;
  float v = in[(size_t)t*DDIM + d];
  float s1 = v, s2 = v*v;
  #pragma unroll
  for (int o = 1; o < 64; o <<= 1){ s1 += __shfl_xor(s1, o, 64); s2 += __shfl_xor(s2, o, 64); }
  __shared__ float ws1[4], ws2[4];
  int wid = d >> 6, lane = d & 63;
  if (lane == 0){ ws1[wid] = s1; ws2[wid] = s2; }
  __syncthreads();
  s1 = ws1[0]+ws1[1]+ws1[2]+ws1[3];
  s2 = ws2[0]+ws2[1]+ws2[2]+ws2[3];
  float mu = s1 * (1.f/DDIM);
  float var = s2 * (1.f/DDIM) - mu*mu;
  float rstd = rsqrtf(var + 1e-5f);
  out[(size_t)t*DDIM + d] = f2bf((v - mu)*rstd*w[d] + b[d]);
}

// ---------------- causal depthwise conv K=4 + SiLU, bf16 -> bf16 -------------------
__global__ __launch_bounds__(256) void conv_silu(
    const u16* __restrict__ xln, const float* __restrict__ cw,
    const float* __restrict__ cb, u16* __restrict__ xc, int t_base){
  int bid = blockIdx.x, d = threadIdx.x;
  int tg = t_base + bid;
  int n = tg / NS, s = tg - n*NS;
  float acc = cb[d];
  #pragma unroll
  for (int k = 0; k < 4; ++k){
    int ss = s + k - 3;
    if (ss >= 0) acc += bf2f(xln[(size_t)(bid + k - 3)*DDIM + d]) * cw[k*DDIM + d];
  }
  float sig = 1.f/(1.f + expf(-acc));
  xc[(size_t)bid*DDIM + d] = f2bf(acc*sig);
}

// ---------------- MFMA GEMM: A[M][K] bf16 @ Wt[N][K] bf16 -> out -------------------
// MODE 0: bf16 out = acc + bias;  MODE 1: fp32 out += acc + bias;
// MODE 2: fp32 ptmp[(kc*Mtot + row)*ldo + col] = acc (K-split slices)
template<int BM,int BN,int NWC,int MR,int NR,int MODE>
__global__ __launch_bounds__(256) void mfma_gemm(
    const u16* __restrict__ A, int lda,
    const u16* __restrict__ Wt, int ldwt,
    const float* __restrict__ bias, void* __restrict__ outp, int ldo,
    int ksteps, int kchunk, int Mtot)
{
  constexpr int AU = (BM*4)/256;
  constexpr int WCNT = BN*4;
  constexpr int WU = (WCNT + 255)/256;
  __shared__ u16 As[BM*40];
  __shared__ u16 Ws[BN*40];
  const int tid = threadIdx.x;
  const int lane = tid & 63, wid = tid >> 6;
  const int wr = wid / NWC, wc = wid % NWC;
  const int fr = lane & 15, kb = lane >> 4;
  const int m0 = blockIdx.x*BM, n0 = blockIdx.y*BN;
  const int kc = blockIdx.z;
  const int kbeg = kc*kchunk;
  const u16* Ab = A + (size_t)m0*lda + kbeg;
  const u16* Wb = Wt + (size_t)n0*ldwt + kbeg;
  f32x4 acc[MR][NR];
  #pragma unroll
  for (int m=0;m<MR;++m)
    #pragma unroll
    for (int n=0;n<NR;++n) acc[m][n] = (f32x4){0.f,0.f,0.f,0.f};

  for (int ks = 0; ks < ksteps; ++ks){
    int k0 = ks*32;
    uint4 ar[AU], wreg[WU];
    #pragma unroll
    for (int u=0; u<AU; ++u){
      int idx = u*256 + tid; int row = idx>>2, seg = idx&3;
      ar[u] = *(const uint4*)(Ab + (size_t)row*lda + k0 + seg*8);
    }
    #pragma unroll
    for (int u=0; u<WU; ++u){
      int idx = u*256 + tid;
      if ((WCNT & 255) == 0 || idx < WCNT){
        int row = idx>>2, seg = idx&3;
        wreg[u] = *(const uint4*)(Wb + (size_t)row*ldwt + k0 + seg*8);
      }
    }
    __syncthreads();
    #pragma unroll
    for (int u=0; u<AU; ++u){
      int idx = u*256 + tid; int row = idx>>2, seg = idx&3;
      *(uint4*)&As[row*40 + seg*8] = ar[u];
    }
    #pragma unroll
    for (int u=0; u<WU; ++u){
      int idx = u*256 + tid;
      if ((WCNT & 255) == 0 || idx < WCNT){
        int row = idx>>2, seg = idx&3;
        *(uint4*)&Ws[row*40 + seg*8] = wreg[u];
      }
    }
    __syncthreads();
    bf16x8 af[MR], wf[NR];
    #pragma unroll
    for (int m=0;m<MR;++m)
      af[m] = *(const bf16x8*)&As[(wr*MR*16 + m*16 + fr)*40 + kb*8];
    #pragma unroll
    for (int n=0;n<NR;++n)
      wf[n] = *(const bf16x8*)&Ws[(wc*NR*16 + n*16 + fr)*40 + kb*8];
    #pragma unroll
    for (int m=0;m<MR;++m)
      #pragma unroll
      for (int n=0;n<NR;++n)
        acc[m][n] = __builtin_amdgcn_mfma_f32_16x16x32_bf16(af[m], wf[n], acc[m][n], 0,0,0);
  }
  #pragma unroll
  for (int m=0;m<MR;++m){
    int rowb = m0 + wr*MR*16 + m*16 + kb*4;
    #pragma unroll
    for (int n=0;n<NR;++n){
      int col = n0 + wc*NR*16 + n*16 + fr;
      #pragma unroll
      for (int r=0;r<4;++r){
        int row = rowb + r;
        float v = acc[m][n][r];
        if (MODE == 0){
          ((u16*)outp)[(size_t)row*ldo + col] = f2bf(v + bias[col]);
        } else if (MODE == 1){
          ((float*)outp)[(size_t)row*ldo + col] += v + bias[col];
        } else {
          ((float*)outp)[((size_t)kc*Mtot + row)*ldo + col] = v;
        }
      }
    }
  }
}

// ---------------- gate GEMM via MFMA: per (g,head) 64x64 weight --------------------
__global__ __launch_bounds__(256) void mfma_gate(
    const u16* __restrict__ xc, const u16* __restrict__ xh,
    const u16* __restrict__ Wgt, const float* __restrict__ gb,
    u16* __restrict__ gates, size_t GSTRIDE)
{
  __shared__ u16 As[128*40];
  __shared__ u16 Ws[64*40];
  const int tid = threadIdx.x;
  const int lane = tid & 63, wid = tid >> 6;
  const int wr = wid >> 1, wc = wid & 1;      // 2x2 waves, wave tile 64x32
  const int fr = lane & 15, kb = lane >> 4;
  const int g = blockIdx.y >> 2, hd = blockIdx.y & 3;
  const int m0 = blockIdx.x*128;
  const u16* Ain = (g < 2) ? xc : xh;
  const u16* Ab = Ain + (size_t)m0*DDIM + hd*DHEAD;
  const u16* Wb = Wgt + (size_t)blockIdx.y*4096;
  f32x4 acc[4][2];
  #pragma unroll
  for (int m=0;m<4;++m){ acc[m][0]=(f32x4){0,0,0,0}; acc[m][1]=(f32x4){0,0,0,0}; }

  #pragma unroll
  for (int ks = 0; ks < 2; ++ks){
    int k0 = ks*32;
    uint4 ar[2], wreg;
    #pragma unroll
    for (int u=0; u<2; ++u){
      int idx = u*256 + tid; int row = idx>>2, seg = idx&3;
      ar[u] = *(const uint4*)(Ab + (size_t)row*DDIM + k0 + seg*8);
    }
    { int row = tid>>2, seg = tid&3;
      wreg = *(const uint4*)(Wb + (size_t)row*64 + k0 + seg*8); }
    __syncthreads();
    #pragma unroll
    for (int u=0; u<2; ++u){
      int idx = u*256 + tid; int row = idx>>2, seg = idx&3;
      *(uint4*)&As[row*40 + seg*8] = ar[u];
    }
    { int row = tid>>2, seg = tid&3;
      *(uint4*)&Ws[row*40 + seg*8] = wreg; }
    __syncthreads();
    bf16x8 af[4], wf[2];
    #pragma unroll
    for (int m=0;m<4;++m)
      af[m] = *(const bf16x8*)&As[(wr*64 + m*16 + fr)*40 + kb*8];
    #pragma unroll
    for (int n=0;n<2;++n)
      wf[n] = *(const bf16x8*)&Ws[(wc*32 + n*16 + fr)*40 + kb*8];
    #pragma unroll
    for (int m=0;m<4;++m)
      #pragma unroll
      for (int n=0;n<2;++n)
        acc[m][n] = __builtin_amdgcn_mfma_f32_16x16x32_bf16(af[m], wf[n], acc[m][n], 0,0,0);
  }
  #pragma unroll
  for (int m=0;m<4;++m){
    int rowb = m0 + wr*64 + m*16 + kb*4;
    #pragma unroll
    for (int n=0;n<2;++n){
      int col = hd*DHEAD + wc*32 + n*16 + fr;
      float bv = gb[g*DDIM + col];
      #pragma unroll
      for (int r=0;r<4;++r){
        gates[(size_t)g*GSTRIDE + (size_t)(rowb + r)*DDIM + col] = f2bf(acc[m][n][r] + bv);
      }
    }
  }
}

// ---------------- sLSTM scan: wave = one (seq, head); no barriers in loop ----------
__global__ __launch_bounds__(256) void slstm_scan(
    const u16* __restrict__ gates, const float* __restrict__ Rg,
    u16* __restrict__ y, size_t GSTRIDE){
  __shared__ u32 RgP[2][64][64];
  int tid = threadIdx.x;
  int si = tid >> 6, e = tid & 63;
  int hd = blockIdx.y;
  int n = blockIdx.x * 4 + si;
  for (int idx = tid; idx < 2*64*64; idx += 256){
    int g2 = idx >> 12;
    int d  = (idx >> 6) & 63;
    int ee = idx & 63;
    float v0 = Rg[(((size_t)(2*g2  )*NHEAD + hd)*DHEAD + d)*DHEAD + ee];
    float v1 = Rg[(((size_t)(2*g2+1)*NHEAD + hd)*DHEAD + d)*DHEAD + ee];
    RgP[g2][d][ee] = (u32)f2bf(v0) | ((u32)f2bf(v1) << 16);
  }
  __syncthreads();
  float c = 0.f, nst = 0.f, m = 0.f, hreg = 0.f;
  const u16* gbase = gates + (size_t)n*NS*DDIM + hd*DHEAD + e;
  u16* ybase = y + (size_t)n*NS*DDIM + hd*DHEAD + e;
  for (int s = 0; s < NS; ++s){
    float r0=0.f, r1=0.f, r2=0.f, r3=0.f;
    #pragma unroll
    for (int d = 0; d < 64; ++d){
      float hv = __shfl(hreg, d, 64);
      u32 u01 = RgP[0][d][e];
      u32 u23 = RgP[1][d][e];
      r0 += hv * bf2f(u01 & 0xffffu);
      r1 += hv * bf2f_hi(u01);
      r2 += hv * bf2f(u23 & 0xffffu);
      r3 += hv * bf2f_hi(u23);
    }
    size_t off = (size_t)s*DDIM;
    float ip = r0 + bf2f(gbase[off]);
    float fp = r1 + bf2f(gbase[GSTRIDE + off]);
    float zp = r2 + bf2f(gbase[2*GSTRIDE + off]);
    float op = r3 + bf2f(gbase[3*GSTRIDE + off]);
    float lsf = fminf(fp, 0.f) - log1pf(expf(-fabsf(fp)));
    float lg  = m + lsf;
    float mn  = fmaxf(ip, lg);
    float iv  = expf(ip - mn);
    float fv  = expf(lg - mn);
    float cn  = fv*c + iv*tanhf(zp);
    float nn2 = fv*nst + iv;
    float hn  = cn / nn2 * (1.f/(1.f + expf(-op)));
    c = cn; nst = nn2; m = mn; hreg = hn;
    ybase[off] = f2bf(hn);
  }
}

// ---------------- per-head groupnorm (over 64) * gn_w + residual into h ------------
__global__ __launch_bounds__(256) void gn_residual(
    const u16* __restrict__ y, const float* __restrict__ gnw,
    float* __restrict__ h){
  int t = blockIdx.x, d = threadIdx.x;
  float v = bf2f(y[(size_t)t*DDIM + d]);
  float s1 = v, s2 = v*v;
  #pragma unroll
  for (int o = 1; o < 64; o <<= 1){ s1 += __shfl_xor(s1, o, 64); s2 += __shfl_xor(s2, o, 64); }
  float mu = s1 * (1.f/64.f);
  float var = s2 * (1.f/64.f) - mu*mu;
  float outv = (v - mu)*rsqrtf(var + 1e-5f)*gnw[d];
  h[(size_t)t*DDIM + d] += outv;
}

// ---------------- gelu(g1)*g2 elementwise ------------------------------------------
__global__ __launch_bounds__(256) void gelu_mul(
    const u16* __restrict__ u, u16* __restrict__ gp, int total){
  int gid = blockIdx.x*256 + threadIdx.x;
  if (gid >= total) return;
  int t = gid / UPDIM, j = gid - t*UPDIM;
  float g1 = bf2f(u[(size_t)t*(2*UPDIM) + j]);
  float g2 = bf2f(u[(size_t)t*(2*UPDIM) + UPDIM + j]);
  float x3 = g1*g1*g1;
  float tv = tanhf(0.7978845608028654f*(g1 + 0.044715f*x3));
  float ge = 0.5f*g1*(1.f + tv);
  gp[gid] = f2bf(ge*g2);
}

// ---------------- proj reduce over K-split slices ----------------------------------
__global__ __launch_bounds__(256) void proj_out(
    const float* __restrict__ ptmp, const float* __restrict__ bproj,
    float* __restrict__ out, int Nc, int n0glob){
  int gid = blockIdx.x*256 + threadIdx.x;
  if (gid >= Nc*PREDN) return;
  float acc = 0.f;
  #pragma unroll
  for (int kc = 0; kc < KC_PROJ; ++kc) acc += ptmp[(size_t)kc*Nc*PREDN + gid];
  int nl = gid / PREDN, j = gid - nl*PREDN;
  int n = n0glob + nl;
  out[((size_t)(n >> 5)*PREDN + j)*CCH + (n & 31)] = acc + bproj[j];
}

extern "C" void kernel_launch(void* const* d_in, const int* in_sizes, int n_in,
                              void* d_out, int out_size, void* d_ws, size_t ws_size,
                              hipStream_t stream) {
  const float* x      = (const float*)d_in[0];
  const float* W_emb  = (const float*)d_in[1];
  const float* b_emb  = (const float*)d_in[2];
  const float* ln1_w  = (const float*)d_in[3];
  const float* ln1_b  = (const float*)d_in[4];
  const float* conv_w = (const float*)d_in[5];
  const float* conv_b = (const float*)d_in[6];
  const float* Wg     = (const float*)d_in[7];
  const float* Rg     = (const float*)d_in[8];
  const float* gb     = (const float*)d_in[9];
  const float* gn_w   = (const float*)d_in[10];
  const float* ln2_w  = (const float*)d_in[11];
  const float* ln2_b  = (const float*)d_in[12];
  const float* up_w   = (const float*)d_in[13];
  const float* up_b   = (const float*)d_in[14];
  const float* dn_w   = (const float*)d_in[15];
  const float* dn_b   = (const float*)d_in[16];
  const float* post_w = (const float*)d_in[17];
  const float* post_b = (const float*)d_in[18];
  const float* W_proj = (const float*)d_in[19];
  const float* b_proj = (const float*)d_in[20];
  float* out = (float*)d_out;

  // ---- workspace layout: bf16 weight area first, then chunk area ----
  const size_t oWu  = 0;                    // [2][768][256] bf16 : 1,572,864 B
  const size_t oWd  = 1572864;              // [2][256][384] bf16 :   786,432 B
  const size_t oWg  = 2359296;              // [2][4][4][64][64]  :   524,288 B
  const size_t oWp  = 2883584;              // [96][16128] bf16   : 3,096,576 B
  const size_t oChunk = 5980160;
  const size_t per_seq = 268800;
  int Nc = 0;
  const int cands[4] = {1024, 512, 256, 128};
  for (int i = 0; i < 4; ++i)
    if (oChunk + (size_t)cands[i]*per_seq <= ws_size){ Nc = cands[i]; break; }
  if (Nc == 0) return;

  char* wsb = (char*)d_ws;
  u16* Wu  = (u16*)(wsb + oWu);
  u16* Wd  = (u16*)(wsb + oWd);
  u16* Wgt = (u16*)(wsb + oWg);
  u16* Wtp = (u16*)(wsb + oWp);

  // weight conversion (every call; deterministic)
  for (int blk = 0; blk < 2; ++blk){
    cvt_transpose<<<(256*768+255)/256, 256, 0, stream>>>(
        up_w + (size_t)blk*256*768, Wu + (size_t)blk*768*256, 256, 768);
    cvt_transpose<<<(384*256+255)/256, 256, 0, stream>>>(
        dn_w + (size_t)blk*384*256, Wd + (size_t)blk*256*384, 384, 256);
  }
  cvt_gate<<<32, 256, 0, stream>>>(Wg, Wgt);
  cvt_transpose<<<(16128*96+255)/256, 256, 0, stream>>>(W_proj, Wtp, 16128, 96);

  for (int n0 = 0; n0 < NSEQ; n0 += Nc){
    const int    nc  = Nc;
    const size_t Tc  = (size_t)nc * NS;
    char* cb = wsb + oChunk;
    float* h_c   = (float*)cb;                        // Tc*1024 B
    u16*   bufA  = (u16*)(cb + Tc*1024);              // Tc*512 B
    u16*   bufB  = (u16*)(cb + Tc*1536);              // Tc*512 B
    u16*   gates = (u16*)(cb + Tc*2048);              // Tc*2048 B
    float* ptmp  = (float*)(cb + Tc*4096);            // nc*KC_PROJ*96*4 B
    u16*   gp    = bufA;                              // spans bufA+bufB (Tc*768 B)
    const size_t GSTRIDE = Tc*DDIM;
    const int t_base = n0*NS;
    const int Tci = (int)Tc;

    patch_embed<<<Tci, 256, 0, stream>>>(x, W_emb, b_emb, h_c, t_base);

    for (int blk = 0; blk < 2; ++blk){
      layernorm_bf16<<<Tci, 256, 0, stream>>>(h_c, ln1_w + blk*DDIM, ln1_b + blk*DDIM, bufA);
      conv_silu<<<Tci, 256, 0, stream>>>(bufA, conv_w + blk*4*DDIM, conv_b + blk*DDIM, bufB, t_base);
      mfma_gate<<<dim3(Tci/128, 16), 256, 0, stream>>>(
          bufB, bufA, Wgt + (size_t)blk*16*4096, gb + blk*4*DDIM, gates, GSTRIDE);
      slstm_scan<<<dim3(nc/4, NHEAD), 256, 0, stream>>>(
          gates, Rg + (size_t)blk*4*NHEAD*DHEAD*DHEAD, bufB, GSTRIDE);
      gn_residual<<<Tci, 256, 0, stream>>>(bufB, gn_w + blk*DDIM, h_c);
      layernorm_bf16<<<Tci, 256, 0, stream>>>(h_c, ln2_w + blk*DDIM, ln2_b + blk*DDIM, bufA);
      mfma_gemm<128,128,2,4,4,0><<<dim3(Tci/128, 6), 256, 0, stream>>>(
          bufA, DDIM, Wu + (size_t)blk*768*256, DDIM,
          up_b + blk*2*UPDIM, (void*)gates, 2*UPDIM, 8, 0, 0);
      gelu_mul<<<(Tci*UPDIM + 255)/256, 256, 0, stream>>>(gates, gp, Tci*UPDIM);
      mfma_gemm<128,128,2,4,4,1><<<dim3(Tci/128, 2), 256, 0, stream>>>(
          gp, UPDIM, Wd + (size_t)blk*256*384, UPDIM,
          dn_b + blk*DDIM, (void*)h_c, DDIM, 12, 0, 0);
    }

    layernorm_bf16<<<Tci, 256, 0, stream>>>(h_c, post_w, post_b, bufA);
    mfma_gemm<64,96,2,2,3,2><<<dim3(nc/64, 1, KC_PROJ), 256, 0, stream>>>(
        bufA, NS*DDIM, Wtp, NS*DDIM,
        b_proj, (void*)ptmp, PREDN, KCHUNK_PROJ/32, KCHUNK_PROJ, nc);
    proj_out<<<(nc*PREDN + 255)/256, 256, 0, stream>>>(ptmp, b_proj, out, nc, n0);
  }
}

// Round 4
// 2247.826 us; speedup vs baseline: 1.4033x; 1.1235x over previous
//
#include <hip/hip_runtime.h>
#include <stdint.h>

typedef unsigned short u16;
typedef unsigned int   u32;
typedef __attribute__((ext_vector_type(8))) short bf16x8;
typedef __attribute__((ext_vector_type(4))) float f32x4;

#define NS      63
#define NSEQ    1024
#define DDIM    256
#define NHEAD   4
#define DHEAD   64
#define UPDIM   384
#define PREDN   96
#define LLEN    512
#define CCH     32
#define PSIZE   16
#define PSTRIDE 8
#define KC_PROJ 8
#define KCHUNK_PROJ 2016

__device__ __forceinline__ float bf2f(u32 lo16){
  union { u32 i; float f; } v; v.i = lo16 << 16; return v.f;
}
__device__ __forceinline__ float bf2f_hi(u32 u){
  union { u32 i; float f; } v; v.i = u & 0xffff0000u; return v.f;
}
__device__ __forceinline__ u16 f2bf(float f){
  union { u32 i; float f; } v; v.f = f;
  u32 u = v.i; u += 0x7fffu + ((u >> 16) & 1u);
  return (u16)(u >> 16);
}

// ---------------- weight convert + transpose: dst[c][r] = bf16(src[r][c]) ----------
__global__ __launch_bounds__(256) void cvt_transpose(
    const float* __restrict__ src, u16* __restrict__ dst, int R, int C){
  int idx = blockIdx.x*256 + threadIdx.x;
  if (idx >= R*C) return;
  int r = idx / C, c = idx - r*C;
  dst[(size_t)c*R + r] = f2bf(src[idx]);
}

// 64x64 per-matrix transpose (used for Rg -> Rgt)
__global__ __launch_bounds__(256) void cvt_gate(
    const float* __restrict__ src, u16* __restrict__ dst){
  int mat = blockIdx.x, t = threadIdx.x;
  const float* s = src + (size_t)mat*4096;
  u16* d = dst + (size_t)mat*4096;
  for (int i = t; i < 4096; i += 256){
    int r = i >> 6, c = i & 63;
    d[c*64 + r] = f2bf(s[i]);
  }
}

// block-diagonal gate weight: dst[blk][pair][512 c][256 k]
// c = gl*256 + hd*64 + e ; gate g = pair*2+gl ; nonzero only for k in head hd
__global__ __launch_bounds__(256) void cvt_gateW(
    const float* __restrict__ Wg, u16* __restrict__ dst){
  int c = blockIdx.x, pair = blockIdx.y, blk = blockIdx.z, k = threadIdx.x;
  int gl = c >> 8, hd = (c >> 6) & 3, e = c & 63;
  int g = pair*2 + gl;
  float v = ((k >> 6) == hd) ? Wg[((((size_t)blk*4 + g)*4 + hd)*64 + (k & 63))*64 + e] : 0.f;
  dst[(((size_t)blk*2 + pair)*512 + c)*256 + k] = f2bf(v);
}

// ---------------- patch embedding (chunk-local h) ----------------------------------
__global__ __launch_bounds__(256) void patch_embed(
    const float* __restrict__ x, const float* __restrict__ Wemb,
    const float* __restrict__ bemb, float* __restrict__ h, int t_base){
  int bid = blockIdx.x, d = threadIdx.x;
  int tg = t_base + bid;
  int n = tg / NS, s = tg - n*NS;
  int b = n >> 5, c = n & 31;
  int l0 = s * PSTRIDE;
  float acc = bemb[d];
  #pragma unroll
  for (int p = 0; p < PSIZE; ++p){
    float xv = x[((size_t)b*LLEN + l0 + p)*CCH + c];
    acc += xv * Wemb[p*DDIM + d];
  }
  h[(size_t)bid*DDIM + d] = acc;
}

// ---------------- layernorm over D=256, fp32 in -> bf16 out ------------------------
__global__ __launch_bounds__(256) void layernorm_bf16(
    const float* __restrict__ in, const float* __restrict__ w,
    const float* __restrict__ b, u16* __restrict__ out){
  int t = blockIdx.x, d = threadIdx.x;
  float v = in[(size_t)t*DDIM + d];
  float s1 = v, s2 = v*v;
  #pragma unroll
  for (int o = 1; o < 64; o <<= 1){ s1 += __shfl_xor(s1, o, 64); s2 += __shfl_xor(s2, o, 64); }
  __shared__ float ws1[4], ws2[4];
  int wid = d >> 6, lane = d & 63;
  if (lane == 0){ ws1[wid] = s1; ws2[wid] = s2; }
  __syncthreads();
  s1 = ws1[0]+ws1[1]+ws1[2]+ws1[3];
  s2 = ws2[0]+ws2[1]+ws2[2]+ws2[3];
  float mu = s1 * (1.f/DDIM);
  float var = s2 * (1.f/DDIM) - mu*mu;
  float rstd = rsqrtf(var + 1e-5f);
  out[(size_t)t*DDIM + d] = f2bf((v - mu)*rstd*w[d] + b[d]);
}

// ---------------- causal depthwise conv K=4 + SiLU, bf16 -> bf16 -------------------
__global__ __launch_bounds__(256) void conv_silu(
    const u16* __restrict__ xln, const float* __restrict__ cw,
    const float* __restrict__ cb, u16* __restrict__ xc, int t_base){
  int bid = blockIdx.x, d = threadIdx.x;
  int tg = t_base + bid;
  int n = tg / NS, s = tg - n*NS;
  float acc = cb[d];
  #pragma unroll
  for (int k = 0; k < 4; ++k){
    int ss = s + k - 3;
    if (ss >= 0) acc += bf2f(xln[(size_t)(bid + k - 3)*DDIM + d]) * cw[k*DDIM + d];
  }
  float sig = 1.f/(1.f + expf(-acc));
  xc[(size_t)bid*DDIM + d] = f2bf(acc*sig);
}

// ---------------- MFMA GEMM: A[M][K] bf16 @ Wt[N][K] bf16 -> out -------------------
// MODE 0: bf16 out = acc + bias;  MODE 1: fp32 out += acc + bias;
// MODE 2: fp32 ptmp[(kc*Mtot + row)*ldo + col] = acc (K-split slices)
template<int BM,int BN,int NWC,int MR,int NR,int MODE>
__global__ __launch_bounds__(256) void mfma_gemm(
    const u16* __restrict__ A, int lda,
    const u16* __restrict__ Wt, int ldwt,
    const float* __restrict__ bias, void* __restrict__ outp, int ldo,
    int ksteps, int kchunk, int Mtot)
{
  constexpr int AU = (BM*4)/256;
  constexpr int WCNT = BN*4;
  constexpr int WU = (WCNT + 255)/256;
  __shared__ u16 As[BM*40];
  __shared__ u16 Ws[BN*40];
  const int tid = threadIdx.x;
  const int lane = tid & 63, wid = tid >> 6;
  const int wr = wid / NWC, wc = wid % NWC;
  const int fr = lane & 15, kb = lane >> 4;
  const int m0 = blockIdx.x*BM, n0 = blockIdx.y*BN;
  const int kc = blockIdx.z;
  const int kbeg = kc*kchunk;
  const u16* Ab = A + (size_t)m0*lda + kbeg;
  const u16* Wb = Wt + (size_t)n0*ldwt + kbeg;
  f32x4 acc[MR][NR];
  #pragma unroll
  for (int m=0;m<MR;++m)
    #pragma unroll
    for (int n=0;n<NR;++n) acc[m][n] = (f32x4){0.f,0.f,0.f,0.f};

  for (int ks = 0; ks < ksteps; ++ks){
    int k0 = ks*32;
    uint4 ar[AU], wreg[WU];
    #pragma unroll
    for (int u=0; u<AU; ++u){
      int idx = u*256 + tid; int row = idx>>2, seg = idx&3;
      ar[u] = *(const uint4*)(Ab + (size_t)row*lda + k0 + seg*8);
    }
    #pragma unroll
    for (int u=0; u<WU; ++u){
      int idx = u*256 + tid;
      if ((WCNT & 255) == 0 || idx < WCNT){
        int row = idx>>2, seg = idx&3;
        wreg[u] = *(const uint4*)(Wb + (size_t)row*ldwt + k0 + seg*8);
      }
    }
    __syncthreads();
    #pragma unroll
    for (int u=0; u<AU; ++u){
      int idx = u*256 + tid; int row = idx>>2, seg = idx&3;
      *(uint4*)&As[row*40 + seg*8] = ar[u];
    }
    #pragma unroll
    for (int u=0; u<WU; ++u){
      int idx = u*256 + tid;
      if ((WCNT & 255) == 0 || idx < WCNT){
        int row = idx>>2, seg = idx&3;
        *(uint4*)&Ws[row*40 + seg*8] = wreg[u];
      }
    }
    __syncthreads();
    bf16x8 af[MR], wf[NR];
    #pragma unroll
    for (int m=0;m<MR;++m)
      af[m] = *(const bf16x8*)&As[(wr*MR*16 + m*16 + fr)*40 + kb*8];
    #pragma unroll
    for (int n=0;n<NR;++n)
      wf[n] = *(const bf16x8*)&Ws[(wc*NR*16 + n*16 + fr)*40 + kb*8];
    #pragma unroll
    for (int m=0;m<MR;++m)
      #pragma unroll
      for (int n=0;n<NR;++n)
        acc[m][n] = __builtin_amdgcn_mfma_f32_16x16x32_bf16(af[m], wf[n], acc[m][n], 0,0,0);
  }
  #pragma unroll
  for (int m=0;m<MR;++m){
    int rowb = m0 + wr*MR*16 + m*16 + kb*4;
    #pragma unroll
    for (int n=0;n<NR;++n){
      int col = n0 + wc*NR*16 + n*16 + fr;
      #pragma unroll
      for (int r=0;r<4;++r){
        int row = rowb + r;
        float v = acc[m][n][r];
        if (MODE == 0){
          ((u16*)outp)[(size_t)row*ldo + col] = f2bf(v + bias[col]);
        } else if (MODE == 1){
          ((float*)outp)[(size_t)row*ldo + col] += v + bias[col];
        } else {
          ((float*)outp)[((size_t)kc*Mtot + row)*ldo + col] = v;
        }
      }
    }
  }
}

// ---------------- FFN up + gelu*g2 fused: A[T][256] @ Wt[768][256] -> gp[T][384] ----
__global__ __launch_bounds__(256) void mfma_up_gelu(
    const u16* __restrict__ A, const u16* __restrict__ Wt,
    const float* __restrict__ ub, u16* __restrict__ gp)
{
  __shared__ u16 As[128*40];
  __shared__ u16 Ws[128*40];   // rows 0..63: g1 cols slice; rows 64..127: g2 cols slice
  const int tid = threadIdx.x;
  const int lane = tid & 63, wid = tid >> 6;
  const int wr = wid >> 1, wc = wid & 1;
  const int fr = lane & 15, kb = lane >> 4;
  const int m0 = blockIdx.x*128, n0 = blockIdx.y*64;
  const u16* Ab = A + (size_t)m0*256;
  const u16* W1 = Wt + (size_t)n0*256;
  const u16* W2 = Wt + (size_t)(384 + n0)*256;
  f32x4 a1[4][2], a2[4][2];
  #pragma unroll
  for (int m=0;m<4;++m)
    #pragma unroll
    for (int n=0;n<2;++n){ a1[m][n]=(f32x4){0,0,0,0}; a2[m][n]=(f32x4){0,0,0,0}; }

  #pragma unroll
  for (int ks = 0; ks < 8; ++ks){
    int k0 = ks*32;
    uint4 ar[2], w1r, w2r;
    #pragma unroll
    for (int u=0; u<2; ++u){
      int idx = u*256 + tid; int row = idx>>2, seg = idx&3;
      ar[u] = *(const uint4*)(Ab + (size_t)row*256 + k0 + seg*8);
    }
    { int row = tid>>2, seg = tid&3;
      w1r = *(const uint4*)(W1 + (size_t)row*256 + k0 + seg*8);
      w2r = *(const uint4*)(W2 + (size_t)row*256 + k0 + seg*8); }
    __syncthreads();
    #pragma unroll
    for (int u=0; u<2; ++u){
      int idx = u*256 + tid; int row = idx>>2, seg = idx&3;
      *(uint4*)&As[row*40 + seg*8] = ar[u];
    }
    { int row = tid>>2, seg = tid&3;
      *(uint4*)&Ws[row*40 + seg*8] = w1r;
      *(uint4*)&Ws[(row+64)*40 + seg*8] = w2r; }
    __syncthreads();
    bf16x8 af[4], wf1[2], wf2[2];
    #pragma unroll
    for (int m=0;m<4;++m)
      af[m] = *(const bf16x8*)&As[(wr*64 + m*16 + fr)*40 + kb*8];
    #pragma unroll
    for (int n=0;n<2;++n){
      wf1[n] = *(const bf16x8*)&Ws[(wc*32 + n*16 + fr)*40 + kb*8];
      wf2[n] = *(const bf16x8*)&Ws[(64 + wc*32 + n*16 + fr)*40 + kb*8];
    }
    #pragma unroll
    for (int m=0;m<4;++m)
      #pragma unroll
      for (int n=0;n<2;++n){
        a1[m][n] = __builtin_amdgcn_mfma_f32_16x16x32_bf16(af[m], wf1[n], a1[m][n], 0,0,0);
        a2[m][n] = __builtin_amdgcn_mfma_f32_16x16x32_bf16(af[m], wf2[n], a2[m][n], 0,0,0);
      }
  }
  #pragma unroll
  for (int m=0;m<4;++m){
    int rowb = m0 + wr*64 + m*16 + kb*4;
    #pragma unroll
    for (int n=0;n<2;++n){
      int col = n0 + wc*32 + n*16 + fr;
      float b1 = ub[col], b2 = ub[384 + col];
      #pragma unroll
      for (int r=0;r<4;++r){
        float g1 = a1[m][n][r] + b1;
        float g2 = a2[m][n][r] + b2;
        float x3 = g1*g1*g1;
        float tv = tanhf(0.7978845608028654f*(g1 + 0.044715f*x3));
        float ge = 0.5f*g1*(1.f + tv);
        gp[(size_t)(rowb + r)*UPDIM + col] = f2bf(ge*g2);
      }
    }
  }
}

// ---------------- sLSTM scan v2: block = 16 seqs x 1 head, 4 waves = 4 gates -------
// gates layout [t][g*256 + hd*64 + e]; fused per-head groupnorm + residual into h_c
__global__ __launch_bounds__(256) void slstm_scan2(
    const u16* __restrict__ gates, const u16* __restrict__ Rgt,
    const float* __restrict__ gnw, float* __restrict__ h_c)
{
  __shared__ u16 h_lds[16*72];
  __shared__ float rec_lds[4][16][68];
  const int tid = threadIdx.x;
  const int w = tid >> 6, lane = tid & 63;
  const int hd = blockIdx.y, grp = blockIdx.x;
  const int fr = lane & 15, kb = lane >> 4;

  // B-fragments for this wave's gate, kept in registers
  bf16x8 bfr[4][2];
  {
    const u16* rb = Rgt + (size_t)(w*NHEAD + hd)*4096;
    #pragma unroll
    for (int n=0;n<4;++n)
      #pragma unroll
      for (int ks=0;ks<2;++ks)
        bfr[n][ks] = *(const bf16x8*)(rb + (size_t)(n*16 + fr)*64 + ks*32 + kb*8);
  }
  for (int i = tid; i < 16*72/2; i += 256) ((u32*)h_lds)[i] = 0u;
  float c[4]={0,0,0,0}, nst[4]={0,0,0,0}, m[4]={0,0,0,0};
  const float gw = gnw[hd*64 + lane];
  const int seq0 = grp*16;
  __syncthreads();

  for (int s = 0; s < NS; ++s){
    // issue gate preact + h_c loads early
    u16 gpre[4][4];
    float hold[4];
    #pragma unroll
    for (int si=0; si<4; ++si){
      size_t t = (size_t)(seq0 + 4*w + si)*NS + s;
      const u16* gp0 = gates + t*1024 + hd*64 + lane;
      gpre[si][0] = gp0[0];
      gpre[si][1] = gp0[256];
      gpre[si][2] = gp0[512];
      gpre[si][3] = gp0[768];
      hold[si] = h_c[t*DDIM + hd*64 + lane];
    }
    // MFMA: rec = H @ Rg[w]
    bf16x8 af0 = *(const bf16x8*)&h_lds[fr*72 + kb*8];
    bf16x8 af1 = *(const bf16x8*)&h_lds[fr*72 + 32 + kb*8];
    f32x4 acc[4];
    #pragma unroll
    for (int n=0;n<4;++n){
      acc[n] = (f32x4){0,0,0,0};
      acc[n] = __builtin_amdgcn_mfma_f32_16x16x32_bf16(af0, bfr[n][0], acc[n], 0,0,0);
      acc[n] = __builtin_amdgcn_mfma_f32_16x16x32_bf16(af1, bfr[n][1], acc[n], 0,0,0);
    }
    #pragma unroll
    for (int n=0;n<4;++n)
      #pragma unroll
      for (int r=0;r<4;++r)
        rec_lds[w][kb*4 + r][n*16 + fr] = acc[n][r];
    __syncthreads();
    // elementwise: wave w owns states s = 4w..4w+3, lane = e
    #pragma unroll
    for (int si=0; si<4; ++si){
      int sidx = 4*w + si;
      float ip = rec_lds[0][sidx][lane] + bf2f(gpre[si][0]);
      float fp = rec_lds[1][sidx][lane] + bf2f(gpre[si][1]);
      float zp = rec_lds[2][sidx][lane] + bf2f(gpre[si][2]);
      float op = rec_lds[3][sidx][lane] + bf2f(gpre[si][3]);
      float lsf = fminf(fp, 0.f) - log1pf(expf(-fabsf(fp)));
      float lg  = m[si] + lsf;
      float mn  = fmaxf(ip, lg);
      float iv  = expf(ip - mn);
      float fv  = expf(lg - mn);
      c[si]   = fv*c[si] + iv*tanhf(zp);
      nst[si] = fv*nst[si] + iv;
      m[si]   = mn;
      float hv = c[si]/nst[si] * (1.f/(1.f + expf(-op)));
      h_lds[sidx*72 + lane] = f2bf(hv);
      // fused groupnorm over e (this wave's 64 lanes) + residual
      float s1 = hv, s2 = hv*hv;
      #pragma unroll
      for (int o=1;o<64;o<<=1){ s1 += __shfl_xor(s1,o,64); s2 += __shfl_xor(s2,o,64); }
      float mu = s1*(1.f/64.f);
      float var = s2*(1.f/64.f) - mu*mu;
      float yn = (hv - mu)*rsqrtf(var + 1e-5f)*gw;
      size_t t = (size_t)(seq0 + sidx)*NS + s;
      h_c[t*DDIM + hd*64 + lane] = hold[si] + yn;
    }
    __syncthreads();
  }
}

// ---------------- proj reduce over K-split slices ----------------------------------
__global__ __launch_bounds__(256) void proj_out(
    const float* __restrict__ ptmp, const float* __restrict__ bproj,
    float* __restrict__ out, int Nc, int n0glob){
  int gid = blockIdx.x*256 + threadIdx.x;
  if (gid >= Nc*PREDN) return;
  float acc = 0.f;
  #pragma unroll
  for (int kc = 0; kc < KC_PROJ; ++kc) acc += ptmp[(size_t)kc*Nc*PREDN + gid];
  int nl = gid / PREDN, j = gid - nl*PREDN;
  int n = n0glob + nl;
  out[((size_t)(n >> 5)*PREDN + j)*CCH + (n & 31)] = acc + bproj[j];
}

extern "C" void kernel_launch(void* const* d_in, const int* in_sizes, int n_in,
                              void* d_out, int out_size, void* d_ws, size_t ws_size,
                              hipStream_t stream) {
  const float* x      = (const float*)d_in[0];
  const float* W_emb  = (const float*)d_in[1];
  const float* b_emb  = (const float*)d_in[2];
  const float* ln1_w  = (const float*)d_in[3];
  const float* ln1_b  = (const float*)d_in[4];
  const float* conv_w = (const float*)d_in[5];
  const float* conv_b = (const float*)d_in[6];
  const float* Wg     = (const float*)d_in[7];
  const float* Rg     = (const float*)d_in[8];
  const float* gb     = (const float*)d_in[9];
  const float* gn_w   = (const float*)d_in[10];
  const float* ln2_w  = (const float*)d_in[11];
  const float* ln2_b  = (const float*)d_in[12];
  const float* up_w   = (const float*)d_in[13];
  const float* up_b   = (const float*)d_in[14];
  const float* dn_w   = (const float*)d_in[15];
  const float* dn_b   = (const float*)d_in[16];
  const float* post_w = (const float*)d_in[17];
  const float* post_b = (const float*)d_in[18];
  const float* W_proj = (const float*)d_in[19];
  const float* b_proj = (const float*)d_in[20];
  float* out = (float*)d_out;

  // ---- workspace layout ----
  const size_t oWu   = 0;          // [2][768][256] bf16 : 1,572,864
  const size_t oWd   = 1572864;    // [2][256][384] bf16 :   786,432
  const size_t oWgD  = 2359296;    // [2][2][512][256] bf16 : 1,048,576
  const size_t oRgt  = 3407872;    // [2][16][64][64] bf16 :   524,288
  const size_t oWp   = 3932160;    // [96][16128] bf16 : 3,096,576
  const size_t oChunk = 7028736;
  const size_t per_seq = 268800;
  int Nc = 0;
  const int cands[4] = {1024, 512, 256, 128};
  for (int i = 0; i < 4; ++i)
    if (oChunk + (size_t)cands[i]*per_seq <= ws_size){ Nc = cands[i]; break; }
  if (Nc == 0) return;

  char* wsb = (char*)d_ws;
  u16* Wu   = (u16*)(wsb + oWu);
  u16* Wd   = (u16*)(wsb + oWd);
  u16* WgD  = (u16*)(wsb + oWgD);
  u16* Rgt  = (u16*)(wsb + oRgt);
  u16* Wtp  = (u16*)(wsb + oWp);

  for (int blk = 0; blk < 2; ++blk){
    cvt_transpose<<<(256*768+255)/256, 256, 0, stream>>>(
        up_w + (size_t)blk*256*768, Wu + (size_t)blk*768*256, 256, 768);
    cvt_transpose<<<(384*256+255)/256, 256, 0, stream>>>(
        dn_w + (size_t)blk*384*256, Wd + (size_t)blk*256*384, 384, 256);
  }
  cvt_gateW<<<dim3(512, 2, 2), 256, 0, stream>>>(Wg, WgD);
  cvt_gate<<<32, 256, 0, stream>>>(Rg, Rgt);
  cvt_transpose<<<(16128*96+255)/256, 256, 0, stream>>>(W_proj, Wtp, 16128, 96);

  for (int n0 = 0; n0 < NSEQ; n0 += Nc){
    const int    nc  = Nc;
    const size_t Tc  = (size_t)nc * NS;
    char* cb = wsb + oChunk;
    float* h_c   = (float*)cb;                        // Tc*1024 B
    u16*   bufA  = (u16*)(cb + Tc*1024);              // Tc*512 B
    u16*   bufB  = (u16*)(cb + Tc*1536);              // Tc*512 B
    u16*   gates = (u16*)(cb + Tc*2048);              // Tc*2048 B ([t][1024])
    float* ptmp  = (float*)(cb + Tc*4096);            // nc*KC_PROJ*96*4 B
    u16*   gp    = gates;                             // reuse after scan (Tc*768 B)
    const int t_base = n0*NS;
    const int Tci = (int)Tc;

    patch_embed<<<Tci, 256, 0, stream>>>(x, W_emb, b_emb, h_c, t_base);

    for (int blk = 0; blk < 2; ++blk){
      layernorm_bf16<<<Tci, 256, 0, stream>>>(h_c, ln1_w + blk*DDIM, ln1_b + blk*DDIM, bufA);
      conv_silu<<<Tci, 256, 0, stream>>>(bufA, conv_w + blk*4*DDIM, conv_b + blk*DDIM, bufB, t_base);
      // gates i,f from xc ; z,o from xh  (block-diagonal dense GEMMs)
      mfma_gemm<128,128,2,4,4,0><<<dim3(Tci/128, 4), 256, 0, stream>>>(
          bufB, DDIM, WgD + (size_t)blk*2*512*256, DDIM,
          gb + blk*4*DDIM, (void*)gates, 1024, 8, 0, 0);
      mfma_gemm<128,128,2,4,4,0><<<dim3(Tci/128, 4), 256, 0, stream>>>(
          bufA, DDIM, WgD + ((size_t)blk*2 + 1)*512*256, DDIM,
          gb + blk*4*DDIM + 512, (void*)(gates + 512), 1024, 8, 0, 0);
      slstm_scan2<<<dim3(nc/16, NHEAD), 256, 0, stream>>>(
          gates, Rgt + (size_t)blk*16*4096, gn_w + blk*DDIM, h_c);
      layernorm_bf16<<<Tci, 256, 0, stream>>>(h_c, ln2_w + blk*DDIM, ln2_b + blk*DDIM, bufA);
      mfma_up_gelu<<<dim3(Tci/128, 6), 256, 0, stream>>>(
          bufA, Wu + (size_t)blk*768*256, up_b + blk*2*UPDIM, gp);
      mfma_gemm<128,128,2,4,4,1><<<dim3(Tci/128, 2), 256, 0, stream>>>(
          gp, UPDIM, Wd + (size_t)blk*256*384, UPDIM,
          dn_b + blk*DDIM, (void*)h_c, DDIM, 12, 0, 0);
    }

    layernorm_bf16<<<Tci, 256, 0, stream>>>(h_c, post_w, post_b, bufA);
    mfma_gemm<64,96,2,2,3,2><<<dim3(nc/64, 1, KC_PROJ), 256, 0, stream>>>(
        bufA, NS*DDIM, Wtp, NS*DDIM,
        b_proj, (void*)ptmp, PREDN, KCHUNK_PROJ/32, KCHUNK_PROJ, nc);
    proj_out<<<(nc*PREDN + 255)/256, 256, 0, stream>>>(ptmp, b_proj, out, nc, n0);
  }
}

// Round 5
// 1669.865 us; speedup vs baseline: 1.8890x; 1.3461x over previous
//
#include <hip/hip_runtime.h>
#include <stdint.h>

typedef unsigned short u16;
typedef unsigned int   u32;
typedef __attribute__((ext_vector_type(8))) short bf16x8;
typedef __attribute__((ext_vector_type(4))) float f32x4;

#define NS      63
#define NSEQ    1024
#define DDIM    256
#define NHEAD   4
#define DHEAD   64
#define UPDIM   384
#define PREDN   96
#define LLEN    512
#define CCH     32
#define PSIZE   16
#define PSTRIDE 8
#define KC_PROJ 8
#define KCHUNK_PROJ 2016

__device__ __forceinline__ float bf2f(u32 lo16){
  union { u32 i; float f; } v; v.i = lo16 << 16; return v.f;
}
__device__ __forceinline__ float bf2f_hi(u32 u){
  union { u32 i; float f; } v; v.i = u & 0xffff0000u; return v.f;
}
__device__ __forceinline__ u16 f2bf(float f){
  union { u32 i; float f; } v; v.f = f;
  u32 u = v.i; u += 0x7fffu + ((u >> 16) & 1u);
  return (u16)(u >> 16);
}

// ---------------- weight convert + transpose: dst[c][r] = bf16(src[r][c]) ----------
__global__ __launch_bounds__(256) void cvt_transpose(
    const float* __restrict__ src, u16* __restrict__ dst, int R, int C){
  int idx = blockIdx.x*256 + threadIdx.x;
  if (idx >= R*C) return;
  int r = idx / C, c = idx - r*C;
  dst[(size_t)c*R + r] = f2bf(src[idx]);
}

// 64x64 per-matrix transpose (used for Rg -> Rgt)
__global__ __launch_bounds__(256) void cvt_gate(
    const float* __restrict__ src, u16* __restrict__ dst){
  int mat = blockIdx.x, t = threadIdx.x;
  const float* s = src + (size_t)mat*4096;
  u16* d = dst + (size_t)mat*4096;
  for (int i = t; i < 4096; i += 256){
    int r = i >> 6, c = i & 63;
    d[c*64 + r] = f2bf(s[i]);
  }
}

// block-diagonal gate weight: dst[blk][p][n][256 k], n = hd*128 + gl*64 + e
__global__ __launch_bounds__(256) void cvt_gateW(
    const float* __restrict__ Wg, u16* __restrict__ dst){
  int n = blockIdx.x, p = blockIdx.y, blk = blockIdx.z, k = threadIdx.x;
  int hd = n >> 7, gl = (n >> 6) & 1, e = n & 63;
  int g = 2*p + gl;
  float v = ((k >> 6) == hd) ? Wg[((((size_t)blk*4 + g)*4 + hd)*64 + (k & 63))*64 + e] : 0.f;
  dst[(((size_t)blk*2 + p)*512 + n)*256 + k] = f2bf(v);
}

// ---------------- patch embedding (chunk-local h) ----------------------------------
__global__ __launch_bounds__(256) void patch_embed(
    const float* __restrict__ x, const float* __restrict__ Wemb,
    const float* __restrict__ bemb, float* __restrict__ h, int t_base){
  int bid = blockIdx.x, d = threadIdx.x;
  int tg = t_base + bid;
  int n = tg / NS, s = tg - n*NS;
  int b = n >> 5, c = n & 31;
  int l0 = s * PSTRIDE;
  float acc = bemb[d];
  #pragma unroll
  for (int p = 0; p < PSIZE; ++p){
    float xv = x[((size_t)b*LLEN + l0 + p)*CCH + c];
    acc += xv * Wemb[p*DDIM + d];
  }
  h[(size_t)bid*DDIM + d] = acc;
}

// ---------------- layernorm over D=256, fp32 in -> bf16 out ------------------------
__global__ __launch_bounds__(256) void layernorm_bf16(
    const float* __restrict__ in, const float* __restrict__ w,
    const float* __restrict__ b, u16* __restrict__ out){
  int t = blockIdx.x, d = threadIdx.x;
  float v = in[(size_t)t*DDIM + d];
  float s1 = v, s2 = v*v;
  #pragma unroll
  for (int o = 1; o < 64; o <<= 1){ s1 += __shfl_xor(s1, o, 64); s2 += __shfl_xor(s2, o, 64); }
  __shared__ float ws1[4], ws2[4];
  int wid = d >> 6, lane = d & 63;
  if (lane == 0){ ws1[wid] = s1; ws2[wid] = s2; }
  __syncthreads();
  s1 = ws1[0]+ws1[1]+ws1[2]+ws1[3];
  s2 = ws2[0]+ws2[1]+ws2[2]+ws2[3];
  float mu = s1 * (1.f/DDIM);
  float var = s2 * (1.f/DDIM) - mu*mu;
  float rstd = rsqrtf(var + 1e-5f);
  out[(size_t)t*DDIM + d] = f2bf((v - mu)*rstd*w[d] + b[d]);
}

// ---------------- fused groupnorm + residual + layernorm ---------------------------
__global__ __launch_bounds__(256) void gn_res_ln(
    const u16* __restrict__ y, const float* __restrict__ gnw,
    const float* __restrict__ w2, const float* __restrict__ b2,
    float* __restrict__ h, u16* __restrict__ outA){
  int t = blockIdx.x, d = threadIdx.x;
  float v = bf2f(y[(size_t)t*DDIM + d]);
  float s1 = v, s2 = v*v;
  #pragma unroll
  for (int o = 1; o < 64; o <<= 1){ s1 += __shfl_xor(s1, o, 64); s2 += __shfl_xor(s2, o, 64); }
  float mu64 = s1*(1.f/64.f);
  float var64 = s2*(1.f/64.f) - mu64*mu64;
  float yn = (v - mu64)*rsqrtf(var64 + 1e-5f)*gnw[d];
  float hn = h[(size_t)t*DDIM + d] + yn;
  h[(size_t)t*DDIM + d] = hn;
  // LN over 256
  float t1 = hn, t2 = hn*hn;
  #pragma unroll
  for (int o = 1; o < 64; o <<= 1){ t1 += __shfl_xor(t1, o, 64); t2 += __shfl_xor(t2, o, 64); }
  __shared__ float ws1[4], ws2[4];
  int wid = d >> 6, lane = d & 63;
  if (lane == 0){ ws1[wid] = t1; ws2[wid] = t2; }
  __syncthreads();
  t1 = ws1[0]+ws1[1]+ws1[2]+ws1[3];
  t2 = ws2[0]+ws2[1]+ws2[2]+ws2[3];
  float mu = t1*(1.f/DDIM);
  float var = t2*(1.f/DDIM) - mu*mu;
  float rstd = rsqrtf(var + 1e-5f);
  outA[(size_t)t*DDIM + d] = f2bf((hn - mu)*rstd*w2[d] + b2[d]);
}

// ---------------- causal depthwise conv K=4 + SiLU, bf16 -> bf16 -------------------
__global__ __launch_bounds__(256) void conv_silu(
    const u16* __restrict__ xln, const float* __restrict__ cw,
    const float* __restrict__ cb, u16* __restrict__ xc, int t_base){
  int bid = blockIdx.x, d = threadIdx.x;
  int tg = t_base + bid;
  int n = tg / NS, s = tg - n*NS;
  float acc = cb[d];
  #pragma unroll
  for (int k = 0; k < 4; ++k){
    int ss = s + k - 3;
    if (ss >= 0) acc += bf2f(xln[(size_t)(bid + k - 3)*DDIM + d]) * cw[k*DDIM + d];
  }
  float sig = 1.f/(1.f + __expf(-acc));
  xc[(size_t)bid*DDIM + d] = f2bf(acc*sig);
}

// ---------------- MFMA GEMM: A[M][K] bf16 @ Wt[N][K] bf16 -> out -------------------
// MODE 0: bf16 out = acc + bias;  MODE 1: fp32 out += acc + bias;
// MODE 2: fp32 ptmp[(kc*Mtot + row)*ldo + col] = acc (K-split slices)
// MODE 3: gate store: phys col = hd*256 + p*128 + e*2 + gl, bias from gb; p = Mtot
template<int BM,int BN,int NWC,int MR,int NR,int MODE>
__global__ __launch_bounds__(256) void mfma_gemm(
    const u16* __restrict__ A, int lda,
    const u16* __restrict__ Wt, int ldwt,
    const float* __restrict__ bias, void* __restrict__ outp, int ldo,
    int ksteps, int kchunk, int Mtot)
{
  constexpr int AU = (BM*4)/256;
  constexpr int WCNT = BN*4;
  constexpr int WU = (WCNT + 255)/256;
  __shared__ u16 As[BM*40];
  __shared__ u16 Ws[BN*40];
  const int tid = threadIdx.x;
  const int lane = tid & 63, wid = tid >> 6;
  const int wr = wid / NWC, wc = wid % NWC;
  const int fr = lane & 15, kb = lane >> 4;
  const int m0 = blockIdx.x*BM, n0 = blockIdx.y*BN;
  const int kc = blockIdx.z;
  const int kbeg = kc*kchunk;
  const u16* Ab = A + (size_t)m0*lda + kbeg;
  const u16* Wb = Wt + (size_t)n0*ldwt + kbeg;
  f32x4 acc[MR][NR];
  #pragma unroll
  for (int m=0;m<MR;++m)
    #pragma unroll
    for (int n=0;n<NR;++n) acc[m][n] = (f32x4){0.f,0.f,0.f,0.f};

  for (int ks = 0; ks < ksteps; ++ks){
    int k0 = ks*32;
    uint4 ar[AU], wreg[WU];
    #pragma unroll
    for (int u=0; u<AU; ++u){
      int idx = u*256 + tid; int row = idx>>2, seg = idx&3;
      ar[u] = *(const uint4*)(Ab + (size_t)row*lda + k0 + seg*8);
    }
    #pragma unroll
    for (int u=0; u<WU; ++u){
      int idx = u*256 + tid;
      if ((WCNT & 255) == 0 || idx < WCNT){
        int row = idx>>2, seg = idx&3;
        wreg[u] = *(const uint4*)(Wb + (size_t)row*ldwt + k0 + seg*8);
      }
    }
    __syncthreads();
    #pragma unroll
    for (int u=0; u<AU; ++u){
      int idx = u*256 + tid; int row = idx>>2, seg = idx&3;
      *(uint4*)&As[row*40 + seg*8] = ar[u];
    }
    #pragma unroll
    for (int u=0; u<WU; ++u){
      int idx = u*256 + tid;
      if ((WCNT & 255) == 0 || idx < WCNT){
        int row = idx>>2, seg = idx&3;
        *(uint4*)&Ws[row*40 + seg*8] = wreg[u];
      }
    }
    __syncthreads();
    bf16x8 af[MR], wf[NR];
    #pragma unroll
    for (int m=0;m<MR;++m)
      af[m] = *(const bf16x8*)&As[(wr*MR*16 + m*16 + fr)*40 + kb*8];
    #pragma unroll
    for (int n=0;n<NR;++n)
      wf[n] = *(const bf16x8*)&Ws[(wc*NR*16 + n*16 + fr)*40 + kb*8];
    #pragma unroll
    for (int m=0;m<MR;++m)
      #pragma unroll
      for (int n=0;n<NR;++n)
        acc[m][n] = __builtin_amdgcn_mfma_f32_16x16x32_bf16(af[m], wf[n], acc[m][n], 0,0,0);
  }
  #pragma unroll
  for (int m=0;m<MR;++m){
    int rowb = m0 + wr*MR*16 + m*16 + kb*4;
    #pragma unroll
    for (int n=0;n<NR;++n){
      int col = n0 + wc*NR*16 + n*16 + fr;
      #pragma unroll
      for (int r=0;r<4;++r){
        int row = rowb + r;
        float v = acc[m][n][r];
        if (MODE == 0){
          ((u16*)outp)[(size_t)row*ldo + col] = f2bf(v + bias[col]);
        } else if (MODE == 1){
          ((float*)outp)[(size_t)row*ldo + col] += v + bias[col];
        } else if (MODE == 2){
          ((float*)outp)[((size_t)kc*Mtot + row)*ldo + col] = v;
        } else {
          int e = col & 63, gl = (col >> 6) & 1, hd2 = col >> 7;
          float bv = bias[(2*Mtot + gl)*256 + hd2*64 + e];
          int phys = hd2*256 + Mtot*128 + e*2 + gl;
          ((u16*)outp)[(size_t)row*ldo + phys] = f2bf(v + bv);
        }
      }
    }
  }
}

// ---------------- FFN up + gelu*g2 fused: A[T][256] @ Wt[768][256] -> gp[T][384] ----
__global__ __launch_bounds__(256) void mfma_up_gelu(
    const u16* __restrict__ A, const u16* __restrict__ Wt,
    const float* __restrict__ ub, u16* __restrict__ gp)
{
  __shared__ u16 As[128*40];
  __shared__ u16 Ws[128*40];
  const int tid = threadIdx.x;
  const int lane = tid & 63, wid = tid >> 6;
  const int wr = wid >> 1, wc = wid & 1;
  const int fr = lane & 15, kb = lane >> 4;
  const int m0 = blockIdx.x*128, n0 = blockIdx.y*64;
  const u16* Ab = A + (size_t)m0*256;
  const u16* W1 = Wt + (size_t)n0*256;
  const u16* W2 = Wt + (size_t)(384 + n0)*256;
  f32x4 a1[4][2], a2[4][2];
  #pragma unroll
  for (int m=0;m<4;++m)
    #pragma unroll
    for (int n=0;n<2;++n){ a1[m][n]=(f32x4){0,0,0,0}; a2[m][n]=(f32x4){0,0,0,0}; }

  #pragma unroll
  for (int ks = 0; ks < 8; ++ks){
    int k0 = ks*32;
    uint4 ar[2], w1r, w2r;
    #pragma unroll
    for (int u=0; u<2; ++u){
      int idx = u*256 + tid; int row = idx>>2, seg = idx&3;
      ar[u] = *(const uint4*)(Ab + (size_t)row*256 + k0 + seg*8);
    }
    { int row = tid>>2, seg = tid&3;
      w1r = *(const uint4*)(W1 + (size_t)row*256 + k0 + seg*8);
      w2r = *(const uint4*)(W2 + (size_t)row*256 + k0 + seg*8); }
    __syncthreads();
    #pragma unroll
    for (int u=0; u<2; ++u){
      int idx = u*256 + tid; int row = idx>>2, seg = idx&3;
      *(uint4*)&As[row*40 + seg*8] = ar[u];
    }
    { int row = tid>>2, seg = tid&3;
      *(uint4*)&Ws[row*40 + seg*8] = w1r;
      *(uint4*)&Ws[(row+64)*40 + seg*8] = w2r; }
    __syncthreads();
    bf16x8 af[4], wf1[2], wf2[2];
    #pragma unroll
    for (int m=0;m<4;++m)
      af[m] = *(const bf16x8*)&As[(wr*64 + m*16 + fr)*40 + kb*8];
    #pragma unroll
    for (int n=0;n<2;++n){
      wf1[n] = *(const bf16x8*)&Ws[(wc*32 + n*16 + fr)*40 + kb*8];
      wf2[n] = *(const bf16x8*)&Ws[(64 + wc*32 + n*16 + fr)*40 + kb*8];
    }
    #pragma unroll
    for (int m=0;m<4;++m)
      #pragma unroll
      for (int n=0;n<2;++n){
        a1[m][n] = __builtin_amdgcn_mfma_f32_16x16x32_bf16(af[m], wf1[n], a1[m][n], 0,0,0);
        a2[m][n] = __builtin_amdgcn_mfma_f32_16x16x32_bf16(af[m], wf2[n], a2[m][n], 0,0,0);
      }
  }
  #pragma unroll
  for (int m=0;m<4;++m){
    int rowb = m0 + wr*64 + m*16 + kb*4;
    #pragma unroll
    for (int n=0;n<2;++n){
      int col = n0 + wc*32 + n*16 + fr;
      float b1 = ub[col], b2 = ub[384 + col];
      #pragma unroll
      for (int r=0;r<4;++r){
        float g1 = a1[m][n][r] + b1;
        float g2 = a2[m][n][r] + b2;
        float x3 = g1*g1*g1;
        float tv = tanhf(0.7978845608028654f*(g1 + 0.044715f*x3));
        float ge = 0.5f*g1*(1.f + tv);
        gp[(size_t)(rowb + r)*UPDIM + col] = f2bf(ge*g2);
      }
    }
  }
}

// ---------------- sLSTM scan v3: prefetched gates, recurrence-only core ------------
// gates layout [t][hd*256 + p*128 + e*2 + gl]; y out bf16 [t][hd*64+e]
__global__ __launch_bounds__(256) void slstm_scan3(
    const u16* __restrict__ gates, const u16* __restrict__ Rgt,
    u16* __restrict__ y)
{
  __shared__ u16 h_lds[16*72];
  __shared__ float rec_lds[4][16][68];
  const int tid = threadIdx.x;
  const int w = tid >> 6, lane = tid & 63;
  const int hd = blockIdx.y, grp = blockIdx.x;
  const int fr = lane & 15, kb = lane >> 4;
  const int seq0 = grp*16;
  const u32* g32 = (const u32*)gates;

  bf16x8 bfr[4][2];
  {
    const u16* rb = Rgt + (size_t)(w*NHEAD + hd)*4096;
    #pragma unroll
    for (int n=0;n<4;++n)
      #pragma unroll
      for (int ks=0;ks<2;++ks)
        bfr[n][ks] = *(const bf16x8*)(rb + (size_t)(n*16 + fr)*64 + ks*32 + kb*8);
  }
  for (int i = tid; i < 16*72/2; i += 256) ((u32*)h_lds)[i] = 0u;
  float c[4]={0,0,0,0}, nst[4]={0,0,0,0}, m[4]={0,0,0,0};

  // prefetch step 0
  u32 gcur[4][2];
  #pragma unroll
  for (int si=0; si<4; ++si){
    size_t base = ((size_t)(seq0 + 4*w + si)*NS)*512 + hd*128 + lane;
    gcur[si][0] = g32[base];
    gcur[si][1] = g32[base + 64];
  }
  __syncthreads();

  for (int s = 0; s < NS; ++s){
    u32 gnxt[4][2];
    if (s + 1 < NS){
      #pragma unroll
      for (int si=0; si<4; ++si){
        size_t base = ((size_t)(seq0 + 4*w + si)*NS + s + 1)*512 + hd*128 + lane;
        gnxt[si][0] = g32[base];
        gnxt[si][1] = g32[base + 64];
      }
    }
    // MFMA: rec = H @ Rg[w]
    bf16x8 af0 = *(const bf16x8*)&h_lds[fr*72 + kb*8];
    bf16x8 af1 = *(const bf16x8*)&h_lds[fr*72 + 32 + kb*8];
    f32x4 acc[4];
    #pragma unroll
    for (int n=0;n<4;++n){
      acc[n] = (f32x4){0,0,0,0};
      acc[n] = __builtin_amdgcn_mfma_f32_16x16x32_bf16(af0, bfr[n][0], acc[n], 0,0,0);
      acc[n] = __builtin_amdgcn_mfma_f32_16x16x32_bf16(af1, bfr[n][1], acc[n], 0,0,0);
    }
    #pragma unroll
    for (int n=0;n<4;++n)
      #pragma unroll
      for (int r=0;r<4;++r)
        rec_lds[w][kb*4 + r][n*16 + fr] = acc[n][r];
    __syncthreads();
    // elementwise: wave w owns seqs 4w..4w+3, lane = e
    #pragma unroll
    for (int si=0; si<4; ++si){
      int sidx = 4*w + si;
      float ip = rec_lds[0][sidx][lane] + bf2f(gcur[si][0] & 0xffffu);
      float fp = rec_lds[1][sidx][lane] + bf2f_hi(gcur[si][0]);
      float zp = rec_lds[2][sidx][lane] + bf2f(gcur[si][1] & 0xffffu);
      float op = rec_lds[3][sidx][lane] + bf2f_hi(gcur[si][1]);
      float sp  = __logf(1.f + __expf(-fabsf(fp)));
      float lg  = m[si] + fminf(fp, 0.f) - sp;
      float mn  = fmaxf(ip, lg);
      float iv  = __expf(ip - mn);
      float fv  = __expf(lg - mn);
      float zz  = fminf(fabsf(zp), 15.f);
      float t2  = __expf(zz + zz);
      float tha = (t2 - 1.f)/(t2 + 1.f);
      float th  = (zp >= 0.f) ? tha : -tha;
      c[si]   = fv*c[si] + iv*th;
      nst[si] = fv*nst[si] + iv;
      m[si]   = mn;
      float hv = c[si] * __builtin_amdgcn_rcpf(nst[si]*(1.f + __expf(-op)));
      h_lds[sidx*72 + lane] = f2bf(hv);
      size_t t = (size_t)(seq0 + sidx)*NS + s;
      y[t*DDIM + hd*64 + lane] = f2bf(hv);
    }
    __syncthreads();
    #pragma unroll
    for (int si=0; si<4; ++si){ gcur[si][0] = gnxt[si][0]; gcur[si][1] = gnxt[si][1]; }
  }
}

// ---------------- proj reduce over K-split slices ----------------------------------
__global__ __launch_bounds__(256) void proj_out(
    const float* __restrict__ ptmp, const float* __restrict__ bproj,
    float* __restrict__ out, int Nc, int n0glob){
  int gid = blockIdx.x*256 + threadIdx.x;
  if (gid >= Nc*PREDN) return;
  float acc = 0.f;
  #pragma unroll
  for (int kc = 0; kc < KC_PROJ; ++kc) acc += ptmp[(size_t)kc*Nc*PREDN + gid];
  int nl = gid / PREDN, j = gid - nl*PREDN;
  int n = n0glob + nl;
  out[((size_t)(n >> 5)*PREDN + j)*CCH + (n & 31)] = acc + bproj[j];
}

extern "C" void kernel_launch(void* const* d_in, const int* in_sizes, int n_in,
                              void* d_out, int out_size, void* d_ws, size_t ws_size,
                              hipStream_t stream) {
  const float* x      = (const float*)d_in[0];
  const float* W_emb  = (const float*)d_in[1];
  const float* b_emb  = (const float*)d_in[2];
  const float* ln1_w  = (const float*)d_in[3];
  const float* ln1_b  = (const float*)d_in[4];
  const float* conv_w = (const float*)d_in[5];
  const float* conv_b = (const float*)d_in[6];
  const float* Wg     = (const float*)d_in[7];
  const float* Rg     = (const float*)d_in[8];
  const float* gb     = (const float*)d_in[9];
  const float* gn_w   = (const float*)d_in[10];
  const float* ln2_w  = (const float*)d_in[11];
  const float* ln2_b  = (const float*)d_in[12];
  const float* up_w   = (const float*)d_in[13];
  const float* up_b   = (const float*)d_in[14];
  const float* dn_w   = (const float*)d_in[15];
  const float* dn_b   = (const float*)d_in[16];
  const float* post_w = (const float*)d_in[17];
  const float* post_b = (const float*)d_in[18];
  const float* W_proj = (const float*)d_in[19];
  const float* b_proj = (const float*)d_in[20];
  float* out = (float*)d_out;

  // ---- workspace layout ----
  const size_t oWu   = 0;          // [2][768][256] bf16 : 1,572,864
  const size_t oWd   = 1572864;    // [2][256][384] bf16 :   786,432
  const size_t oWgD  = 2359296;    // [2][2][512][256] bf16 : 1,048,576
  const size_t oRgt  = 3407872;    // [2][16][64][64] bf16 :   524,288
  const size_t oWp   = 3932160;    // [96][16128] bf16 : 3,096,576
  const size_t oChunk = 7028736;
  const size_t per_seq = 268800;
  int Nc = 0;
  const int cands[4] = {1024, 512, 256, 128};
  for (int i = 0; i < 4; ++i)
    if (oChunk + (size_t)cands[i]*per_seq <= ws_size){ Nc = cands[i]; break; }
  if (Nc == 0) return;

  char* wsb = (char*)d_ws;
  u16* Wu   = (u16*)(wsb + oWu);
  u16* Wd   = (u16*)(wsb + oWd);
  u16* WgD  = (u16*)(wsb + oWgD);
  u16* Rgt  = (u16*)(wsb + oRgt);
  u16* Wtp  = (u16*)(wsb + oWp);

  for (int blk = 0; blk < 2; ++blk){
    cvt_transpose<<<(256*768+255)/256, 256, 0, stream>>>(
        up_w + (size_t)blk*256*768, Wu + (size_t)blk*768*256, 256, 768);
    cvt_transpose<<<(384*256+255)/256, 256, 0, stream>>>(
        dn_w + (size_t)blk*384*256, Wd + (size_t)blk*256*384, 384, 256);
  }
  cvt_gateW<<<dim3(512, 2, 2), 256, 0, stream>>>(Wg, WgD);
  cvt_gate<<<32, 256, 0, stream>>>(Rg, Rgt);
  cvt_transpose<<<(16128*96+255)/256, 256, 0, stream>>>(W_proj, Wtp, 16128, 96);

  for (int n0 = 0; n0 < NSEQ; n0 += Nc){
    const int    nc  = Nc;
    const size_t Tc  = (size_t)nc * NS;
    char* cb = wsb + oChunk;
    float* h_c   = (float*)cb;                        // Tc*1024 B
    u16*   bufA  = (u16*)(cb + Tc*1024);              // Tc*512 B
    u16*   bufB  = (u16*)(cb + Tc*1536);              // Tc*512 B
    u16*   gates = (u16*)(cb + Tc*2048);              // Tc*2048 B ([t][1024])
    float* ptmp  = (float*)(cb + Tc*4096);            // nc*KC_PROJ*96*4 B
    u16*   gp    = gates;                             // reuse after scan (Tc*768 B)
    const int t_base = n0*NS;
    const int Tci = (int)Tc;

    patch_embed<<<Tci, 256, 0, stream>>>(x, W_emb, b_emb, h_c, t_base);

    for (int blk = 0; blk < 2; ++blk){
      layernorm_bf16<<<Tci, 256, 0, stream>>>(h_c, ln1_w + blk*DDIM, ln1_b + blk*DDIM, bufA);
      conv_silu<<<Tci, 256, 0, stream>>>(bufA, conv_w + blk*4*DDIM, conv_b + blk*DDIM, bufB, t_base);
      // gate pair p=0 (i,f from xc); p=1 (z,o from xh); scan-friendly layout
      mfma_gemm<128,128,2,4,4,3><<<dim3(Tci/128, 4), 256, 0, stream>>>(
          bufB, DDIM, WgD + (size_t)blk*2*512*256, DDIM,
          gb + blk*4*DDIM, (void*)gates, 1024, 8, 0, 0);
      mfma_gemm<128,128,2,4,4,3><<<dim3(Tci/128, 4), 256, 0, stream>>>(
          bufA, DDIM, WgD + ((size_t)blk*2 + 1)*512*256, DDIM,
          gb + blk*4*DDIM, (void*)gates, 1024, 8, 0, 1);
      slstm_scan3<<<dim3(nc/16, NHEAD), 256, 0, stream>>>(
          gates, Rgt + (size_t)blk*16*4096, bufB);
      gn_res_ln<<<Tci, 256, 0, stream>>>(
          bufB, gn_w + blk*DDIM, ln2_w + blk*DDIM, ln2_b + blk*DDIM, h_c, bufA);
      mfma_up_gelu<<<dim3(Tci/128, 6), 256, 0, stream>>>(
          bufA, Wu + (size_t)blk*768*256, up_b + blk*2*UPDIM, gp);
      mfma_gemm<128,128,2,4,4,1><<<dim3(Tci/128, 2), 256, 0, stream>>>(
          gp, UPDIM, Wd + (size_t)blk*256*384, UPDIM,
          dn_b + blk*DDIM, (void*)h_c, DDIM, 12, 0, 0);
    }

    layernorm_bf16<<<Tci, 256, 0, stream>>>(h_c, post_w, post_b, bufA);
    mfma_gemm<64,96,2,2,3,2><<<dim3(nc/64, 1, KC_PROJ), 256, 0, stream>>>(
        bufA, NS*DDIM, Wtp, NS*DDIM,
        b_proj, (void*)ptmp, PREDN, KCHUNK_PROJ/32, KCHUNK_PROJ, nc);
    proj_out<<<(nc*PREDN + 255)/256, 256, 0, stream>>>(ptmp, b_proj, out, nc, n0);
  }
}

// Round 6
// 1150.047 us; speedup vs baseline: 2.7428x; 1.4520x over previous
//
#include <hip/hip_runtime.h>
#include <stdint.h>

typedef unsigned short u16;
typedef unsigned int   u32;
typedef __attribute__((ext_vector_type(8))) short bf16x8;
typedef __attribute__((ext_vector_type(4))) float f32x4;

#define NS      63
#define NSEQ    1024
#define DDIM    256
#define NHEAD   4
#define DHEAD   64
#define UPDIM   384
#define PREDN   96
#define LLEN    512
#define CCH     32
#define PSIZE   16
#define PSTRIDE 8
#define KC_PROJ 8
#define KCHUNK_PROJ 2016

__device__ __forceinline__ float bf2f(u32 lo16){
  union { u32 i; float f; } v; v.i = lo16 << 16; return v.f;
}
__device__ __forceinline__ float bf2f_hi(u32 u){
  union { u32 i; float f; } v; v.i = u & 0xffff0000u; return v.f;
}
__device__ __forceinline__ u16 f2bf(float f){
  union { u32 i; float f; } v; v.f = f;
  u32 u = v.i; u += 0x7fffu + ((u >> 16) & 1u);
  return (u16)(u >> 16);
}

// async global->LDS, 16B per lane; lds base must be wave-uniform (HW adds lane*16)
__device__ __forceinline__ void gload16(const u16* g, u16* lds){
  __builtin_amdgcn_global_load_lds(
      (const __attribute__((address_space(1))) u32*)g,
      (__attribute__((address_space(3))) u32*)lds, 16, 0, 0);
}

// ---------------- weight convert + transpose: dst[c][r] = bf16(src[r][c]) ----------
__global__ __launch_bounds__(256) void cvt_transpose(
    const float* __restrict__ src, u16* __restrict__ dst, int R, int C){
  int idx = blockIdx.x*256 + threadIdx.x;
  if (idx >= R*C) return;
  int r = idx / C, c = idx - r*C;
  dst[(size_t)c*R + r] = f2bf(src[idx]);
}

// 64x64 per-matrix transpose (Rg -> Rgt)
__global__ __launch_bounds__(256) void cvt_gate(
    const float* __restrict__ src, u16* __restrict__ dst){
  int mat = blockIdx.x, t = threadIdx.x;
  const float* s = src + (size_t)mat*4096;
  u16* d = dst + (size_t)mat*4096;
  for (int i = t; i < 4096; i += 256){
    int r = i >> 6, c = i & 63;
    d[c*64 + r] = f2bf(s[i]);
  }
}

// gate weight, true-K layout: dst[(blk*2+p)*4+hd][n=gl*64+e][k] = Wg[blk][2p+gl][hd][k][e]
__global__ __launch_bounds__(256) void cvt_gateW2(
    const float* __restrict__ Wg, u16* __restrict__ dst){
  int mi = blockIdx.x;                 // 0..15
  int blk = mi >> 3, p = (mi >> 2) & 1, hd = mi & 3;
  u16* d = dst + (size_t)mi*8192;
  for (int i = threadIdx.x; i < 8192; i += 256){
    int n = i >> 6, k = i & 63;
    int gl = n >> 6, e = n & 63;
    int g = 2*p + gl;
    d[i] = f2bf(Wg[((((size_t)blk*4 + g)*4 + hd)*64 + k)*64 + e]);
  }
}

// ---------------- patch embedding + ln1(blk0) fused --------------------------------
__global__ __launch_bounds__(256) void patch_embed_ln(
    const float* __restrict__ x, const float* __restrict__ Wemb,
    const float* __restrict__ bemb, const float* __restrict__ w1,
    const float* __restrict__ b1, float* __restrict__ h,
    u16* __restrict__ outA, int t_base){
  int bid = blockIdx.x, d = threadIdx.x;
  int tg = t_base + bid;
  int n = tg / NS, s = tg - n*NS;
  int b = n >> 5, c = n & 31;
  int l0 = s * PSTRIDE;
  float acc = bemb[d];
  #pragma unroll
  for (int p = 0; p < PSIZE; ++p){
    float xv = x[((size_t)b*LLEN + l0 + p)*CCH + c];
    acc += xv * Wemb[p*DDIM + d];
  }
  h[(size_t)bid*DDIM + d] = acc;
  float s1 = acc, s2 = acc*acc;
  #pragma unroll
  for (int o = 1; o < 64; o <<= 1){ s1 += __shfl_xor(s1, o, 64); s2 += __shfl_xor(s2, o, 64); }
  __shared__ float ws1[4], ws2[4];
  int wid = d >> 6, lane = d & 63;
  if (lane == 0){ ws1[wid] = s1; ws2[wid] = s2; }
  __syncthreads();
  s1 = ws1[0]+ws1[1]+ws1[2]+ws1[3];
  s2 = ws2[0]+ws2[1]+ws2[2]+ws2[3];
  float mu = s1 * (1.f/DDIM);
  float var = s2 * (1.f/DDIM) - mu*mu;
  float rstd = rsqrtf(var + 1e-5f);
  outA[(size_t)bid*DDIM + d] = f2bf((acc - mu)*rstd*w1[d] + b1[d]);
}

// ---------------- layernorm over D=256, fp32 in -> bf16 out ------------------------
__global__ __launch_bounds__(256) void layernorm_bf16(
    const float* __restrict__ in, const float* __restrict__ w,
    const float* __restrict__ b, u16* __restrict__ out){
  int t = blockIdx.x, d = threadIdx.x;
  float v = in[(size_t)t*DDIM + d];
  float s1 = v, s2 = v*v;
  #pragma unroll
  for (int o = 1; o < 64; o <<= 1){ s1 += __shfl_xor(s1, o, 64); s2 += __shfl_xor(s2, o, 64); }
  __shared__ float ws1[4], ws2[4];
  int wid = d >> 6, lane = d & 63;
  if (lane == 0){ ws1[wid] = s1; ws2[wid] = s2; }
  __syncthreads();
  s1 = ws1[0]+ws1[1]+ws1[2]+ws1[3];
  s2 = ws2[0]+ws2[1]+ws2[2]+ws2[3];
  float mu = s1 * (1.f/DDIM);
  float var = s2 * (1.f/DDIM) - mu*mu;
  float rstd = rsqrtf(var + 1e-5f);
  out[(size_t)t*DDIM + d] = f2bf((v - mu)*rstd*w[d] + b[d]);
}

// ---------------- fused groupnorm + residual + layernorm ---------------------------
__global__ __launch_bounds__(256) void gn_res_ln(
    const u16* __restrict__ y, const float* __restrict__ gnw,
    const float* __restrict__ w2, const float* __restrict__ b2,
    float* __restrict__ h, u16* __restrict__ outA){
  int t = blockIdx.x, d = threadIdx.x;
  float v = bf2f(y[(size_t)t*DDIM + d]);
  float s1 = v, s2 = v*v;
  #pragma unroll
  for (int o = 1; o < 64; o <<= 1){ s1 += __shfl_xor(s1, o, 64); s2 += __shfl_xor(s2, o, 64); }
  float mu64 = s1*(1.f/64.f);
  float var64 = s2*(1.f/64.f) - mu64*mu64;
  float yn = (v - mu64)*rsqrtf(var64 + 1e-5f)*gnw[d];
  float hn = h[(size_t)t*DDIM + d] + yn;
  h[(size_t)t*DDIM + d] = hn;
  float t1 = hn, t2 = hn*hn;
  #pragma unroll
  for (int o = 1; o < 64; o <<= 1){ t1 += __shfl_xor(t1, o, 64); t2 += __shfl_xor(t2, o, 64); }
  __shared__ float ws1[4], ws2[4];
  int wid = d >> 6, lane = d & 63;
  if (lane == 0){ ws1[wid] = t1; ws2[wid] = t2; }
  __syncthreads();
  t1 = ws1[0]+ws1[1]+ws1[2]+ws1[3];
  t2 = ws2[0]+ws2[1]+ws2[2]+ws2[3];
  float mu = t1*(1.f/DDIM);
  float var = t2*(1.f/DDIM) - mu*mu;
  float rstd = rsqrtf(var + 1e-5f);
  outA[(size_t)t*DDIM + d] = f2bf((hn - mu)*rstd*w2[d] + b2[d]);
}

// ---------------- causal depthwise conv K=4 + SiLU ---------------------------------
__global__ __launch_bounds__(256) void conv_silu(
    const u16* __restrict__ xln, const float* __restrict__ cw,
    const float* __restrict__ cb, u16* __restrict__ xc, int t_base){
  int bid = blockIdx.x, d = threadIdx.x;
  int tg = t_base + bid;
  int n = tg / NS, s = tg - n*NS;
  float acc = cb[d];
  #pragma unroll
  for (int k = 0; k < 4; ++k){
    int ss = s + k - 3;
    if (ss >= 0) acc += bf2f(xln[(size_t)(bid + k - 3)*DDIM + d]) * cw[k*DDIM + d];
  }
  float sig = 1.f/(1.f + __expf(-acc));
  xc[(size_t)bid*DDIM + d] = f2bf(acc*sig);
}

// ---------------- generic MFMA GEMM, global_load_lds 2-phase -----------------------
// MODE 1: fp32 out += acc + bias;  MODE 2: fp32 ptmp[(kc*Mtot+row)*ldo+col] = acc
template<int BM,int BN,int WR,int WC,int MR,int NR,int MODE>
__global__ __launch_bounds__(256) void mfma_gemm2(
    const u16* __restrict__ A, int lda,
    const u16* __restrict__ Wt, int ldwt,
    const float* __restrict__ bias, void* __restrict__ outp, int ldo,
    int ksteps, int kchunk, int Mtot)
{
  constexpr int nA = BM/16, nW = BN/16;
  __shared__ u16 As[2][BM*32];
  __shared__ u16 Ws[2][BN*32];
  const int tid = threadIdx.x;
  const int lane = tid & 63, wid = tid >> 6;
  const int wr = wid / WC, wc = wid % WC;
  const int fr = lane & 15, kb = lane >> 4;
  const int m0 = blockIdx.x*BM, n0 = blockIdx.y*BN;
  const int kc = blockIdx.z;
  const int kbeg = kc*kchunk;
  const u16* Ab = A + (size_t)m0*lda + kbeg;
  const u16* Wb = Wt + (size_t)n0*ldwt + kbeg;
  const int lrow = lane >> 2, lcol = (lane & 3)*8;

  auto stage = [&](int buf, int ks){
    int k0 = ks*32;
    for (int c = wid; c < nA; c += 4)
      gload16(Ab + (size_t)(c*16 + lrow)*lda + k0 + lcol, &As[buf][c*512]);
    for (int c = wid; c < nW; c += 4)
      gload16(Wb + (size_t)(c*16 + lrow)*ldwt + k0 + lcol, &Ws[buf][c*512]);
  };

  f32x4 acc[MR][NR];
  #pragma unroll
  for (int m=0;m<MR;++m)
    #pragma unroll
    for (int n=0;n<NR;++n) acc[m][n] = (f32x4){0.f,0.f,0.f,0.f};

  stage(0, 0);
  __syncthreads();
  int cur = 0;
  for (int ks = 0; ks < ksteps; ++ks){
    if (ks + 1 < ksteps) stage(cur^1, ks+1);
    bf16x8 af[MR], wf[NR];
    #pragma unroll
    for (int m=0;m<MR;++m)
      af[m] = *(const bf16x8*)&As[cur][(wr*MR*16 + m*16 + fr)*32 + kb*8];
    #pragma unroll
    for (int n=0;n<NR;++n)
      wf[n] = *(const bf16x8*)&Ws[cur][(wc*NR*16 + n*16 + fr)*32 + kb*8];
    #pragma unroll
    for (int m=0;m<MR;++m)
      #pragma unroll
      for (int n=0;n<NR;++n)
        acc[m][n] = __builtin_amdgcn_mfma_f32_16x16x32_bf16(af[m], wf[n], acc[m][n], 0,0,0);
    __syncthreads();
    cur ^= 1;
  }
  #pragma unroll
  for (int m=0;m<MR;++m){
    int rowb = m0 + wr*MR*16 + m*16 + kb*4;
    #pragma unroll
    for (int n=0;n<NR;++n){
      int col = n0 + wc*NR*16 + n*16 + fr;
      #pragma unroll
      for (int r=0;r<4;++r){
        int row = rowb + r;
        float v = acc[m][n][r];
        if (MODE == 1){
          ((float*)outp)[(size_t)row*ldo + col] += v + bias[col];
        } else {
          ((float*)outp)[((size_t)kc*Mtot + row)*ldo + col] = v;
        }
      }
    }
  }
}

// ---------------- gate GEMM, true K=64 per (pair,head) -----------------------------
// out col phys = hd*256 + p*128 + e*2 + gl ; bias gb[(2p+gl)*256 + hd*64 + e]
__global__ __launch_bounds__(256) void mfma_gate2(
    const u16* __restrict__ xc, const u16* __restrict__ xh,
    const u16* __restrict__ Wg2, const float* __restrict__ gb,
    u16* __restrict__ gates)
{
  __shared__ u16 As[2][128*32];
  __shared__ u16 Ws[2][128*32];
  const int tid = threadIdx.x;
  const int lane = tid & 63, wid = tid >> 6;
  const int wr = wid >> 1, wc = wid & 1;
  const int fr = lane & 15, kb = lane >> 4;
  const int p = blockIdx.y >> 2, hd = blockIdx.y & 3;
  const int m0 = blockIdx.x*128;
  const u16* Ain = (p == 0) ? xc : xh;
  const u16* Wb = Wg2 + (size_t)blockIdx.y*8192;    // [128][64]
  const int lrow = lane >> 2, lcol = (lane & 3)*8;

  auto stage = [&](int buf, int ks){
    int k0 = ks*32;
    for (int c = wid; c < 8; c += 4)
      gload16(Ain + (size_t)(m0 + c*16 + lrow)*DDIM + hd*64 + k0 + lcol, &As[buf][c*512]);
    for (int c = wid; c < 8; c += 4)
      gload16(Wb + (size_t)(c*16 + lrow)*64 + k0 + lcol, &Ws[buf][c*512]);
  };

  f32x4 acc[4][4];
  #pragma unroll
  for (int m=0;m<4;++m)
    #pragma unroll
    for (int n=0;n<4;++n) acc[m][n] = (f32x4){0.f,0.f,0.f,0.f};

  stage(0, 0);
  __syncthreads();
  int cur = 0;
  #pragma unroll
  for (int ks = 0; ks < 2; ++ks){
    if (ks == 0) stage(1, 1);
    bf16x8 af[4], wf[4];
    #pragma unroll
    for (int m=0;m<4;++m)
      af[m] = *(const bf16x8*)&As[cur][(wr*64 + m*16 + fr)*32 + kb*8];
    #pragma unroll
    for (int n=0;n<4;++n)
      wf[n] = *(const bf16x8*)&Ws[cur][(wc*64 + n*16 + fr)*32 + kb*8];
    #pragma unroll
    for (int m=0;m<4;++m)
      #pragma unroll
      for (int n=0;n<4;++n)
        acc[m][n] = __builtin_amdgcn_mfma_f32_16x16x32_bf16(af[m], wf[n], acc[m][n], 0,0,0);
    __syncthreads();
    cur ^= 1;
  }
  #pragma unroll
  for (int m=0;m<4;++m){
    int rowb = m0 + wr*64 + m*16 + kb*4;
    #pragma unroll
    for (int n=0;n<4;++n){
      int cl = wc*64 + n*16 + fr;
      int gl = cl >> 6, e = cl & 63;
      float bv = gb[(2*p + gl)*256 + hd*64 + e];
      int phys = hd*256 + p*128 + e*2 + gl;
      #pragma unroll
      for (int r=0;r<4;++r)
        gates[(size_t)(rowb + r)*1024 + phys] = f2bf(acc[m][n][r] + bv);
    }
  }
}

// ---------------- FFN up + gelu*g2 fused, global_load_lds 2-phase ------------------
__global__ __launch_bounds__(256) void mfma_up_gelu2(
    const u16* __restrict__ A, const u16* __restrict__ Wt,
    const float* __restrict__ ub, u16* __restrict__ gp)
{
  __shared__ u16 As[2][128*32];
  __shared__ u16 Ws[2][128*32];   // rows 0-63: g1 slice; rows 64-127: g2 slice
  const int tid = threadIdx.x;
  const int lane = tid & 63, wid = tid >> 6;
  const int wr = wid >> 1, wc = wid & 1;
  const int fr = lane & 15, kb = lane >> 4;
  const int m0 = blockIdx.x*128, n0 = blockIdx.y*64;
  const u16* W1 = Wt + (size_t)n0*256;
  const u16* W2 = Wt + (size_t)(384 + n0)*256;
  const int lrow = lane >> 2, lcol = (lane & 3)*8;

  auto stage = [&](int buf, int ks){
    int k0 = ks*32;
    for (int c = wid; c < 8; c += 4)
      gload16(A + (size_t)(m0 + c*16 + lrow)*256 + k0 + lcol, &As[buf][c*512]);
    for (int c = wid; c < 8; c += 4){
      const u16* src = (c < 4) ? (W1 + (size_t)(c*16 + lrow)*256)
                               : (W2 + (size_t)((c-4)*16 + lrow)*256);
      gload16(src + k0 + lcol, &Ws[buf][c*512]);
    }
  };

  f32x4 a1[4][2], a2[4][2];
  #pragma unroll
  for (int m=0;m<4;++m)
    #pragma unroll
    for (int n=0;n<2;++n){ a1[m][n]=(f32x4){0,0,0,0}; a2[m][n]=(f32x4){0,0,0,0}; }

  stage(0, 0);
  __syncthreads();
  int cur = 0;
  #pragma unroll
  for (int ks = 0; ks < 8; ++ks){
    if (ks + 1 < 8) stage(cur^1, ks+1);
    bf16x8 af[4], wf1[2], wf2[2];
    #pragma unroll
    for (int m=0;m<4;++m)
      af[m] = *(const bf16x8*)&As[cur][(wr*64 + m*16 + fr)*32 + kb*8];
    #pragma unroll
    for (int n=0;n<2;++n){
      wf1[n] = *(const bf16x8*)&Ws[cur][(wc*32 + n*16 + fr)*32 + kb*8];
      wf2[n] = *(const bf16x8*)&Ws[cur][(64 + wc*32 + n*16 + fr)*32 + kb*8];
    }
    #pragma unroll
    for (int m=0;m<4;++m)
      #pragma unroll
      for (int n=0;n<2;++n){
        a1[m][n] = __builtin_amdgcn_mfma_f32_16x16x32_bf16(af[m], wf1[n], a1[m][n], 0,0,0);
        a2[m][n] = __builtin_amdgcn_mfma_f32_16x16x32_bf16(af[m], wf2[n], a2[m][n], 0,0,0);
      }
    __syncthreads();
    cur ^= 1;
  }
  #pragma unroll
  for (int m=0;m<4;++m){
    int rowb = m0 + wr*64 + m*16 + kb*4;
    #pragma unroll
    for (int n=0;n<2;++n){
      int col = n0 + wc*32 + n*16 + fr;
      float b1 = ub[col], b2 = ub[384 + col];
      #pragma unroll
      for (int r=0;r<4;++r){
        float g1 = a1[m][n][r] + b1;
        float g2 = a2[m][n][r] + b2;
        float x3 = g1*g1*g1;
        float tv = tanhf(0.7978845608028654f*(g1 + 0.044715f*x3));
        float ge = 0.5f*g1*(1.f + tv);
        gp[(size_t)(rowb + r)*UPDIM + col] = f2bf(ge*g2);
      }
    }
  }
}

// ---------------- sLSTM scan v3 (unchanged) ----------------------------------------
__global__ __launch_bounds__(256) void slstm_scan3(
    const u16* __restrict__ gates, const u16* __restrict__ Rgt,
    u16* __restrict__ y)
{
  __shared__ u16 h_lds[16*72];
  __shared__ float rec_lds[4][16][68];
  const int tid = threadIdx.x;
  const int w = tid >> 6, lane = tid & 63;
  const int hd = blockIdx.y, grp = blockIdx.x;
  const int fr = lane & 15, kb = lane >> 4;
  const int seq0 = grp*16;
  const u32* g32 = (const u32*)gates;

  bf16x8 bfr[4][2];
  {
    const u16* rb = Rgt + (size_t)(w*NHEAD + hd)*4096;
    #pragma unroll
    for (int n=0;n<4;++n)
      #pragma unroll
      for (int ks=0;ks<2;++ks)
        bfr[n][ks] = *(const bf16x8*)(rb + (size_t)(n*16 + fr)*64 + ks*32 + kb*8);
  }
  for (int i = tid; i < 16*72/2; i += 256) ((u32*)h_lds)[i] = 0u;
  float c[4]={0,0,0,0}, nst[4]={0,0,0,0}, m[4]={0,0,0,0};

  u32 gcur[4][2];
  #pragma unroll
  for (int si=0; si<4; ++si){
    size_t base = ((size_t)(seq0 + 4*w + si)*NS)*512 + hd*128 + lane;
    gcur[si][0] = g32[base];
    gcur[si][1] = g32[base + 64];
  }
  __syncthreads();

  for (int s = 0; s < NS; ++s){
    u32 gnxt[4][2];
    if (s + 1 < NS){
      #pragma unroll
      for (int si=0; si<4; ++si){
        size_t base = ((size_t)(seq0 + 4*w + si)*NS + s + 1)*512 + hd*128 + lane;
        gnxt[si][0] = g32[base];
        gnxt[si][1] = g32[base + 64];
      }
    }
    bf16x8 af0 = *(const bf16x8*)&h_lds[fr*72 + kb*8];
    bf16x8 af1 = *(const bf16x8*)&h_lds[fr*72 + 32 + kb*8];
    f32x4 acc[4];
    #pragma unroll
    for (int n=0;n<4;++n){
      acc[n] = (f32x4){0,0,0,0};
      acc[n] = __builtin_amdgcn_mfma_f32_16x16x32_bf16(af0, bfr[n][0], acc[n], 0,0,0);
      acc[n] = __builtin_amdgcn_mfma_f32_16x16x32_bf16(af1, bfr[n][1], acc[n], 0,0,0);
    }
    #pragma unroll
    for (int n=0;n<4;++n)
      #pragma unroll
      for (int r=0;r<4;++r)
        rec_lds[w][kb*4 + r][n*16 + fr] = acc[n][r];
    __syncthreads();
    #pragma unroll
    for (int si=0; si<4; ++si){
      int sidx = 4*w + si;
      float ip = rec_lds[0][sidx][lane] + bf2f(gcur[si][0] & 0xffffu);
      float fp = rec_lds[1][sidx][lane] + bf2f_hi(gcur[si][0]);
      float zp = rec_lds[2][sidx][lane] + bf2f(gcur[si][1] & 0xffffu);
      float op = rec_lds[3][sidx][lane] + bf2f_hi(gcur[si][1]);
      float sp  = __logf(1.f + __expf(-fabsf(fp)));
      float lg  = m[si] + fminf(fp, 0.f) - sp;
      float mn  = fmaxf(ip, lg);
      float iv  = __expf(ip - mn);
      float fv  = __expf(lg - mn);
      float zz  = fminf(fabsf(zp), 15.f);
      float t2  = __expf(zz + zz);
      float tha = (t2 - 1.f)/(t2 + 1.f);
      float th  = (zp >= 0.f) ? tha : -tha;
      c[si]   = fv*c[si] + iv*th;
      nst[si] = fv*nst[si] + iv;
      m[si]   = mn;
      float hv = c[si] * __builtin_amdgcn_rcpf(nst[si]*(1.f + __expf(-op)));
      h_lds[sidx*72 + lane] = f2bf(hv);
      size_t t = (size_t)(seq0 + sidx)*NS + s;
      y[t*DDIM + hd*64 + lane] = f2bf(hv);
    }
    __syncthreads();
    #pragma unroll
    for (int si=0; si<4; ++si){ gcur[si][0] = gnxt[si][0]; gcur[si][1] = gnxt[si][1]; }
  }
}

// ---------------- proj reduce over K-split slices ----------------------------------
__global__ __launch_bounds__(256) void proj_out(
    const float* __restrict__ ptmp, const float* __restrict__ bproj,
    float* __restrict__ out, int Nc, int n0glob){
  int gid = blockIdx.x*256 + threadIdx.x;
  if (gid >= Nc*PREDN) return;
  float acc = 0.f;
  #pragma unroll
  for (int kc = 0; kc < KC_PROJ; ++kc) acc += ptmp[(size_t)kc*Nc*PREDN + gid];
  int nl = gid / PREDN, j = gid - nl*PREDN;
  int n = n0glob + nl;
  out[((size_t)(n >> 5)*PREDN + j)*CCH + (n & 31)] = acc + bproj[j];
}

extern "C" void kernel_launch(void* const* d_in, const int* in_sizes, int n_in,
                              void* d_out, int out_size, void* d_ws, size_t ws_size,
                              hipStream_t stream) {
  const float* x      = (const float*)d_in[0];
  const float* W_emb  = (const float*)d_in[1];
  const float* b_emb  = (const float*)d_in[2];
  const float* ln1_w  = (const float*)d_in[3];
  const float* ln1_b  = (const float*)d_in[4];
  const float* conv_w = (const float*)d_in[5];
  const float* conv_b = (const float*)d_in[6];
  const float* Wg     = (const float*)d_in[7];
  const float* Rg     = (const float*)d_in[8];
  const float* gb     = (const float*)d_in[9];
  const float* gn_w   = (const float*)d_in[10];
  const float* ln2_w  = (const float*)d_in[11];
  const float* ln2_b  = (const float*)d_in[12];
  const float* up_w   = (const float*)d_in[13];
  const float* up_b   = (const float*)d_in[14];
  const float* dn_w   = (const float*)d_in[15];
  const float* dn_b   = (const float*)d_in[16];
  const float* post_w = (const float*)d_in[17];
  const float* post_b = (const float*)d_in[18];
  const float* W_proj = (const float*)d_in[19];
  const float* b_proj = (const float*)d_in[20];
  float* out = (float*)d_out;

  // ---- workspace layout ----
  const size_t oWu   = 0;          // [2][768][256] bf16 : 1,572,864
  const size_t oWd   = 1572864;    // [2][256][384] bf16 :   786,432
  const size_t oWg2  = 2359296;    // [2][8][128][64] bf16 :  262,144
  const size_t oRgt  = 2621440;    // [2][16][64][64] bf16 :  524,288
  const size_t oWp   = 3145728;    // [96][16128] bf16 : 3,096,576
  const size_t oChunk = 6242304;
  const size_t per_seq = 268800;
  int Nc = 0;
  const int cands[4] = {1024, 512, 256, 128};
  for (int i = 0; i < 4; ++i)
    if (oChunk + (size_t)cands[i]*per_seq <= ws_size){ Nc = cands[i]; break; }
  if (Nc == 0) return;

  char* wsb = (char*)d_ws;
  u16* Wu   = (u16*)(wsb + oWu);
  u16* Wd   = (u16*)(wsb + oWd);
  u16* Wg2  = (u16*)(wsb + oWg2);
  u16* Rgt  = (u16*)(wsb + oRgt);
  u16* Wtp  = (u16*)(wsb + oWp);

  for (int blk = 0; blk < 2; ++blk){
    cvt_transpose<<<(256*768+255)/256, 256, 0, stream>>>(
        up_w + (size_t)blk*256*768, Wu + (size_t)blk*768*256, 256, 768);
    cvt_transpose<<<(384*256+255)/256, 256, 0, stream>>>(
        dn_w + (size_t)blk*384*256, Wd + (size_t)blk*256*384, 384, 256);
  }
  cvt_gateW2<<<16, 256, 0, stream>>>(Wg, Wg2);
  cvt_gate<<<32, 256, 0, stream>>>(Rg, Rgt);
  cvt_transpose<<<(16128*96+255)/256, 256, 0, stream>>>(W_proj, Wtp, 16128, 96);

  for (int n0 = 0; n0 < NSEQ; n0 += Nc){
    const int    nc  = Nc;
    const size_t Tc  = (size_t)nc * NS;
    char* cb = wsb + oChunk;
    float* h_c   = (float*)cb;                        // Tc*1024 B
    u16*   bufA  = (u16*)(cb + Tc*1024);              // Tc*512 B
    u16*   bufB  = (u16*)(cb + Tc*1536);              // Tc*512 B
    u16*   gates = (u16*)(cb + Tc*2048);              // Tc*2048 B ([t][1024])
    float* ptmp  = (float*)(cb + Tc*4096);            // nc*KC_PROJ*96*4 B
    u16*   gp    = gates;                             // reuse after scan (Tc*768 B)
    const int t_base = n0*NS;
    const int Tci = (int)Tc;

    patch_embed_ln<<<Tci, 256, 0, stream>>>(
        x, W_emb, b_emb, ln1_w, ln1_b, h_c, bufA, t_base);

    for (int blk = 0; blk < 2; ++blk){
      if (blk == 1)
        layernorm_bf16<<<Tci, 256, 0, stream>>>(h_c, ln1_w + DDIM, ln1_b + DDIM, bufA);
      conv_silu<<<Tci, 256, 0, stream>>>(bufA, conv_w + blk*4*DDIM, conv_b + blk*DDIM, bufB, t_base);
      mfma_gate2<<<dim3(Tci/128, 8), 256, 0, stream>>>(
          bufB, bufA, Wg2 + (size_t)blk*8*8192, gb + blk*4*DDIM, gates);
      slstm_scan3<<<dim3(nc/16, NHEAD), 256, 0, stream>>>(
          gates, Rgt + (size_t)blk*16*4096, bufB);
      gn_res_ln<<<Tci, 256, 0, stream>>>(
          bufB, gn_w + blk*DDIM, ln2_w + blk*DDIM, ln2_b + blk*DDIM, h_c, bufA);
      mfma_up_gelu2<<<dim3(Tci/128, 6), 256, 0, stream>>>(
          bufA, Wu + (size_t)blk*768*256, up_b + blk*2*UPDIM, gp);
      mfma_gemm2<128,128,2,2,4,4,1><<<dim3(Tci/128, 2), 256, 0, stream>>>(
          gp, UPDIM, Wd + (size_t)blk*256*384, UPDIM,
          dn_b + blk*DDIM, (void*)h_c, DDIM, 12, 0, 0);
    }

    layernorm_bf16<<<Tci, 256, 0, stream>>>(h_c, post_w, post_b, bufA);
    mfma_gemm2<64,96,2,2,2,3,2><<<dim3(nc/64, 1, KC_PROJ), 256, 0, stream>>>(
        bufA, NS*DDIM, Wtp, NS*DDIM,
        b_proj, (void*)ptmp, PREDN, KCHUNK_PROJ/32, KCHUNK_PROJ, nc);
    proj_out<<<(nc*PREDN + 255)/256, 256, 0, stream>>>(ptmp, b_proj, out, nc, n0);
  }
}

// Round 7
// 908.337 us; speedup vs baseline: 3.4726x; 1.2661x over previous
//
#include <hip/hip_runtime.h>
#include <stdint.h>

typedef unsigned short u16;
typedef unsigned int   u32;
typedef __attribute__((ext_vector_type(8))) short bf16x8;
typedef __attribute__((ext_vector_type(4))) float f32x4;

#define NS      63
#define NSEQ    1024
#define DDIM    256
#define NHEAD   4
#define DHEAD   64
#define UPDIM   384
#define PREDN   96
#define LLEN    512
#define CCH     32
#define PSIZE   16
#define PSTRIDE 8
#define KC_PROJ 8
#define KCHUNK_PROJ 2016

__device__ __forceinline__ float bf2f(u32 lo16){
  union { u32 i; float f; } v; v.i = lo16 << 16; return v.f;
}
__device__ __forceinline__ float bf2f_hi(u32 u){
  union { u32 i; float f; } v; v.i = u & 0xffff0000u; return v.f;
}
__device__ __forceinline__ u16 f2bf(float f){
  union { u32 i; float f; } v; v.f = f;
  u32 u = v.i; u += 0x7fffu + ((u >> 16) & 1u);
  return (u16)(u >> 16);
}

// async global->LDS, 16B per lane; lds base wave-uniform (HW adds lane*16)
__device__ __forceinline__ void gload16(const u16* g, u16* lds){
  __builtin_amdgcn_global_load_lds(
      (const __attribute__((address_space(1))) u32*)g,
      (__attribute__((address_space(3))) u32*)lds, 16, 0, 0);
}

// ---------------- weight convert + transpose ---------------------------------------
__global__ __launch_bounds__(256) void cvt_transpose(
    const float* __restrict__ src, u16* __restrict__ dst, int R, int C){
  int idx = blockIdx.x*256 + threadIdx.x;
  if (idx >= R*C) return;
  int r = idx / C, c = idx - r*C;
  dst[(size_t)c*R + r] = f2bf(src[idx]);
}

__global__ __launch_bounds__(256) void cvt_gate(
    const float* __restrict__ src, u16* __restrict__ dst){
  int mat = blockIdx.x, t = threadIdx.x;
  const float* s = src + (size_t)mat*4096;
  u16* d = dst + (size_t)mat*4096;
  for (int i = t; i < 4096; i += 256){
    int r = i >> 6, c = i & 63;
    d[c*64 + r] = f2bf(s[i]);
  }
}

// gate weight true-K layout: dst[(blk*2+p)*4+hd][n=gl*64+e][k]
__global__ __launch_bounds__(256) void cvt_gateW2(
    const float* __restrict__ Wg, u16* __restrict__ dst){
  int mi = blockIdx.x;
  int blk = mi >> 3, p = (mi >> 2) & 1, hd = mi & 3;
  u16* d = dst + (size_t)mi*8192;
  for (int i = threadIdx.x; i < 8192; i += 256){
    int n = i >> 6, k = i & 63;
    int gl = n >> 6, e = n & 63;
    int g = 2*p + gl;
    d[i] = f2bf(Wg[((((size_t)blk*4 + g)*4 + hd)*64 + k)*64 + e]);
  }
}

// ---------------- patch embedding + ln1(blk0) fused, h bf16 ------------------------
__global__ __launch_bounds__(256) void patch_embed_ln(
    const float* __restrict__ x, const float* __restrict__ Wemb,
    const float* __restrict__ bemb, const float* __restrict__ w1,
    const float* __restrict__ b1, u16* __restrict__ h,
    u16* __restrict__ outA, int t_base){
  int bid = blockIdx.x, d = threadIdx.x;
  int tg = t_base + bid;
  int n = tg / NS, s = tg - n*NS;
  int b = n >> 5, c = n & 31;
  int l0 = s * PSTRIDE;
  float acc = bemb[d];
  #pragma unroll
  for (int p = 0; p < PSIZE; ++p){
    float xv = x[((size_t)b*LLEN + l0 + p)*CCH + c];
    acc += xv * Wemb[p*DDIM + d];
  }
  h[(size_t)bid*DDIM + d] = f2bf(acc);
  float s1 = acc, s2 = acc*acc;
  #pragma unroll
  for (int o = 1; o < 64; o <<= 1){ s1 += __shfl_xor(s1, o, 64); s2 += __shfl_xor(s2, o, 64); }
  __shared__ float ws1[4], ws2[4];
  int wid = d >> 6, lane = d & 63;
  if (lane == 0){ ws1[wid] = s1; ws2[wid] = s2; }
  __syncthreads();
  s1 = ws1[0]+ws1[1]+ws1[2]+ws1[3];
  s2 = ws2[0]+ws2[1]+ws2[2]+ws2[3];
  float mu = s1 * (1.f/DDIM);
  float var = s2 * (1.f/DDIM) - mu*mu;
  float rstd = rsqrtf(var + 1e-5f);
  outA[(size_t)bid*DDIM + d] = f2bf((acc - mu)*rstd*w1[d] + b1[d]);
}

// ---------------- layernorm over D=256, bf16 in -> bf16 out ------------------------
__global__ __launch_bounds__(256) void layernorm_bf16(
    const u16* __restrict__ in, const float* __restrict__ w,
    const float* __restrict__ b, u16* __restrict__ out){
  int t = blockIdx.x, d = threadIdx.x;
  float v = bf2f(in[(size_t)t*DDIM + d]);
  float s1 = v, s2 = v*v;
  #pragma unroll
  for (int o = 1; o < 64; o <<= 1){ s1 += __shfl_xor(s1, o, 64); s2 += __shfl_xor(s2, o, 64); }
  __shared__ float ws1[4], ws2[4];
  int wid = d >> 6, lane = d & 63;
  if (lane == 0){ ws1[wid] = s1; ws2[wid] = s2; }
  __syncthreads();
  s1 = ws1[0]+ws1[1]+ws1[2]+ws1[3];
  s2 = ws2[0]+ws2[1]+ws2[2]+ws2[3];
  float mu = s1 * (1.f/DDIM);
  float var = s2 * (1.f/DDIM) - mu*mu;
  float rstd = rsqrtf(var + 1e-5f);
  out[(size_t)t*DDIM + d] = f2bf((v - mu)*rstd*w[d] + b[d]);
}

// ---------------- fused groupnorm + residual + layernorm (h bf16) ------------------
__global__ __launch_bounds__(256) void gn_res_ln(
    const u16* __restrict__ y, const float* __restrict__ gnw,
    const float* __restrict__ w2, const float* __restrict__ b2,
    u16* __restrict__ h, u16* __restrict__ outA){
  int t = blockIdx.x, d = threadIdx.x;
  float v = bf2f(y[(size_t)t*DDIM + d]);
  float s1 = v, s2 = v*v;
  #pragma unroll
  for (int o = 1; o < 64; o <<= 1){ s1 += __shfl_xor(s1, o, 64); s2 += __shfl_xor(s2, o, 64); }
  float mu64 = s1*(1.f/64.f);
  float var64 = s2*(1.f/64.f) - mu64*mu64;
  float yn = (v - mu64)*rsqrtf(var64 + 1e-5f)*gnw[d];
  float hn = bf2f(h[(size_t)t*DDIM + d]) + yn;
  h[(size_t)t*DDIM + d] = f2bf(hn);
  float t1 = hn, t2 = hn*hn;
  #pragma unroll
  for (int o = 1; o < 64; o <<= 1){ t1 += __shfl_xor(t1, o, 64); t2 += __shfl_xor(t2, o, 64); }
  __shared__ float ws1[4], ws2[4];
  int wid = d >> 6, lane = d & 63;
  if (lane == 0){ ws1[wid] = t1; ws2[wid] = t2; }
  __syncthreads();
  t1 = ws1[0]+ws1[1]+ws1[2]+ws1[3];
  t2 = ws2[0]+ws2[1]+ws2[2]+ws2[3];
  float mu = t1*(1.f/DDIM);
  float var = t2*(1.f/DDIM) - mu*mu;
  float rstd = rsqrtf(var + 1e-5f);
  outA[(size_t)t*DDIM + d] = f2bf((hn - mu)*rstd*w2[d] + b2[d]);
}

// ---------------- causal depthwise conv K=4 + SiLU ---------------------------------
__global__ __launch_bounds__(256) void conv_silu(
    const u16* __restrict__ xln, const float* __restrict__ cw,
    const float* __restrict__ cb, u16* __restrict__ xc, int t_base){
  int bid = blockIdx.x, d = threadIdx.x;
  int tg = t_base + bid;
  int n = tg / NS, s = tg - n*NS;
  float acc = cb[d];
  #pragma unroll
  for (int k = 0; k < 4; ++k){
    int ss = s + k - 3;
    if (ss >= 0) acc += bf2f(xln[(size_t)(bid + k - 3)*DDIM + d]) * cw[k*DDIM + d];
  }
  float sig = 1.f/(1.f + __expf(-acc));
  xc[(size_t)bid*DDIM + d] = f2bf(acc*sig);
}

// ---------------- generic MFMA GEMM, global_load_lds 2-phase -----------------------
// MODE 1: bf16 out += acc + bias (RMW);  MODE 2: fp32 ptmp[(kc*Mtot+row)*ldo+col]=acc
template<int BM,int BN,int WR,int WC,int MR,int NR,int MODE>
__global__ __launch_bounds__(256) void mfma_gemm2(
    const u16* __restrict__ A, int lda,
    const u16* __restrict__ Wt, int ldwt,
    const float* __restrict__ bias, void* __restrict__ outp, int ldo,
    int ksteps, int kchunk, int Mtot)
{
  constexpr int nA = BM/16, nW = BN/16;
  __shared__ u16 As[2][BM*32];
  __shared__ u16 Ws[2][BN*32];
  const int tid = threadIdx.x;
  const int lane = tid & 63, wid = tid >> 6;
  const int wr = wid / WC, wc = wid % WC;
  const int fr = lane & 15, kb = lane >> 4;
  const int m0 = blockIdx.x*BM, n0 = blockIdx.y*BN;
  const int kc = blockIdx.z;
  const int kbeg = kc*kchunk;
  const u16* Ab = A + (size_t)m0*lda + kbeg;
  const u16* Wb = Wt + (size_t)n0*ldwt + kbeg;
  const int lrow = lane >> 2, lcol = (lane & 3)*8;

  auto stage = [&](int buf, int ks){
    int k0 = ks*32;
    for (int c = wid; c < nA; c += 4)
      gload16(Ab + (size_t)(c*16 + lrow)*lda + k0 + lcol, &As[buf][c*512]);
    for (int c = wid; c < nW; c += 4)
      gload16(Wb + (size_t)(c*16 + lrow)*ldwt + k0 + lcol, &Ws[buf][c*512]);
  };

  f32x4 acc[MR][NR];
  #pragma unroll
  for (int m=0;m<MR;++m)
    #pragma unroll
    for (int n=0;n<NR;++n) acc[m][n] = (f32x4){0.f,0.f,0.f,0.f};

  stage(0, 0);
  __syncthreads();
  int cur = 0;
  for (int ks = 0; ks < ksteps; ++ks){
    if (ks + 1 < ksteps) stage(cur^1, ks+1);
    bf16x8 af[MR], wf[NR];
    #pragma unroll
    for (int m=0;m<MR;++m)
      af[m] = *(const bf16x8*)&As[cur][(wr*MR*16 + m*16 + fr)*32 + kb*8];
    #pragma unroll
    for (int n=0;n<NR;++n)
      wf[n] = *(const bf16x8*)&Ws[cur][(wc*NR*16 + n*16 + fr)*32 + kb*8];
    #pragma unroll
    for (int m=0;m<MR;++m)
      #pragma unroll
      for (int n=0;n<NR;++n)
        acc[m][n] = __builtin_amdgcn_mfma_f32_16x16x32_bf16(af[m], wf[n], acc[m][n], 0,0,0);
    __syncthreads();
    cur ^= 1;
  }
  #pragma unroll
  for (int m=0;m<MR;++m){
    int rowb = m0 + wr*MR*16 + m*16 + kb*4;
    #pragma unroll
    for (int n=0;n<NR;++n){
      int col = n0 + wc*NR*16 + n*16 + fr;
      #pragma unroll
      for (int r=0;r<4;++r){
        int row = rowb + r;
        float v = acc[m][n][r];
        if (MODE == 1){
          u16* dst = (u16*)outp + (size_t)row*ldo + col;
          *dst = f2bf(bf2f(*dst) + v + bias[col]);
        } else {
          ((float*)outp)[((size_t)kc*Mtot + row)*ldo + col] = v;
        }
      }
    }
  }
}

// ---------------- gate GEMM, true K=64 per (pair,head) -----------------------------
__global__ __launch_bounds__(256) void mfma_gate2(
    const u16* __restrict__ xc, const u16* __restrict__ xh,
    const u16* __restrict__ Wg2, const float* __restrict__ gb,
    u16* __restrict__ gates)
{
  __shared__ u16 As[2][128*32];
  __shared__ u16 Ws[2][128*32];
  const int tid = threadIdx.x;
  const int lane = tid & 63, wid = tid >> 6;
  const int wr = wid >> 1, wc = wid & 1;
  const int fr = lane & 15, kb = lane >> 4;
  const int p = blockIdx.y >> 2, hd = blockIdx.y & 3;
  const int m0 = blockIdx.x*128;
  const u16* Ain = (p == 0) ? xc : xh;
  const u16* Wb = Wg2 + (size_t)blockIdx.y*8192;
  const int lrow = lane >> 2, lcol = (lane & 3)*8;

  auto stage = [&](int buf, int ks){
    int k0 = ks*32;
    for (int c = wid; c < 8; c += 4)
      gload16(Ain + (size_t)(m0 + c*16 + lrow)*DDIM + hd*64 + k0 + lcol, &As[buf][c*512]);
    for (int c = wid; c < 8; c += 4)
      gload16(Wb + (size_t)(c*16 + lrow)*64 + k0 + lcol, &Ws[buf][c*512]);
  };

  f32x4 acc[4][4];
  #pragma unroll
  for (int m=0;m<4;++m)
    #pragma unroll
    for (int n=0;n<4;++n) acc[m][n] = (f32x4){0.f,0.f,0.f,0.f};

  stage(0, 0);
  __syncthreads();
  int cur = 0;
  #pragma unroll
  for (int ks = 0; ks < 2; ++ks){
    if (ks == 0) stage(1, 1);
    bf16x8 af[4], wf[4];
    #pragma unroll
    for (int m=0;m<4;++m)
      af[m] = *(const bf16x8*)&As[cur][(wr*64 + m*16 + fr)*32 + kb*8];
    #pragma unroll
    for (int n=0;n<4;++n)
      wf[n] = *(const bf16x8*)&Ws[cur][(wc*64 + n*16 + fr)*32 + kb*8];
    #pragma unroll
    for (int m=0;m<4;++m)
      #pragma unroll
      for (int n=0;n<4;++n)
        acc[m][n] = __builtin_amdgcn_mfma_f32_16x16x32_bf16(af[m], wf[n], acc[m][n], 0,0,0);
    __syncthreads();
    cur ^= 1;
  }
  #pragma unroll
  for (int m=0;m<4;++m){
    int rowb = m0 + wr*64 + m*16 + kb*4;
    #pragma unroll
    for (int n=0;n<4;++n){
      int cl = wc*64 + n*16 + fr;
      int gl = cl >> 6, e = cl & 63;
      float bv = gb[(2*p + gl)*256 + hd*64 + e];
      int phys = hd*256 + p*128 + e*2 + gl;
      #pragma unroll
      for (int r=0;r<4;++r)
        gates[(size_t)(rowb + r)*1024 + phys] = f2bf(acc[m][n][r] + bv);
    }
  }
}

// ---------------- FFN up + fast gelu*g2 fused --------------------------------------
__global__ __launch_bounds__(256) void mfma_up_gelu2(
    const u16* __restrict__ A, const u16* __restrict__ Wt,
    const float* __restrict__ ub, u16* __restrict__ gp)
{
  __shared__ u16 As[2][128*32];
  __shared__ u16 Ws[2][128*32];
  const int tid = threadIdx.x;
  const int lane = tid & 63, wid = tid >> 6;
  const int wr = wid >> 1, wc = wid & 1;
  const int fr = lane & 15, kb = lane >> 4;
  const int m0 = blockIdx.x*128, n0 = blockIdx.y*64;
  const u16* W1 = Wt + (size_t)n0*256;
  const u16* W2 = Wt + (size_t)(384 + n0)*256;
  const int lrow = lane >> 2, lcol = (lane & 3)*8;

  auto stage = [&](int buf, int ks){
    int k0 = ks*32;
    for (int c = wid; c < 8; c += 4)
      gload16(A + (size_t)(m0 + c*16 + lrow)*256 + k0 + lcol, &As[buf][c*512]);
    for (int c = wid; c < 8; c += 4){
      const u16* src = (c < 4) ? (W1 + (size_t)(c*16 + lrow)*256)
                               : (W2 + (size_t)((c-4)*16 + lrow)*256);
      gload16(src + k0 + lcol, &Ws[buf][c*512]);
    }
  };

  f32x4 a1[4][2], a2[4][2];
  #pragma unroll
  for (int m=0;m<4;++m)
    #pragma unroll
    for (int n=0;n<2;++n){ a1[m][n]=(f32x4){0,0,0,0}; a2[m][n]=(f32x4){0,0,0,0}; }

  stage(0, 0);
  __syncthreads();
  int cur = 0;
  #pragma unroll
  for (int ks = 0; ks < 8; ++ks){
    if (ks + 1 < 8) stage(cur^1, ks+1);
    bf16x8 af[4], wf1[2], wf2[2];
    #pragma unroll
    for (int m=0;m<4;++m)
      af[m] = *(const bf16x8*)&As[cur][(wr*64 + m*16 + fr)*32 + kb*8];
    #pragma unroll
    for (int n=0;n<2;++n){
      wf1[n] = *(const bf16x8*)&Ws[cur][(wc*32 + n*16 + fr)*32 + kb*8];
      wf2[n] = *(const bf16x8*)&Ws[cur][(64 + wc*32 + n*16 + fr)*32 + kb*8];
    }
    #pragma unroll
    for (int m=0;m<4;++m)
      #pragma unroll
      for (int n=0;n<2;++n){
        a1[m][n] = __builtin_amdgcn_mfma_f32_16x16x32_bf16(af[m], wf1[n], a1[m][n], 0,0,0);
        a2[m][n] = __builtin_amdgcn_mfma_f32_16x16x32_bf16(af[m], wf2[n], a2[m][n], 0,0,0);
      }
    __syncthreads();
    cur ^= 1;
  }
  #pragma unroll
  for (int m=0;m<4;++m){
    int rowb = m0 + wr*64 + m*16 + kb*4;
    #pragma unroll
    for (int n=0;n<2;++n){
      int col = n0 + wc*32 + n*16 + fr;
      float b1 = ub[col], b2 = ub[384 + col];
      #pragma unroll
      for (int r=0;r<4;++r){
        float g1 = a1[m][n][r] + b1;
        float g2 = a2[m][n][r] + b2;
        float u  = 0.7978845608028654f*(g1 + 0.044715f*g1*g1*g1);
        float uc = fminf(fmaxf(u, -20.f), 20.f);
        float t2 = __expf(uc + uc);
        float th = (t2 - 1.f)/(t2 + 1.f);
        float ge = 0.5f*g1*(1.f + th);
        gp[(size_t)(rowb + r)*UPDIM + col] = f2bf(ge*g2);
      }
    }
  }
}

// ---------------- sLSTM scan v4: raw barriers (no vmcnt drain), 2-deep prefetch ----
__global__ __launch_bounds__(256) void slstm_scan4(
    const u16* __restrict__ gates, const u16* __restrict__ Rgt,
    u16* __restrict__ y)
{
  __shared__ u16 h_lds[16*72];
  __shared__ float rec_lds[4][16][68];
  const int tid = threadIdx.x;
  const int w = tid >> 6, lane = tid & 63;
  const int hd = blockIdx.y, grp = blockIdx.x;
  const int fr = lane & 15, kb = lane >> 4;
  const int seq0 = grp*16;
  const u32* g32 = (const u32*)gates;

  bf16x8 bfr[4][2];
  {
    const u16* rb = Rgt + (size_t)(w*NHEAD + hd)*4096;
    #pragma unroll
    for (int n=0;n<4;++n)
      #pragma unroll
      for (int ks=0;ks<2;++ks)
        bfr[n][ks] = *(const bf16x8*)(rb + (size_t)(n*16 + fr)*64 + ks*32 + kb*8);
  }
  for (int i = tid; i < 16*72/2; i += 256) ((u32*)h_lds)[i] = 0u;
  float c[4]={0,0,0,0}, nst[4]={0,0,0,0}, m[4]={0,0,0,0};

  size_t gb4[4];
  #pragma unroll
  for (int si=0; si<4; ++si)
    gb4[si] = ((size_t)(seq0 + 4*w + si)*NS)*512 + hd*128 + lane;

  u32 g0[4][2], g1[4][2];
  #pragma unroll
  for (int si=0; si<4; ++si){
    g0[si][0] = g32[gb4[si]];        g0[si][1] = g32[gb4[si] + 64];
    g1[si][0] = g32[gb4[si] + 512];  g1[si][1] = g32[gb4[si] + 576];
  }
  __syncthreads();

  for (int s = 0; s < NS; ++s){
    u32 gn[4][2] = {};
    if (s + 2 < NS){
      #pragma unroll
      for (int si=0; si<4; ++si){
        size_t b2 = gb4[si] + (size_t)(s+2)*512;
        gn[si][0] = g32[b2];
        gn[si][1] = g32[b2 + 64];
      }
    }
    // MFMA: rec = H @ Rg[w]
    bf16x8 af0 = *(const bf16x8*)&h_lds[fr*72 + kb*8];
    bf16x8 af1 = *(const bf16x8*)&h_lds[fr*72 + 32 + kb*8];
    f32x4 acc[4];
    #pragma unroll
    for (int n=0;n<4;++n){
      acc[n] = (f32x4){0,0,0,0};
      acc[n] = __builtin_amdgcn_mfma_f32_16x16x32_bf16(af0, bfr[n][0], acc[n], 0,0,0);
      acc[n] = __builtin_amdgcn_mfma_f32_16x16x32_bf16(af1, bfr[n][1], acc[n], 0,0,0);
    }
    #pragma unroll
    for (int n=0;n<4;++n)
      #pragma unroll
      for (int r=0;r<4;++r)
        rec_lds[w][kb*4 + r][n*16 + fr] = acc[n][r];
    asm volatile("s_waitcnt lgkmcnt(0)" ::: "memory");
    __builtin_amdgcn_s_barrier();
    // elementwise: wave w owns seqs 4w..4w+3, lane = e
    #pragma unroll
    for (int si=0; si<4; ++si){
      int sidx = 4*w + si;
      float ip = rec_lds[0][sidx][lane] + bf2f(g0[si][0] & 0xffffu);
      float fp = rec_lds[1][sidx][lane] + bf2f_hi(g0[si][0]);
      float zp = rec_lds[2][sidx][lane] + bf2f(g0[si][1] & 0xffffu);
      float op = rec_lds[3][sidx][lane] + bf2f_hi(g0[si][1]);
      float sp  = __logf(1.f + __expf(-fabsf(fp)));
      float lg  = m[si] + fminf(fp, 0.f) - sp;
      float mn  = fmaxf(ip, lg);
      float iv  = __expf(ip - mn);
      float fv  = __expf(lg - mn);
      float zz  = fminf(fabsf(zp), 15.f);
      float t2  = __expf(zz + zz);
      float tha = (t2 - 1.f)/(t2 + 1.f);
      float th  = (zp >= 0.f) ? tha : -tha;
      c[si]   = fv*c[si] + iv*th;
      nst[si] = fv*nst[si] + iv;
      m[si]   = mn;
      float hv = c[si] * __builtin_amdgcn_rcpf(nst[si]*(1.f + __expf(-op)));
      h_lds[sidx*72 + lane] = f2bf(hv);
      size_t t = (size_t)(seq0 + sidx)*NS + s;
      y[t*DDIM + hd*64 + lane] = f2bf(hv);
    }
    asm volatile("s_waitcnt lgkmcnt(0)" ::: "memory");
    __builtin_amdgcn_s_barrier();
    #pragma unroll
    for (int si=0; si<4; ++si){
      g0[si][0] = g1[si][0]; g0[si][1] = g1[si][1];
      g1[si][0] = gn[si][0]; g1[si][1] = gn[si][1];
    }
  }
}

// ---------------- proj reduce over K-split slices ----------------------------------
__global__ __launch_bounds__(256) void proj_out(
    const float* __restrict__ ptmp, const float* __restrict__ bproj,
    float* __restrict__ out, int Nc, int n0glob){
  int gid = blockIdx.x*256 + threadIdx.x;
  if (gid >= Nc*PREDN) return;
  float acc = 0.f;
  #pragma unroll
  for (int kc = 0; kc < KC_PROJ; ++kc) acc += ptmp[(size_t)kc*Nc*PREDN + gid];
  int nl = gid / PREDN, j = gid - nl*PREDN;
  int n = n0glob + nl;
  out[((size_t)(n >> 5)*PREDN + j)*CCH + (n & 31)] = acc + bproj[j];
}

extern "C" void kernel_launch(void* const* d_in, const int* in_sizes, int n_in,
                              void* d_out, int out_size, void* d_ws, size_t ws_size,
                              hipStream_t stream) {
  const float* x      = (const float*)d_in[0];
  const float* W_emb  = (const float*)d_in[1];
  const float* b_emb  = (const float*)d_in[2];
  const float* ln1_w  = (const float*)d_in[3];
  const float* ln1_b  = (const float*)d_in[4];
  const float* conv_w = (const float*)d_in[5];
  const float* conv_b = (const float*)d_in[6];
  const float* Wg     = (const float*)d_in[7];
  const float* Rg     = (const float*)d_in[8];
  const float* gb     = (const float*)d_in[9];
  const float* gn_w   = (const float*)d_in[10];
  const float* ln2_w  = (const float*)d_in[11];
  const float* ln2_b  = (const float*)d_in[12];
  const float* up_w   = (const float*)d_in[13];
  const float* up_b   = (const float*)d_in[14];
  const float* dn_w   = (const float*)d_in[15];
  const float* dn_b   = (const float*)d_in[16];
  const float* post_w = (const float*)d_in[17];
  const float* post_b = (const float*)d_in[18];
  const float* W_proj = (const float*)d_in[19];
  const float* b_proj = (const float*)d_in[20];
  float* out = (float*)d_out;

  // ---- workspace: weights then chunk area (h bf16, ptmp overlaid in gates) ----
  const size_t oWu   = 0;          // [2][768][256] bf16 : 1,572,864
  const size_t oWd   = 1572864;    // [2][256][384] bf16 :   786,432
  const size_t oWg2  = 2359296;    // [2][8][128][64] bf16 :  262,144
  const size_t oRgt  = 2621440;    // [2][16][64][64] bf16 :  524,288
  const size_t oWp   = 3145728;    // [96][16128] bf16 : 3,096,576
  const size_t oChunk = 6242304;
  const size_t per_seq = (size_t)3584*NS;   // 225,792 B
  int Nc = 0;
  const int cands[6] = {1024, 768, 512, 384, 256, 128};
  for (int i = 0; i < 6; ++i)
    if (oChunk + (size_t)cands[i]*per_seq <= ws_size){ Nc = cands[i]; break; }
  if (Nc == 0) return;

  char* wsb = (char*)d_ws;
  u16* Wu   = (u16*)(wsb + oWu);
  u16* Wd   = (u16*)(wsb + oWd);
  u16* Wg2  = (u16*)(wsb + oWg2);
  u16* Rgt  = (u16*)(wsb + oRgt);
  u16* Wtp  = (u16*)(wsb + oWp);

  for (int blk = 0; blk < 2; ++blk){
    cvt_transpose<<<(256*768+255)/256, 256, 0, stream>>>(
        up_w + (size_t)blk*256*768, Wu + (size_t)blk*768*256, 256, 768);
    cvt_transpose<<<(384*256+255)/256, 256, 0, stream>>>(
        dn_w + (size_t)blk*384*256, Wd + (size_t)blk*256*384, 384, 256);
  }
  cvt_gateW2<<<16, 256, 0, stream>>>(Wg, Wg2);
  cvt_gate<<<32, 256, 0, stream>>>(Rg, Rgt);
  cvt_transpose<<<(16128*96+255)/256, 256, 0, stream>>>(W_proj, Wtp, 16128, 96);

  for (int n0 = 0; n0 < NSEQ; n0 += Nc){
    const int    nc  = (NSEQ - n0 < Nc) ? (NSEQ - n0) : Nc;
    const size_t Tc  = (size_t)nc * NS;
    char* cb = wsb + oChunk;
    u16*   h_c   = (u16*)cb;                          // Tc*512 B (bf16)
    u16*   bufA  = (u16*)(cb + Tc*512);               // Tc*512 B
    u16*   bufB  = (u16*)(cb + Tc*1024);              // Tc*512 B
    u16*   gates = (u16*)(cb + Tc*1536);              // Tc*2048 B ([t][1024])
    u16*   gp    = gates;                             // reuse (Tc*768 B)
    float* ptmp  = (float*)(cb + Tc*1536 + Tc*1024);  // overlay in gates tail
    const int t_base = n0*NS;
    const int Tci = (int)Tc;

    patch_embed_ln<<<Tci, 256, 0, stream>>>(
        x, W_emb, b_emb, ln1_w, ln1_b, h_c, bufA, t_base);

    for (int blk = 0; blk < 2; ++blk){
      if (blk == 1)
        layernorm_bf16<<<Tci, 256, 0, stream>>>(h_c, ln1_w + DDIM, ln1_b + DDIM, bufA);
      conv_silu<<<Tci, 256, 0, stream>>>(bufA, conv_w + blk*4*DDIM, conv_b + blk*DDIM, bufB, t_base);
      mfma_gate2<<<dim3(Tci/128, 8), 256, 0, stream>>>(
          bufB, bufA, Wg2 + (size_t)blk*8*8192, gb + blk*4*DDIM, gates);
      slstm_scan4<<<dim3(nc/16, NHEAD), 256, 0, stream>>>(
          gates, Rgt + (size_t)blk*16*4096, bufB);
      gn_res_ln<<<Tci, 256, 0, stream>>>(
          bufB, gn_w + blk*DDIM, ln2_w + blk*DDIM, ln2_b + blk*DDIM, h_c, bufA);
      mfma_up_gelu2<<<dim3(Tci/128, 6), 256, 0, stream>>>(
          bufA, Wu + (size_t)blk*768*256, up_b + blk*2*UPDIM, gp);
      mfma_gemm2<128,128,2,2,4,4,1><<<dim3(Tci/128, 2), 256, 0, stream>>>(
          gp, UPDIM, Wd + (size_t)blk*256*384, UPDIM,
          dn_b + blk*DDIM, (void*)h_c, DDIM, 12, 0, 0);
    }

    layernorm_bf16<<<Tci, 256, 0, stream>>>(h_c, post_w, post_b, bufA);
    mfma_gemm2<64,96,2,2,2,3,2><<<dim3(nc/64, 1, KC_PROJ), 256, 0, stream>>>(
        bufA, NS*DDIM, Wtp, NS*DDIM,
        b_proj, (void*)ptmp, PREDN, KCHUNK_PROJ/32, KCHUNK_PROJ, nc);
    proj_out<<<(nc*PREDN + 255)/256, 256, 0, stream>>>(ptmp, b_proj, out, nc, n0);
  }
}

// Round 8
// 789.790 us; speedup vs baseline: 3.9939x; 1.1501x over previous
//
#include <hip/hip_runtime.h>
#include <stdint.h>

typedef unsigned short u16;
typedef unsigned int   u32;
typedef __attribute__((ext_vector_type(8))) short bf16x8;
typedef __attribute__((ext_vector_type(4))) float f32x4;

#define NS      63
#define NSEQ    1024
#define DDIM    256
#define NHEAD   4
#define DHEAD   64
#define UPDIM   384
#define PREDN   96
#define LLEN    512
#define CCH     32
#define PSIZE   16
#define PSTRIDE 8
#define KC_PROJ 8
#define KCHUNK_PROJ 2016

__device__ __forceinline__ float bf2f(u32 lo16){
  union { u32 i; float f; } v; v.i = lo16 << 16; return v.f;
}
__device__ __forceinline__ float bf2f_hi(u32 u){
  union { u32 i; float f; } v; v.i = u & 0xffff0000u; return v.f;
}
__device__ __forceinline__ u16 f2bf(float f){
  union { u32 i; float f; } v; v.f = f;
  u32 u = v.i; u += 0x7fffu + ((u >> 16) & 1u);
  return (u16)(u >> 16);
}

__device__ __forceinline__ void gload16(const u16* g, u16* lds){
  __builtin_amdgcn_global_load_lds(
      (const __attribute__((address_space(1))) u32*)g,
      (__attribute__((address_space(3))) u32*)lds, 16, 0, 0);
}

// ---------------- LDS-tiled transpose: dst[c][r] = bf16(src[r][c]) -----------------
__global__ __launch_bounds__(256) void cvt_transpose_t(
    const float* __restrict__ src, u16* __restrict__ dst, int R, int C){
  __shared__ u16 tile[32][33];
  int rb = blockIdx.x*32, cb = blockIdx.y*32;
  int tx = threadIdx.x & 31, ty = threadIdx.x >> 5;
  #pragma unroll
  for (int i = ty; i < 32; i += 8){
    int r = rb + i, c = cb + tx;
    tile[i][tx] = (r < R && c < C) ? f2bf(src[(size_t)r*C + c]) : (u16)0;
  }
  __syncthreads();
  #pragma unroll
  for (int i = ty; i < 32; i += 8){
    int c = cb + i, r = rb + tx;
    if (c < C && r < R) dst[(size_t)c*R + r] = tile[tx][i];
  }
}

// 64x64 per-matrix transpose (Rg -> Rgt); small, once per call
__global__ __launch_bounds__(256) void cvt_gate(
    const float* __restrict__ src, u16* __restrict__ dst){
  int mat = blockIdx.x, t = threadIdx.x;
  const float* s = src + (size_t)mat*4096;
  u16* d = dst + (size_t)mat*4096;
  for (int i = t; i < 4096; i += 256){
    int r = i >> 6, c = i & 63;
    d[c*64 + r] = f2bf(s[i]);
  }
}

// gate weight true-K layout, col order n = e*2+gl: dst[(blk*2+p)*4+hd][n][k]
__global__ __launch_bounds__(256) void cvt_gateW2(
    const float* __restrict__ Wg, u16* __restrict__ dst){
  int mi = blockIdx.x;
  int blk = mi >> 3, p = (mi >> 2) & 1, hd = mi & 3;
  u16* d = dst + (size_t)mi*8192;
  for (int i = threadIdx.x; i < 8192; i += 256){
    int n = i >> 6, k = i & 63;
    int e = n >> 1, gl = n & 1;
    int g = 2*p + gl;
    d[i] = f2bf(Wg[((((size_t)blk*4 + g)*4 + hd)*64 + k)*64 + e]);
  }
}

// ---------------- patch embedding + ln1(blk0), wave = token, vectorized ------------
__global__ __launch_bounds__(256) void patch_embed_ln_v(
    const float* __restrict__ x, const float* __restrict__ Wemb,
    const float* __restrict__ bemb, const float* __restrict__ w1,
    const float* __restrict__ b1, u16* __restrict__ h,
    u16* __restrict__ outA, int t_base){
  int wv = blockIdx.x*4 + (threadIdx.x >> 6);
  int lane = threadIdx.x & 63;
  int tg = t_base + wv;
  int n = tg / NS, s = tg - n*NS;
  int b = n >> 5, c = n & 31;
  int l0 = s * PSTRIDE;
  float4 acc = *(const float4*)(bemb + lane*4);
  #pragma unroll
  for (int p = 0; p < PSIZE; ++p){
    float xv = x[((size_t)b*LLEN + l0 + p)*CCH + c];
    float4 we = *(const float4*)(Wemb + p*DDIM + lane*4);
    acc.x += xv*we.x; acc.y += xv*we.y; acc.z += xv*we.z; acc.w += xv*we.w;
  }
  ushort4 hu; hu.x=f2bf(acc.x); hu.y=f2bf(acc.y); hu.z=f2bf(acc.z); hu.w=f2bf(acc.w);
  *(ushort4*)(h + (size_t)wv*DDIM + lane*4) = hu;
  float s1 = acc.x+acc.y+acc.z+acc.w;
  float s2 = acc.x*acc.x+acc.y*acc.y+acc.z*acc.z+acc.w*acc.w;
  #pragma unroll
  for (int o = 1; o < 64; o <<= 1){ s1 += __shfl_xor(s1,o,64); s2 += __shfl_xor(s2,o,64); }
  float mu = s1*(1.f/DDIM);
  float var = s2*(1.f/DDIM) - mu*mu;
  float rstd = rsqrtf(var + 1e-5f);
  float4 wf = *(const float4*)(w1 + lane*4);
  float4 bf = *(const float4*)(b1 + lane*4);
  ushort4 o4;
  o4.x = f2bf((acc.x-mu)*rstd*wf.x + bf.x);
  o4.y = f2bf((acc.y-mu)*rstd*wf.y + bf.y);
  o4.z = f2bf((acc.z-mu)*rstd*wf.z + bf.z);
  o4.w = f2bf((acc.w-mu)*rstd*wf.w + bf.w);
  *(ushort4*)(outA + (size_t)wv*DDIM + lane*4) = o4;
}

// ---------------- layernorm, wave = token, vectorized ------------------------------
__global__ __launch_bounds__(256) void layernorm_v(
    const u16* __restrict__ in, const float* __restrict__ w,
    const float* __restrict__ b, u16* __restrict__ out){
  int wv = blockIdx.x*4 + (threadIdx.x >> 6);
  int lane = threadIdx.x & 63;
  ushort4 u = *(const ushort4*)(in + (size_t)wv*DDIM + lane*4);
  float v0=bf2f(u.x), v1=bf2f(u.y), v2=bf2f(u.z), v3=bf2f(u.w);
  float s1 = v0+v1+v2+v3, s2 = v0*v0+v1*v1+v2*v2+v3*v3;
  #pragma unroll
  for (int o = 1; o < 64; o <<= 1){ s1 += __shfl_xor(s1,o,64); s2 += __shfl_xor(s2,o,64); }
  float mu = s1*(1.f/DDIM);
  float var = s2*(1.f/DDIM) - mu*mu;
  float rstd = rsqrtf(var + 1e-5f);
  float4 wf = *(const float4*)(w + lane*4);
  float4 bf = *(const float4*)(b + lane*4);
  ushort4 o4;
  o4.x = f2bf((v0-mu)*rstd*wf.x + bf.x);
  o4.y = f2bf((v1-mu)*rstd*wf.y + bf.y);
  o4.z = f2bf((v2-mu)*rstd*wf.z + bf.z);
  o4.w = f2bf((v3-mu)*rstd*wf.w + bf.w);
  *(ushort4*)(out + (size_t)wv*DDIM + lane*4) = o4;
}

// ---------------- fused groupnorm + residual + layernorm, vectorized ---------------
__global__ __launch_bounds__(256) void gn_res_ln_v(
    const u16* __restrict__ y, const float* __restrict__ gnw,
    const float* __restrict__ w2, const float* __restrict__ b2,
    u16* __restrict__ h, u16* __restrict__ outA){
  int wv = blockIdx.x*4 + (threadIdx.x >> 6);
  int lane = threadIdx.x & 63;
  ushort4 u = *(const ushort4*)(y + (size_t)wv*DDIM + lane*4);
  float v0=bf2f(u.x), v1=bf2f(u.y), v2=bf2f(u.z), v3=bf2f(u.w);
  float s1 = v0+v1+v2+v3, s2 = v0*v0+v1*v1+v2*v2+v3*v3;
  #pragma unroll
  for (int o = 1; o < 16; o <<= 1){ s1 += __shfl_xor(s1,o,64); s2 += __shfl_xor(s2,o,64); }
  float mu64 = s1*(1.f/64.f);
  float var64 = s2*(1.f/64.f) - mu64*mu64;
  float rstd64 = rsqrtf(var64 + 1e-5f);
  float4 gw = *(const float4*)(gnw + lane*4);
  ushort4 hu = *(const ushort4*)(h + (size_t)wv*DDIM + lane*4);
  float h0 = bf2f(hu.x) + (v0-mu64)*rstd64*gw.x;
  float h1 = bf2f(hu.y) + (v1-mu64)*rstd64*gw.y;
  float h2 = bf2f(hu.z) + (v2-mu64)*rstd64*gw.z;
  float h3 = bf2f(hu.w) + (v3-mu64)*rstd64*gw.w;
  ushort4 hn; hn.x=f2bf(h0); hn.y=f2bf(h1); hn.z=f2bf(h2); hn.w=f2bf(h3);
  *(ushort4*)(h + (size_t)wv*DDIM + lane*4) = hn;
  float t1 = h0+h1+h2+h3, t2 = h0*h0+h1*h1+h2*h2+h3*h3;
  #pragma unroll
  for (int o = 1; o < 64; o <<= 1){ t1 += __shfl_xor(t1,o,64); t2 += __shfl_xor(t2,o,64); }
  float mu = t1*(1.f/DDIM);
  float var = t2*(1.f/DDIM) - mu*mu;
  float rstd = rsqrtf(var + 1e-5f);
  float4 wf = *(const float4*)(w2 + lane*4);
  float4 bf = *(const float4*)(b2 + lane*4);
  ushort4 o4;
  o4.x = f2bf((h0-mu)*rstd*wf.x + bf.x);
  o4.y = f2bf((h1-mu)*rstd*wf.y + bf.y);
  o4.z = f2bf((h2-mu)*rstd*wf.z + bf.z);
  o4.w = f2bf((h3-mu)*rstd*wf.w + bf.w);
  *(ushort4*)(outA + (size_t)wv*DDIM + lane*4) = o4;
}

// ---------------- causal depthwise conv K=4 + SiLU, vectorized ---------------------
__global__ __launch_bounds__(256) void conv_silu_v(
    const u16* __restrict__ xln, const float* __restrict__ cw,
    const float* __restrict__ cb, u16* __restrict__ xc){
  int wv = blockIdx.x*4 + (threadIdx.x >> 6);
  int lane = threadIdx.x & 63;
  int s = wv % NS;
  float4 acc = *(const float4*)(cb + lane*4);
  #pragma unroll
  for (int k = 0; k < 4; ++k){
    int ss = s + k - 3;
    if (ss >= 0){
      ushort4 xu = *(const ushort4*)(xln + (size_t)(wv + k - 3)*DDIM + lane*4);
      float4 cv = *(const float4*)(cw + k*DDIM + lane*4);
      acc.x += bf2f(xu.x)*cv.x; acc.y += bf2f(xu.y)*cv.y;
      acc.z += bf2f(xu.z)*cv.z; acc.w += bf2f(xu.w)*cv.w;
    }
  }
  ushort4 o4;
  o4.x = f2bf(acc.x/(1.f + __expf(-acc.x)));
  o4.y = f2bf(acc.y/(1.f + __expf(-acc.y)));
  o4.z = f2bf(acc.z/(1.f + __expf(-acc.z)));
  o4.w = f2bf(acc.w/(1.f + __expf(-acc.w)));
  *(ushort4*)(xc + (size_t)wv*DDIM + lane*4) = o4;
}

// ---------------- generic MFMA GEMM, global_load_lds 2-phase -----------------------
// MODE 1: bf16 out += acc + bias (RMW);  MODE 2: fp32 ptmp[(kc*Mtot+row)*ldo+col]=acc
template<int BM,int BN,int WR,int WC,int MR,int NR,int MODE>
__global__ __launch_bounds__(256) void mfma_gemm2(
    const u16* __restrict__ A, int lda,
    const u16* __restrict__ Wt, int ldwt,
    const float* __restrict__ bias, void* __restrict__ outp, int ldo,
    int ksteps, int kchunk, int Mtot)
{
  constexpr int nA = BM/16, nW = BN/16;
  __shared__ u16 As[2][BM*32];
  __shared__ u16 Ws[2][BN*32];
  const int tid = threadIdx.x;
  const int lane = tid & 63, wid = tid >> 6;
  const int wr = wid / WC, wc = wid % WC;
  const int fr = lane & 15, kb = lane >> 4;
  const int m0 = blockIdx.x*BM, n0 = blockIdx.y*BN;
  const int kc = blockIdx.z;
  const int kbeg = kc*kchunk;
  const u16* Ab = A + (size_t)m0*lda + kbeg;
  const u16* Wb = Wt + (size_t)n0*ldwt + kbeg;
  const int lrow = lane >> 2, lcol = (lane & 3)*8;

  auto stage = [&](int buf, int ks){
    int k0 = ks*32;
    for (int c = wid; c < nA; c += 4)
      gload16(Ab + (size_t)(c*16 + lrow)*lda + k0 + lcol, &As[buf][c*512]);
    for (int c = wid; c < nW; c += 4)
      gload16(Wb + (size_t)(c*16 + lrow)*ldwt + k0 + lcol, &Ws[buf][c*512]);
  };

  f32x4 acc[MR][NR];
  #pragma unroll
  for (int m=0;m<MR;++m)
    #pragma unroll
    for (int n=0;n<NR;++n) acc[m][n] = (f32x4){0.f,0.f,0.f,0.f};

  stage(0, 0);
  __syncthreads();
  int cur = 0;
  for (int ks = 0; ks < ksteps; ++ks){
    if (ks + 1 < ksteps) stage(cur^1, ks+1);
    bf16x8 af[MR], wf[NR];
    #pragma unroll
    for (int m=0;m<MR;++m)
      af[m] = *(const bf16x8*)&As[cur][(wr*MR*16 + m*16 + fr)*32 + kb*8];
    #pragma unroll
    for (int n=0;n<NR;++n)
      wf[n] = *(const bf16x8*)&Ws[cur][(wc*NR*16 + n*16 + fr)*32 + kb*8];
    #pragma unroll
    for (int m=0;m<MR;++m)
      #pragma unroll
      for (int n=0;n<NR;++n)
        acc[m][n] = __builtin_amdgcn_mfma_f32_16x16x32_bf16(af[m], wf[n], acc[m][n], 0,0,0);
    __syncthreads();
    cur ^= 1;
  }
  #pragma unroll
  for (int m=0;m<MR;++m){
    int rowb = m0 + wr*MR*16 + m*16 + kb*4;
    #pragma unroll
    for (int n=0;n<NR;++n){
      int col = n0 + wc*NR*16 + n*16 + fr;
      #pragma unroll
      for (int r=0;r<4;++r){
        int row = rowb + r;
        float v = acc[m][n][r];
        if (MODE == 1){
          u16* dst = (u16*)outp + (size_t)row*ldo + col;
          *dst = f2bf(bf2f(*dst) + v + bias[col]);
        } else {
          ((float*)outp)[((size_t)kc*Mtot + row)*ldo + col] = v;
        }
      }
    }
  }
}

// ---------------- gate GEMM, true K=64, coalesced stores ---------------------------
__global__ __launch_bounds__(256) void mfma_gate2(
    const u16* __restrict__ xc, const u16* __restrict__ xh,
    const u16* __restrict__ Wg2, const float* __restrict__ gb,
    u16* __restrict__ gates)
{
  __shared__ u16 As[2][128*32];
  __shared__ u16 Ws[2][128*32];
  const int tid = threadIdx.x;
  const int lane = tid & 63, wid = tid >> 6;
  const int wr = wid >> 1, wc = wid & 1;
  const int fr = lane & 15, kb = lane >> 4;
  const int p = blockIdx.y >> 2, hd = blockIdx.y & 3;
  const int m0 = blockIdx.x*128;
  const u16* Ain = (p == 0) ? xc : xh;
  const u16* Wb = Wg2 + (size_t)blockIdx.y*8192;
  const int lrow = lane >> 2, lcol = (lane & 3)*8;

  auto stage = [&](int buf, int ks){
    int k0 = ks*32;
    for (int c = wid; c < 8; c += 4)
      gload16(Ain + (size_t)(m0 + c*16 + lrow)*DDIM + hd*64 + k0 + lcol, &As[buf][c*512]);
    for (int c = wid; c < 8; c += 4)
      gload16(Wb + (size_t)(c*16 + lrow)*64 + k0 + lcol, &Ws[buf][c*512]);
  };

  f32x4 acc[4][4];
  #pragma unroll
  for (int m=0;m<4;++m)
    #pragma unroll
    for (int n=0;n<4;++n) acc[m][n] = (f32x4){0.f,0.f,0.f,0.f};

  stage(0, 0);
  __syncthreads();
  int cur = 0;
  #pragma unroll
  for (int ks = 0; ks < 2; ++ks){
    if (ks == 0) stage(1, 1);
    bf16x8 af[4], wf[4];
    #pragma unroll
    for (int m=0;m<4;++m)
      af[m] = *(const bf16x8*)&As[cur][(wr*64 + m*16 + fr)*32 + kb*8];
    #pragma unroll
    for (int n=0;n<4;++n)
      wf[n] = *(const bf16x8*)&Ws[cur][(wc*64 + n*16 + fr)*32 + kb*8];
    #pragma unroll
    for (int m=0;m<4;++m)
      #pragma unroll
      for (int n=0;n<4;++n)
        acc[m][n] = __builtin_amdgcn_mfma_f32_16x16x32_bf16(af[m], wf[n], acc[m][n], 0,0,0);
    __syncthreads();
    cur ^= 1;
  }
  #pragma unroll
  for (int m=0;m<4;++m){
    int rowb = m0 + wr*64 + m*16 + kb*4;
    #pragma unroll
    for (int n=0;n<4;++n){
      int cl = wc*64 + n*16 + fr;      // col order = e*2+gl (weight pre-permuted)
      int e = cl >> 1, gl = cl & 1;
      float bv = gb[(2*p + gl)*256 + hd*64 + e];
      int phys = hd*256 + p*128 + cl;
      #pragma unroll
      for (int r=0;r<4;++r)
        gates[(size_t)(rowb + r)*1024 + phys] = f2bf(acc[m][n][r] + bv);
    }
  }
}

// ---------------- FFN up + fast gelu*g2, BM=256 ------------------------------------
__global__ __launch_bounds__(256) void mfma_up_gelu3(
    const u16* __restrict__ A, const u16* __restrict__ Wt,
    const float* __restrict__ ub, u16* __restrict__ gp)
{
  __shared__ u16 As[2][256*32];
  __shared__ u16 Ws[2][128*32];
  const int tid = threadIdx.x;
  const int lane = tid & 63, wid = tid >> 6;
  const int fr = lane & 15, kb = lane >> 4;
  const int m0 = blockIdx.x*256, n0 = blockIdx.y*64;
  const u16* W1 = Wt + (size_t)n0*256;
  const u16* W2 = Wt + (size_t)(384 + n0)*256;
  const int lrow = lane >> 2, lcol = (lane & 3)*8;

  auto stage = [&](int buf, int ks){
    int k0 = ks*32;
    for (int c = wid; c < 16; c += 4)
      gload16(A + (size_t)(m0 + c*16 + lrow)*256 + k0 + lcol, &As[buf][c*512]);
    for (int c = wid; c < 8; c += 4){
      const u16* src = (c < 4) ? (W1 + (size_t)(c*16 + lrow)*256)
                               : (W2 + (size_t)((c-4)*16 + lrow)*256);
      gload16(src + k0 + lcol, &Ws[buf][c*512]);
    }
  };

  f32x4 a1[4][4], a2[4][4];
  #pragma unroll
  for (int m=0;m<4;++m)
    #pragma unroll
    for (int n=0;n<4;++n){ a1[m][n]=(f32x4){0,0,0,0}; a2[m][n]=(f32x4){0,0,0,0}; }

  stage(0, 0);
  __syncthreads();
  int cur = 0;
  #pragma unroll
  for (int ks = 0; ks < 8; ++ks){
    if (ks + 1 < 8) stage(cur^1, ks+1);
    bf16x8 af[4], wf1[4], wf2[4];
    #pragma unroll
    for (int m=0;m<4;++m)
      af[m] = *(const bf16x8*)&As[cur][(wid*64 + m*16 + fr)*32 + kb*8];
    #pragma unroll
    for (int n=0;n<4;++n){
      wf1[n] = *(const bf16x8*)&Ws[cur][(n*16 + fr)*32 + kb*8];
      wf2[n] = *(const bf16x8*)&Ws[cur][(64 + n*16 + fr)*32 + kb*8];
    }
    #pragma unroll
    for (int m=0;m<4;++m)
      #pragma unroll
      for (int n=0;n<4;++n){
        a1[m][n] = __builtin_amdgcn_mfma_f32_16x16x32_bf16(af[m], wf1[n], a1[m][n], 0,0,0);
        a2[m][n] = __builtin_amdgcn_mfma_f32_16x16x32_bf16(af[m], wf2[n], a2[m][n], 0,0,0);
      }
    __syncthreads();
    cur ^= 1;
  }
  #pragma unroll
  for (int m=0;m<4;++m){
    int rowb = m0 + wid*64 + m*16 + kb*4;
    #pragma unroll
    for (int n=0;n<4;++n){
      int col = n0 + n*16 + fr;
      float b1 = ub[col], b2 = ub[384 + col];
      #pragma unroll
      for (int r=0;r<4;++r){
        float g1 = a1[m][n][r] + b1;
        float g2 = a2[m][n][r] + b2;
        float u  = 0.7978845608028654f*(g1 + 0.044715f*g1*g1*g1);
        float uc = fminf(fmaxf(u, -20.f), 20.f);
        float t2 = __expf(uc + uc);
        float th = (t2 - 1.f)/(t2 + 1.f);
        float ge = 0.5f*g1*(1.f + th);
        gp[(size_t)(rowb + r)*UPDIM + col] = f2bf(ge*g2);
      }
    }
  }
}

// ---------------- sLSTM scan v4 (unchanged) ----------------------------------------
__global__ __launch_bounds__(256) void slstm_scan4(
    const u16* __restrict__ gates, const u16* __restrict__ Rgt,
    u16* __restrict__ y)
{
  __shared__ u16 h_lds[16*72];
  __shared__ float rec_lds[4][16][68];
  const int tid = threadIdx.x;
  const int w = tid >> 6, lane = tid & 63;
  const int hd = blockIdx.y, grp = blockIdx.x;
  const int fr = lane & 15, kb = lane >> 4;
  const int seq0 = grp*16;
  const u32* g32 = (const u32*)gates;

  bf16x8 bfr[4][2];
  {
    const u16* rb = Rgt + (size_t)(w*NHEAD + hd)*4096;
    #pragma unroll
    for (int n=0;n<4;++n)
      #pragma unroll
      for (int ks=0;ks<2;++ks)
        bfr[n][ks] = *(const bf16x8*)(rb + (size_t)(n*16 + fr)*64 + ks*32 + kb*8);
  }
  for (int i = tid; i < 16*72/2; i += 256) ((u32*)h_lds)[i] = 0u;
  float c[4]={0,0,0,0}, nst[4]={0,0,0,0}, m[4]={0,0,0,0};

  size_t gb4[4];
  #pragma unroll
  for (int si=0; si<4; ++si)
    gb4[si] = ((size_t)(seq0 + 4*w + si)*NS)*512 + hd*128 + lane;

  u32 g0[4][2], g1[4][2];
  #pragma unroll
  for (int si=0; si<4; ++si){
    g0[si][0] = g32[gb4[si]];        g0[si][1] = g32[gb4[si] + 64];
    g1[si][0] = g32[gb4[si] + 512];  g1[si][1] = g32[gb4[si] + 576];
  }
  __syncthreads();

  for (int s = 0; s < NS; ++s){
    u32 gn[4][2] = {};
    if (s + 2 < NS){
      #pragma unroll
      for (int si=0; si<4; ++si){
        size_t b2 = gb4[si] + (size_t)(s+2)*512;
        gn[si][0] = g32[b2];
        gn[si][1] = g32[b2 + 64];
      }
    }
    bf16x8 af0 = *(const bf16x8*)&h_lds[fr*72 + kb*8];
    bf16x8 af1 = *(const bf16x8*)&h_lds[fr*72 + 32 + kb*8];
    f32x4 acc[4];
    #pragma unroll
    for (int n=0;n<4;++n){
      acc[n] = (f32x4){0,0,0,0};
      acc[n] = __builtin_amdgcn_mfma_f32_16x16x32_bf16(af0, bfr[n][0], acc[n], 0,0,0);
      acc[n] = __builtin_amdgcn_mfma_f32_16x16x32_bf16(af1, bfr[n][1], acc[n], 0,0,0);
    }
    #pragma unroll
    for (int n=0;n<4;++n)
      #pragma unroll
      for (int r=0;r<4;++r)
        rec_lds[w][kb*4 + r][n*16 + fr] = acc[n][r];
    asm volatile("s_waitcnt lgkmcnt(0)" ::: "memory");
    __builtin_amdgcn_s_barrier();
    #pragma unroll
    for (int si=0; si<4; ++si){
      int sidx = 4*w + si;
      float ip = rec_lds[0][sidx][lane] + bf2f(g0[si][0] & 0xffffu);
      float fp = rec_lds[1][sidx][lane] + bf2f_hi(g0[si][0]);
      float zp = rec_lds[2][sidx][lane] + bf2f(g0[si][1] & 0xffffu);
      float op = rec_lds[3][sidx][lane] + bf2f_hi(g0[si][1]);
      float sp  = __logf(1.f + __expf(-fabsf(fp)));
      float lg  = m[si] + fminf(fp, 0.f) - sp;
      float mn  = fmaxf(ip, lg);
      float iv  = __expf(ip - mn);
      float fv  = __expf(lg - mn);
      float zz  = fminf(fabsf(zp), 15.f);
      float t2  = __expf(zz + zz);
      float tha = (t2 - 1.f)/(t2 + 1.f);
      float th  = (zp >= 0.f) ? tha : -tha;
      c[si]   = fv*c[si] + iv*th;
      nst[si] = fv*nst[si] + iv;
      m[si]   = mn;
      float hv = c[si] * __builtin_amdgcn_rcpf(nst[si]*(1.f + __expf(-op)));
      h_lds[sidx*72 + lane] = f2bf(hv);
      size_t t = (size_t)(seq0 + sidx)*NS + s;
      y[t*DDIM + hd*64 + lane] = f2bf(hv);
    }
    asm volatile("s_waitcnt lgkmcnt(0)" ::: "memory");
    __builtin_amdgcn_s_barrier();
    #pragma unroll
    for (int si=0; si<4; ++si){
      g0[si][0] = g1[si][0]; g0[si][1] = g1[si][1];
      g1[si][0] = gn[si][0]; g1[si][1] = gn[si][1];
    }
  }
}

// ---------------- proj reduce over K-split slices ----------------------------------
__global__ __launch_bounds__(256) void proj_out(
    const float* __restrict__ ptmp, const float* __restrict__ bproj,
    float* __restrict__ out, int Nc, int n0glob){
  int gid = blockIdx.x*256 + threadIdx.x;
  if (gid >= Nc*PREDN) return;
  float acc = 0.f;
  #pragma unroll
  for (int kc = 0; kc < KC_PROJ; ++kc) acc += ptmp[(size_t)kc*Nc*PREDN + gid];
  int nl = gid / PREDN, j = gid - nl*PREDN;
  int n = n0glob + nl;
  out[((size_t)(n >> 5)*PREDN + j)*CCH + (n & 31)] = acc + bproj[j];
}

extern "C" void kernel_launch(void* const* d_in, const int* in_sizes, int n_in,
                              void* d_out, int out_size, void* d_ws, size_t ws_size,
                              hipStream_t stream) {
  const float* x      = (const float*)d_in[0];
  const float* W_emb  = (const float*)d_in[1];
  const float* b_emb  = (const float*)d_in[2];
  const float* ln1_w  = (const float*)d_in[3];
  const float* ln1_b  = (const float*)d_in[4];
  const float* conv_w = (const float*)d_in[5];
  const float* conv_b = (const float*)d_in[6];
  const float* Wg     = (const float*)d_in[7];
  const float* Rg     = (const float*)d_in[8];
  const float* gb     = (const float*)d_in[9];
  const float* gn_w   = (const float*)d_in[10];
  const float* ln2_w  = (const float*)d_in[11];
  const float* ln2_b  = (const float*)d_in[12];
  const float* up_w   = (const float*)d_in[13];
  const float* up_b   = (const float*)d_in[14];
  const float* dn_w   = (const float*)d_in[15];
  const float* dn_b   = (const float*)d_in[16];
  const float* post_w = (const float*)d_in[17];
  const float* post_b = (const float*)d_in[18];
  const float* W_proj = (const float*)d_in[19];
  const float* b_proj = (const float*)d_in[20];
  float* out = (float*)d_out;

  const size_t oWu   = 0;          // [2][768][256] bf16 : 1,572,864
  const size_t oWd   = 1572864;    // [2][256][384] bf16 :   786,432
  const size_t oWg2  = 2359296;    // [2][8][128][64] bf16 :  262,144
  const size_t oRgt  = 2621440;    // [2][16][64][64] bf16 :  524,288
  const size_t oWp   = 3145728;    // [96][16128] bf16 : 3,096,576
  const size_t oChunk = 6242304;
  const size_t per_seq = (size_t)3584*NS;   // 225,792 B
  int Nc = 0;
  const int cands[3] = {1024, 512, 256};   // nc*63 must be multiple of 256
  for (int i = 0; i < 3; ++i)
    if (oChunk + (size_t)cands[i]*per_seq <= ws_size){ Nc = cands[i]; break; }
  if (Nc == 0) return;

  char* wsb = (char*)d_ws;
  u16* Wu   = (u16*)(wsb + oWu);
  u16* Wd   = (u16*)(wsb + oWd);
  u16* Wg2  = (u16*)(wsb + oWg2);
  u16* Rgt  = (u16*)(wsb + oRgt);
  u16* Wtp  = (u16*)(wsb + oWp);

  for (int blk = 0; blk < 2; ++blk){
    cvt_transpose_t<<<dim3(8, 24), 256, 0, stream>>>(
        up_w + (size_t)blk*256*768, Wu + (size_t)blk*768*256, 256, 768);
    cvt_transpose_t<<<dim3(12, 8), 256, 0, stream>>>(
        dn_w + (size_t)blk*384*256, Wd + (size_t)blk*256*384, 384, 256);
  }
  cvt_gateW2<<<16, 256, 0, stream>>>(Wg, Wg2);
  cvt_gate<<<32, 256, 0, stream>>>(Rg, Rgt);
  cvt_transpose_t<<<dim3(504, 3), 256, 0, stream>>>(W_proj, Wtp, 16128, 96);

  for (int n0 = 0; n0 < NSEQ; n0 += Nc){
    const int    nc  = (NSEQ - n0 < Nc) ? (NSEQ - n0) : Nc;
    const size_t Tc  = (size_t)nc * NS;
    char* cb = wsb + oChunk;
    u16*   h_c   = (u16*)cb;                          // Tc*512 B
    u16*   bufA  = (u16*)(cb + Tc*512);               // Tc*512 B
    u16*   bufB  = (u16*)(cb + Tc*1024);              // Tc*512 B
    u16*   gates = (u16*)(cb + Tc*1536);              // Tc*2048 B
    u16*   gp    = gates;                             // reuse (Tc*768 B)
    float* ptmp  = (float*)(cb + Tc*1536 + Tc*1024);  // overlay in gates tail
    const int t_base = n0*NS;
    const int Tci = (int)Tc;

    patch_embed_ln_v<<<Tci/4, 256, 0, stream>>>(
        x, W_emb, b_emb, ln1_w, ln1_b, h_c, bufA, t_base);

    for (int blk = 0; blk < 2; ++blk){
      if (blk == 1)
        layernorm_v<<<Tci/4, 256, 0, stream>>>(h_c, ln1_w + DDIM, ln1_b + DDIM, bufA);
      conv_silu_v<<<Tci/4, 256, 0, stream>>>(bufA, conv_w + blk*4*DDIM, conv_b + blk*DDIM, bufB);
      mfma_gate2<<<dim3(Tci/128, 8), 256, 0, stream>>>(
          bufB, bufA, Wg2 + (size_t)blk*8*8192, gb + blk*4*DDIM, gates);
      slstm_scan4<<<dim3(nc/16, NHEAD), 256, 0, stream>>>(
          gates, Rgt + (size_t)blk*16*4096, bufB);
      gn_res_ln_v<<<Tci/4, 256, 0, stream>>>(
          bufB, gn_w + blk*DDIM, ln2_w + blk*DDIM, ln2_b + blk*DDIM, h_c, bufA);
      mfma_up_gelu3<<<dim3(Tci/256, 6), 256, 0, stream>>>(
          bufA, Wu + (size_t)blk*768*256, up_b + blk*2*UPDIM, gp);
      mfma_gemm2<256,128,4,1,4,8,1><<<dim3(Tci/256, 2), 256, 0, stream>>>(
          gp, UPDIM, Wd + (size_t)blk*256*384, UPDIM,
          dn_b + blk*DDIM, (void*)h_c, DDIM, 12, 0, 0);
    }

    layernorm_v<<<Tci/4, 256, 0, stream>>>(h_c, post_w, post_b, bufA);
    mfma_gemm2<64,96,2,2,2,3,2><<<dim3(nc/64, 1, KC_PROJ), 256, 0, stream>>>(
        bufA, NS*DDIM, Wtp, NS*DDIM,
        b_proj, (void*)ptmp, PREDN, KCHUNK_PROJ/32, KCHUNK_PROJ, nc);
    proj_out<<<(nc*PREDN + 255)/256, 256, 0, stream>>>(ptmp, b_proj, out, nc, n0);
  }
}

// Round 9
// 760.064 us; speedup vs baseline: 4.1501x; 1.0391x over previous
//
#include <hip/hip_runtime.h>
#include <stdint.h>

typedef unsigned short u16;
typedef unsigned int   u32;
typedef __attribute__((ext_vector_type(8))) short bf16x8;
typedef __attribute__((ext_vector_type(4))) float f32x4;

#define NS      63
#define NSEQ    1024
#define DDIM    256
#define NHEAD   4
#define DHEAD   64
#define UPDIM   384
#define PREDN   96
#define LLEN    512
#define CCH     32
#define PSIZE   16
#define PSTRIDE 8
#define KC_PROJ 8
#define KCHUNK_PROJ 2016

__device__ __forceinline__ float bf2f(u32 lo16){
  union { u32 i; float f; } v; v.i = lo16 << 16; return v.f;
}
__device__ __forceinline__ float bf2f_hi(u32 u){
  union { u32 i; float f; } v; v.i = u & 0xffff0000u; return v.f;
}
__device__ __forceinline__ u16 f2bf(float f){
  union { u32 i; float f; } v; v.f = f;
  u32 u = v.i; u += 0x7fffu + ((u >> 16) & 1u);
  return (u16)(u >> 16);
}

__device__ __forceinline__ void gload16(const u16* g, u16* lds){
  __builtin_amdgcn_global_load_lds(
      (const __attribute__((address_space(1))) u32*)g,
      (__attribute__((address_space(3))) u32*)lds, 16, 0, 0);
}

template<int N> __device__ __forceinline__ void waitcnt_vm(){
  if constexpr (N == 0) asm volatile("s_waitcnt vmcnt(0)" ::: "memory");
  else if constexpr (N == 4) asm volatile("s_waitcnt vmcnt(4)" ::: "memory");
  else if constexpr (N == 6) asm volatile("s_waitcnt vmcnt(6)" ::: "memory");
}

// ---------------- LDS-tiled transpose: dst[c][r] = bf16(src[r][c]) -----------------
__global__ __launch_bounds__(256) void cvt_transpose_t(
    const float* __restrict__ src, u16* __restrict__ dst, int R, int C){
  __shared__ u16 tile[32][33];
  int rb = blockIdx.x*32, cb = blockIdx.y*32;
  int tx = threadIdx.x & 31, ty = threadIdx.x >> 5;
  #pragma unroll
  for (int i = ty; i < 32; i += 8){
    int r = rb + i, c = cb + tx;
    tile[i][tx] = (r < R && c < C) ? f2bf(src[(size_t)r*C + c]) : (u16)0;
  }
  __syncthreads();
  #pragma unroll
  for (int i = ty; i < 32; i += 8){
    int c = cb + i, r = rb + tx;
    if (c < C && r < R) dst[(size_t)c*R + r] = tile[tx][i];
  }
}

__global__ __launch_bounds__(256) void cvt_gate(
    const float* __restrict__ src, u16* __restrict__ dst){
  int mat = blockIdx.x, t = threadIdx.x;
  const float* s = src + (size_t)mat*4096;
  u16* d = dst + (size_t)mat*4096;
  for (int i = t; i < 4096; i += 256){
    int r = i >> 6, c = i & 63;
    d[c*64 + r] = f2bf(s[i]);
  }
}

// gate weight true-K layout, col order n = e*2+gl: dst[(blk*2+p)*4+hd][n][k]
__global__ __launch_bounds__(256) void cvt_gateW2(
    const float* __restrict__ Wg, u16* __restrict__ dst){
  int mi = blockIdx.x;
  int blk = mi >> 3, p = (mi >> 2) & 1, hd = mi & 3;
  u16* d = dst + (size_t)mi*8192;
  for (int i = threadIdx.x; i < 8192; i += 256){
    int n = i >> 6, k = i & 63;
    int e = n >> 1, gl = n & 1;
    int g = 2*p + gl;
    d[i] = f2bf(Wg[((((size_t)blk*4 + g)*4 + hd)*64 + k)*64 + e]);
  }
}

// ---------------- patch embedding + ln1(blk0), wave = token, vectorized ------------
__global__ __launch_bounds__(256) void patch_embed_ln_v(
    const float* __restrict__ x, const float* __restrict__ Wemb,
    const float* __restrict__ bemb, const float* __restrict__ w1,
    const float* __restrict__ b1, u16* __restrict__ h,
    u16* __restrict__ outA, int t_base){
  int wv = blockIdx.x*4 + (threadIdx.x >> 6);
  int lane = threadIdx.x & 63;
  int tg = t_base + wv;
  int n = tg / NS, s = tg - n*NS;
  int b = n >> 5, c = n & 31;
  int l0 = s * PSTRIDE;
  float4 acc = *(const float4*)(bemb + lane*4);
  #pragma unroll
  for (int p = 0; p < PSIZE; ++p){
    float xv = x[((size_t)b*LLEN + l0 + p)*CCH + c];
    float4 we = *(const float4*)(Wemb + p*DDIM + lane*4);
    acc.x += xv*we.x; acc.y += xv*we.y; acc.z += xv*we.z; acc.w += xv*we.w;
  }
  ushort4 hu; hu.x=f2bf(acc.x); hu.y=f2bf(acc.y); hu.z=f2bf(acc.z); hu.w=f2bf(acc.w);
  *(ushort4*)(h + (size_t)wv*DDIM + lane*4) = hu;
  float s1 = acc.x+acc.y+acc.z+acc.w;
  float s2 = acc.x*acc.x+acc.y*acc.y+acc.z*acc.z+acc.w*acc.w;
  #pragma unroll
  for (int o = 1; o < 64; o <<= 1){ s1 += __shfl_xor(s1,o,64); s2 += __shfl_xor(s2,o,64); }
  float mu = s1*(1.f/DDIM);
  float var = s2*(1.f/DDIM) - mu*mu;
  float rstd = rsqrtf(var + 1e-5f);
  float4 wf = *(const float4*)(w1 + lane*4);
  float4 bf = *(const float4*)(b1 + lane*4);
  ushort4 o4;
  o4.x = f2bf((acc.x-mu)*rstd*wf.x + bf.x);
  o4.y = f2bf((acc.y-mu)*rstd*wf.y + bf.y);
  o4.z = f2bf((acc.z-mu)*rstd*wf.z + bf.z);
  o4.w = f2bf((acc.w-mu)*rstd*wf.w + bf.w);
  *(ushort4*)(outA + (size_t)wv*DDIM + lane*4) = o4;
}

// ---------------- layernorm, wave = token, vectorized ------------------------------
__global__ __launch_bounds__(256) void layernorm_v(
    const u16* __restrict__ in, const float* __restrict__ w,
    const float* __restrict__ b, u16* __restrict__ out){
  int wv = blockIdx.x*4 + (threadIdx.x >> 6);
  int lane = threadIdx.x & 63;
  ushort4 u = *(const ushort4*)(in + (size_t)wv*DDIM + lane*4);
  float v0=bf2f(u.x), v1=bf2f(u.y), v2=bf2f(u.z), v3=bf2f(u.w);
  float s1 = v0+v1+v2+v3, s2 = v0*v0+v1*v1+v2*v2+v3*v3;
  #pragma unroll
  for (int o = 1; o < 64; o <<= 1){ s1 += __shfl_xor(s1,o,64); s2 += __shfl_xor(s2,o,64); }
  float mu = s1*(1.f/DDIM);
  float var = s2*(1.f/DDIM) - mu*mu;
  float rstd = rsqrtf(var + 1e-5f);
  float4 wf = *(const float4*)(w + lane*4);
  float4 bf = *(const float4*)(b + lane*4);
  ushort4 o4;
  o4.x = f2bf((v0-mu)*rstd*wf.x + bf.x);
  o4.y = f2bf((v1-mu)*rstd*wf.y + bf.y);
  o4.z = f2bf((v2-mu)*rstd*wf.z + bf.z);
  o4.w = f2bf((v3-mu)*rstd*wf.w + bf.w);
  *(ushort4*)(out + (size_t)wv*DDIM + lane*4) = o4;
}

// ---------------- fused groupnorm + residual + layernorm, vectorized ---------------
__global__ __launch_bounds__(256) void gn_res_ln_v(
    const u16* __restrict__ y, const float* __restrict__ gnw,
    const float* __restrict__ w2, const float* __restrict__ b2,
    u16* __restrict__ h, u16* __restrict__ outA){
  int wv = blockIdx.x*4 + (threadIdx.x >> 6);
  int lane = threadIdx.x & 63;
  ushort4 u = *(const ushort4*)(y + (size_t)wv*DDIM + lane*4);
  float v0=bf2f(u.x), v1=bf2f(u.y), v2=bf2f(u.z), v3=bf2f(u.w);
  float s1 = v0+v1+v2+v3, s2 = v0*v0+v1*v1+v2*v2+v3*v3;
  #pragma unroll
  for (int o = 1; o < 16; o <<= 1){ s1 += __shfl_xor(s1,o,64); s2 += __shfl_xor(s2,o,64); }
  float mu64 = s1*(1.f/64.f);
  float var64 = s2*(1.f/64.f) - mu64*mu64;
  float rstd64 = rsqrtf(var64 + 1e-5f);
  float4 gw = *(const float4*)(gnw + lane*4);
  ushort4 hu = *(const ushort4*)(h + (size_t)wv*DDIM + lane*4);
  float h0 = bf2f(hu.x) + (v0-mu64)*rstd64*gw.x;
  float h1 = bf2f(hu.y) + (v1-mu64)*rstd64*gw.y;
  float h2 = bf2f(hu.z) + (v2-mu64)*rstd64*gw.z;
  float h3 = bf2f(hu.w) + (v3-mu64)*rstd64*gw.w;
  ushort4 hn; hn.x=f2bf(h0); hn.y=f2bf(h1); hn.z=f2bf(h2); hn.w=f2bf(h3);
  *(ushort4*)(h + (size_t)wv*DDIM + lane*4) = hn;
  float t1 = h0+h1+h2+h3, t2 = h0*h0+h1*h1+h2*h2+h3*h3;
  #pragma unroll
  for (int o = 1; o < 64; o <<= 1){ t1 += __shfl_xor(t1,o,64); t2 += __shfl_xor(t2,o,64); }
  float mu = t1*(1.f/DDIM);
  float var = t2*(1.f/DDIM) - mu*mu;
  float rstd = rsqrtf(var + 1e-5f);
  float4 wf = *(const float4*)(w2 + lane*4);
  float4 bf = *(const float4*)(b2 + lane*4);
  ushort4 o4;
  o4.x = f2bf((h0-mu)*rstd*wf.x + bf.x);
  o4.y = f2bf((h1-mu)*rstd*wf.y + bf.y);
  o4.z = f2bf((h2-mu)*rstd*wf.z + bf.z);
  o4.w = f2bf((h3-mu)*rstd*wf.w + bf.w);
  *(ushort4*)(outA + (size_t)wv*DDIM + lane*4) = o4;
}

// ---------------- causal depthwise conv K=4 + SiLU, vectorized ---------------------
__global__ __launch_bounds__(256) void conv_silu_v(
    const u16* __restrict__ xln, const float* __restrict__ cw,
    const float* __restrict__ cb, u16* __restrict__ xc){
  int wv = blockIdx.x*4 + (threadIdx.x >> 6);
  int lane = threadIdx.x & 63;
  int s = wv % NS;
  float4 acc = *(const float4*)(cb + lane*4);
  #pragma unroll
  for (int k = 0; k < 4; ++k){
    int ss = s + k - 3;
    if (ss >= 0){
      ushort4 xu = *(const ushort4*)(xln + (size_t)(wv + k - 3)*DDIM + lane*4);
      float4 cv = *(const float4*)(cw + k*DDIM + lane*4);
      acc.x += bf2f(xu.x)*cv.x; acc.y += bf2f(xu.y)*cv.y;
      acc.z += bf2f(xu.z)*cv.z; acc.w += bf2f(xu.w)*cv.w;
    }
  }
  ushort4 o4;
  o4.x = f2bf(acc.x/(1.f + __expf(-acc.x)));
  o4.y = f2bf(acc.y/(1.f + __expf(-acc.y)));
  o4.z = f2bf(acc.z/(1.f + __expf(-acc.z)));
  o4.w = f2bf(acc.w/(1.f + __expf(-acc.w)));
  *(ushort4*)(xc + (size_t)wv*DDIM + lane*4) = o4;
}

// ---------------- generic MFMA GEMM ------------------------------------------------
// grid: blockIdx.x = n-tile (fast), blockIdx.y = m-tile
// MODE 1: bf16 out += acc + bias (RMW);  MODE 2: fp32 ptmp[(kc*Mtot+row)*ldo+col]=acc
// VM > 0: counted-vmcnt raw-barrier pipeline (VM = per-wave loads per stage)
template<int BM,int BN,int WR,int WC,int MR,int NR,int MODE,int VM>
__global__ __launch_bounds__(256) void mfma_gemm2(
    const u16* __restrict__ A, int lda,
    const u16* __restrict__ Wt, int ldwt,
    const float* __restrict__ bias, void* __restrict__ outp, int ldo,
    int ksteps, int kchunk, int Mtot)
{
  constexpr int nA = BM/16, nW = BN/16;
  __shared__ u16 As[2][BM*32];
  __shared__ u16 Ws[2][BN*32];
  const int tid = threadIdx.x;
  const int lane = tid & 63, wid = tid >> 6;
  const int wr = wid / WC, wc = wid % WC;
  const int fr = lane & 15, kb = lane >> 4;
  const int m0 = blockIdx.y*BM, n0 = blockIdx.x*BN;
  const int kc = blockIdx.z;
  const int kbeg = kc*kchunk;
  const u16* Ab = A + (size_t)m0*lda + kbeg;
  const u16* Wb = Wt + (size_t)n0*ldwt + kbeg;
  const int lrow = lane >> 2, lcol = (lane & 3)*8;

  auto stage = [&](int buf, int ks){
    int k0 = ks*32;
    for (int c = wid; c < nA; c += 4)
      gload16(Ab + (size_t)(c*16 + lrow)*lda + k0 + lcol, &As[buf][c*512]);
    for (int c = wid; c < nW; c += 4)
      gload16(Wb + (size_t)(c*16 + lrow)*ldwt + k0 + lcol, &Ws[buf][c*512]);
  };

  f32x4 acc[MR][NR];
  #pragma unroll
  for (int m=0;m<MR;++m)
    #pragma unroll
    for (int n=0;n<NR;++n) acc[m][n] = (f32x4){0.f,0.f,0.f,0.f};

  stage(0, 0);
  if (VM == 0) __syncthreads();
  int cur = 0;
  for (int ks = 0; ks < ksteps; ++ks){
    if (VM == 0){
      if (ks + 1 < ksteps) stage(cur^1, ks+1);
    } else {
      if (ks + 1 < ksteps){ stage(cur^1, ks+1); waitcnt_vm<VM>(); }
      else waitcnt_vm<0>();
      __builtin_amdgcn_s_barrier();
      asm volatile("" ::: "memory");
    }
    bf16x8 af[MR], wf[NR];
    #pragma unroll
    for (int m=0;m<MR;++m)
      af[m] = *(const bf16x8*)&As[cur][(wr*MR*16 + m*16 + fr)*32 + kb*8];
    #pragma unroll
    for (int n=0;n<NR;++n)
      wf[n] = *(const bf16x8*)&Ws[cur][(wc*NR*16 + n*16 + fr)*32 + kb*8];
    #pragma unroll
    for (int m=0;m<MR;++m)
      #pragma unroll
      for (int n=0;n<NR;++n)
        acc[m][n] = __builtin_amdgcn_mfma_f32_16x16x32_bf16(af[m], wf[n], acc[m][n], 0,0,0);
    if (VM == 0){
      __syncthreads();
    } else {
      asm volatile("" ::: "memory");
      __builtin_amdgcn_s_barrier();
    }
    cur ^= 1;
  }
  #pragma unroll
  for (int m=0;m<MR;++m){
    int rowb = m0 + wr*MR*16 + m*16 + kb*4;
    #pragma unroll
    for (int n=0;n<NR;++n){
      int col = n0 + wc*NR*16 + n*16 + fr;
      #pragma unroll
      for (int r=0;r<4;++r){
        int row = rowb + r;
        float v = acc[m][n][r];
        if (MODE == 1){
          u16* dst = (u16*)outp + (size_t)row*ldo + col;
          *dst = f2bf(bf2f(*dst) + v + bias[col]);
        } else {
          ((float*)outp)[((size_t)kc*Mtot + row)*ldo + col] = v;
        }
      }
    }
  }
}

// ---------------- gate GEMM, counted vmcnt, grid (8, m-tiles) ----------------------
__global__ __launch_bounds__(256) void mfma_gate2(
    const u16* __restrict__ xc, const u16* __restrict__ xh,
    const u16* __restrict__ Wg2, const float* __restrict__ gb,
    u16* __restrict__ gates)
{
  __shared__ u16 As[2][128*32];
  __shared__ u16 Ws[2][128*32];
  const int tid = threadIdx.x;
  const int lane = tid & 63, wid = tid >> 6;
  const int wr = wid >> 1, wc = wid & 1;
  const int fr = lane & 15, kb = lane >> 4;
  const int p = blockIdx.x >> 2, hd = blockIdx.x & 3;
  const int m0 = blockIdx.y*128;
  const u16* Ain = (p == 0) ? xc : xh;
  const u16* Wb = Wg2 + (size_t)blockIdx.x*8192;
  const int lrow = lane >> 2, lcol = (lane & 3)*8;

  auto stage = [&](int buf, int ks){
    int k0 = ks*32;
    for (int c = wid; c < 8; c += 4)
      gload16(Ain + (size_t)(m0 + c*16 + lrow)*DDIM + hd*64 + k0 + lcol, &As[buf][c*512]);
    for (int c = wid; c < 8; c += 4)
      gload16(Wb + (size_t)(c*16 + lrow)*64 + k0 + lcol, &Ws[buf][c*512]);
  };

  f32x4 acc[4][4];
  #pragma unroll
  for (int m=0;m<4;++m)
    #pragma unroll
    for (int n=0;n<4;++n) acc[m][n] = (f32x4){0.f,0.f,0.f,0.f};

  stage(0, 0);
  int cur = 0;
  #pragma unroll
  for (int ks = 0; ks < 2; ++ks){
    if (ks == 0){ stage(1, 1); waitcnt_vm<4>(); }
    else waitcnt_vm<0>();
    __builtin_amdgcn_s_barrier();
    asm volatile("" ::: "memory");
    bf16x8 af[4], wf[4];
    #pragma unroll
    for (int m=0;m<4;++m)
      af[m] = *(const bf16x8*)&As[cur][(wr*64 + m*16 + fr)*32 + kb*8];
    #pragma unroll
    for (int n=0;n<4;++n)
      wf[n] = *(const bf16x8*)&Ws[cur][(wc*64 + n*16 + fr)*32 + kb*8];
    #pragma unroll
    for (int m=0;m<4;++m)
      #pragma unroll
      for (int n=0;n<4;++n)
        acc[m][n] = __builtin_amdgcn_mfma_f32_16x16x32_bf16(af[m], wf[n], acc[m][n], 0,0,0);
    asm volatile("" ::: "memory");
    __builtin_amdgcn_s_barrier();
    cur ^= 1;
  }
  #pragma unroll
  for (int m=0;m<4;++m){
    int rowb = m0 + wr*64 + m*16 + kb*4;
    #pragma unroll
    for (int n=0;n<4;++n){
      int cl = wc*64 + n*16 + fr;
      int e = cl >> 1, gl = cl & 1;
      float bv = gb[(2*p + gl)*256 + hd*64 + e];
      int phys = hd*256 + p*128 + cl;
      #pragma unroll
      for (int r=0;r<4;++r)
        gates[(size_t)(rowb + r)*1024 + phys] = f2bf(acc[m][n][r] + bv);
    }
  }
}

// ---------------- FFN up + fast gelu*g2, BM=256, counted vmcnt, grid (6, m) --------
__global__ __launch_bounds__(256) void mfma_up_gelu3(
    const u16* __restrict__ A, const u16* __restrict__ Wt,
    const float* __restrict__ ub, u16* __restrict__ gp)
{
  __shared__ u16 As[2][256*32];
  __shared__ u16 Ws[2][128*32];
  const int tid = threadIdx.x;
  const int lane = tid & 63, wid = tid >> 6;
  const int fr = lane & 15, kb = lane >> 4;
  const int m0 = blockIdx.y*256, n0 = blockIdx.x*64;
  const u16* W1 = Wt + (size_t)n0*256;
  const u16* W2 = Wt + (size_t)(384 + n0)*256;
  const int lrow = lane >> 2, lcol = (lane & 3)*8;

  auto stage = [&](int buf, int ks){
    int k0 = ks*32;
    for (int c = wid; c < 16; c += 4)
      gload16(A + (size_t)(m0 + c*16 + lrow)*256 + k0 + lcol, &As[buf][c*512]);
    for (int c = wid; c < 8; c += 4){
      const u16* src = (c < 4) ? (W1 + (size_t)(c*16 + lrow)*256)
                               : (W2 + (size_t)((c-4)*16 + lrow)*256);
      gload16(src + k0 + lcol, &Ws[buf][c*512]);
    }
  };

  f32x4 a1[4][4], a2[4][4];
  #pragma unroll
  for (int m=0;m<4;++m)
    #pragma unroll
    for (int n=0;n<4;++n){ a1[m][n]=(f32x4){0,0,0,0}; a2[m][n]=(f32x4){0,0,0,0}; }

  stage(0, 0);
  int cur = 0;
  #pragma unroll
  for (int ks = 0; ks < 8; ++ks){
    if (ks + 1 < 8){ stage(cur^1, ks+1); waitcnt_vm<6>(); }
    else waitcnt_vm<0>();
    __builtin_amdgcn_s_barrier();
    asm volatile("" ::: "memory");
    bf16x8 af[4], wf1[4], wf2[4];
    #pragma unroll
    for (int m=0;m<4;++m)
      af[m] = *(const bf16x8*)&As[cur][(wid*64 + m*16 + fr)*32 + kb*8];
    #pragma unroll
    for (int n=0;n<4;++n){
      wf1[n] = *(const bf16x8*)&Ws[cur][(n*16 + fr)*32 + kb*8];
      wf2[n] = *(const bf16x8*)&Ws[cur][(64 + n*16 + fr)*32 + kb*8];
    }
    #pragma unroll
    for (int m=0;m<4;++m)
      #pragma unroll
      for (int n=0;n<4;++n){
        a1[m][n] = __builtin_amdgcn_mfma_f32_16x16x32_bf16(af[m], wf1[n], a1[m][n], 0,0,0);
        a2[m][n] = __builtin_amdgcn_mfma_f32_16x16x32_bf16(af[m], wf2[n], a2[m][n], 0,0,0);
      }
    asm volatile("" ::: "memory");
    __builtin_amdgcn_s_barrier();
    cur ^= 1;
  }
  #pragma unroll
  for (int m=0;m<4;++m){
    int rowb = m0 + wid*64 + m*16 + kb*4;
    #pragma unroll
    for (int n=0;n<4;++n){
      int col = n0 + n*16 + fr;
      float b1 = ub[col], b2 = ub[384 + col];
      #pragma unroll
      for (int r=0;r<4;++r){
        float g1 = a1[m][n][r] + b1;
        float g2 = a2[m][n][r] + b2;
        float u  = 0.7978845608028654f*(g1 + 0.044715f*g1*g1*g1);
        float uc = fminf(fmaxf(u, -20.f), 20.f);
        float t2 = __expf(uc + uc);
        float th = (t2 - 1.f)/(t2 + 1.f);
        float ge = 0.5f*g1*(1.f + th);
        gp[(size_t)(rowb + r)*UPDIM + col] = f2bf(ge*g2);
      }
    }
  }
}

// ---------------- sLSTM scan v4 (unchanged) ----------------------------------------
__global__ __launch_bounds__(256) void slstm_scan4(
    const u16* __restrict__ gates, const u16* __restrict__ Rgt,
    u16* __restrict__ y)
{
  __shared__ u16 h_lds[16*72];
  __shared__ float rec_lds[4][16][68];
  const int tid = threadIdx.x;
  const int w = tid >> 6, lane = tid & 63;
  const int hd = blockIdx.y, grp = blockIdx.x;
  const int fr = lane & 15, kb = lane >> 4;
  const int seq0 = grp*16;
  const u32* g32 = (const u32*)gates;

  bf16x8 bfr[4][2];
  {
    const u16* rb = Rgt + (size_t)(w*NHEAD + hd)*4096;
    #pragma unroll
    for (int n=0;n<4;++n)
      #pragma unroll
      for (int ks=0;ks<2;++ks)
        bfr[n][ks] = *(const bf16x8*)(rb + (size_t)(n*16 + fr)*64 + ks*32 + kb*8);
  }
  for (int i = tid; i < 16*72/2; i += 256) ((u32*)h_lds)[i] = 0u;
  float c[4]={0,0,0,0}, nst[4]={0,0,0,0}, m[4]={0,0,0,0};

  size_t gb4[4];
  #pragma unroll
  for (int si=0; si<4; ++si)
    gb4[si] = ((size_t)(seq0 + 4*w + si)*NS)*512 + hd*128 + lane;

  u32 g0[4][2], g1[4][2];
  #pragma unroll
  for (int si=0; si<4; ++si){
    g0[si][0] = g32[gb4[si]];        g0[si][1] = g32[gb4[si] + 64];
    g1[si][0] = g32[gb4[si] + 512];  g1[si][1] = g32[gb4[si] + 576];
  }
  __syncthreads();

  for (int s = 0; s < NS; ++s){
    u32 gn[4][2] = {};
    if (s + 2 < NS){
      #pragma unroll
      for (int si=0; si<4; ++si){
        size_t b2 = gb4[si] + (size_t)(s+2)*512;
        gn[si][0] = g32[b2];
        gn[si][1] = g32[b2 + 64];
      }
    }
    bf16x8 af0 = *(const bf16x8*)&h_lds[fr*72 + kb*8];
    bf16x8 af1 = *(const bf16x8*)&h_lds[fr*72 + 32 + kb*8];
    f32x4 acc[4];
    #pragma unroll
    for (int n=0;n<4;++n){
      acc[n] = (f32x4){0,0,0,0};
      acc[n] = __builtin_amdgcn_mfma_f32_16x16x32_bf16(af0, bfr[n][0], acc[n], 0,0,0);
      acc[n] = __builtin_amdgcn_mfma_f32_16x16x32_bf16(af1, bfr[n][1], acc[n], 0,0,0);
    }
    #pragma unroll
    for (int n=0;n<4;++n)
      #pragma unroll
      for (int r=0;r<4;++r)
        rec_lds[w][kb*4 + r][n*16 + fr] = acc[n][r];
    asm volatile("s_waitcnt lgkmcnt(0)" ::: "memory");
    __builtin_amdgcn_s_barrier();
    #pragma unroll
    for (int si=0; si<4; ++si){
      int sidx = 4*w + si;
      float ip = rec_lds[0][sidx][lane] + bf2f(g0[si][0] & 0xffffu);
      float fp = rec_lds[1][sidx][lane] + bf2f_hi(g0[si][0]);
      float zp = rec_lds[2][sidx][lane] + bf2f(g0[si][1] & 0xffffu);
      float op = rec_lds[3][sidx][lane] + bf2f_hi(g0[si][1]);
      float sp  = __logf(1.f + __expf(-fabsf(fp)));
      float lg  = m[si] + fminf(fp, 0.f) - sp;
      float mn  = fmaxf(ip, lg);
      float iv  = __expf(ip - mn);
      float fv  = __expf(lg - mn);
      float zz  = fminf(fabsf(zp), 15.f);
      float t2  = __expf(zz + zz);
      float tha = (t2 - 1.f)/(t2 + 1.f);
      float th  = (zp >= 0.f) ? tha : -tha;
      c[si]   = fv*c[si] + iv*th;
      nst[si] = fv*nst[si] + iv;
      m[si]   = mn;
      float hv = c[si] * __builtin_amdgcn_rcpf(nst[si]*(1.f + __expf(-op)));
      h_lds[sidx*72 + lane] = f2bf(hv);
      size_t t = (size_t)(seq0 + sidx)*NS + s;
      y[t*DDIM + hd*64 + lane] = f2bf(hv);
    }
    asm volatile("s_waitcnt lgkmcnt(0)" ::: "memory");
    __builtin_amdgcn_s_barrier();
    #pragma unroll
    for (int si=0; si<4; ++si){
      g0[si][0] = g1[si][0]; g0[si][1] = g1[si][1];
      g1[si][0] = gn[si][0]; g1[si][1] = gn[si][1];
    }
  }
}

// ---------------- proj reduce over K-split slices ----------------------------------
__global__ __launch_bounds__(256) void proj_out(
    const float* __restrict__ ptmp, const float* __restrict__ bproj,
    float* __restrict__ out, int Nc, int n0glob){
  int gid = blockIdx.x*256 + threadIdx.x;
  if (gid >= Nc*PREDN) return;
  float acc = 0.f;
  #pragma unroll
  for (int kc = 0; kc < KC_PROJ; ++kc) acc += ptmp[(size_t)kc*Nc*PREDN + gid];
  int nl = gid / PREDN, j = gid - nl*PREDN;
  int n = n0glob + nl;
  out[((size_t)(n >> 5)*PREDN + j)*CCH + (n & 31)] = acc + bproj[j];
}

extern "C" void kernel_launch(void* const* d_in, const int* in_sizes, int n_in,
                              void* d_out, int out_size, void* d_ws, size_t ws_size,
                              hipStream_t stream) {
  const float* x      = (const float*)d_in[0];
  const float* W_emb  = (const float*)d_in[1];
  const float* b_emb  = (const float*)d_in[2];
  const float* ln1_w  = (const float*)d_in[3];
  const float* ln1_b  = (const float*)d_in[4];
  const float* conv_w = (const float*)d_in[5];
  const float* conv_b = (const float*)d_in[6];
  const float* Wg     = (const float*)d_in[7];
  const float* Rg     = (const float*)d_in[8];
  const float* gb     = (const float*)d_in[9];
  const float* gn_w   = (const float*)d_in[10];
  const float* ln2_w  = (const float*)d_in[11];
  const float* ln2_b  = (const float*)d_in[12];
  const float* up_w   = (const float*)d_in[13];
  const float* up_b   = (const float*)d_in[14];
  const float* dn_w   = (const float*)d_in[15];
  const float* dn_b   = (const float*)d_in[16];
  const float* post_w = (const float*)d_in[17];
  const float* post_b = (const float*)d_in[18];
  const float* W_proj = (const float*)d_in[19];
  const float* b_proj = (const float*)d_in[20];
  float* out = (float*)d_out;

  const size_t oWu   = 0;          // [2][768][256] bf16 : 1,572,864
  const size_t oWd   = 1572864;    // [2][256][384] bf16 :   786,432
  const size_t oWg2  = 2359296;    // [2][8][128][64] bf16 :  262,144
  const size_t oRgt  = 2621440;    // [2][16][64][64] bf16 :  524,288
  const size_t oWp   = 3145728;    // [96][16128] bf16 : 3,096,576
  const size_t oChunk = 6242304;
  const size_t per_seq = (size_t)3584*NS;   // 225,792 B
  int Nc = 0;
  const int cands[3] = {1024, 512, 256};
  for (int i = 0; i < 3; ++i)
    if (oChunk + (size_t)cands[i]*per_seq <= ws_size){ Nc = cands[i]; break; }
  if (Nc == 0) return;

  char* wsb = (char*)d_ws;
  u16* Wu   = (u16*)(wsb + oWu);
  u16* Wd   = (u16*)(wsb + oWd);
  u16* Wg2  = (u16*)(wsb + oWg2);
  u16* Rgt  = (u16*)(wsb + oRgt);
  u16* Wtp  = (u16*)(wsb + oWp);

  for (int blk = 0; blk < 2; ++blk){
    cvt_transpose_t<<<dim3(8, 24), 256, 0, stream>>>(
        up_w + (size_t)blk*256*768, Wu + (size_t)blk*768*256, 256, 768);
    cvt_transpose_t<<<dim3(12, 8), 256, 0, stream>>>(
        dn_w + (size_t)blk*384*256, Wd + (size_t)blk*256*384, 384, 256);
  }
  cvt_gateW2<<<16, 256, 0, stream>>>(Wg, Wg2);
  cvt_gate<<<32, 256, 0, stream>>>(Rg, Rgt);
  cvt_transpose_t<<<dim3(504, 3), 256, 0, stream>>>(W_proj, Wtp, 16128, 96);

  for (int n0 = 0; n0 < NSEQ; n0 += Nc){
    const int    nc  = (NSEQ - n0 < Nc) ? (NSEQ - n0) : Nc;
    const size_t Tc  = (size_t)nc * NS;
    char* cb = wsb + oChunk;
    u16*   h_c   = (u16*)cb;                          // Tc*512 B
    u16*   bufA  = (u16*)(cb + Tc*512);               // Tc*512 B
    u16*   bufB  = (u16*)(cb + Tc*1024);              // Tc*512 B
    u16*   gates = (u16*)(cb + Tc*1536);              // Tc*2048 B
    u16*   gp    = gates;                             // reuse (Tc*768 B)
    float* ptmp  = (float*)(cb + Tc*1536 + Tc*1024);  // overlay in gates tail
    const int t_base = n0*NS;
    const int Tci = (int)Tc;

    patch_embed_ln_v<<<Tci/4, 256, 0, stream>>>(
        x, W_emb, b_emb, ln1_w, ln1_b, h_c, bufA, t_base);

    for (int blk = 0; blk < 2; ++blk){
      if (blk == 1)
        layernorm_v<<<Tci/4, 256, 0, stream>>>(h_c, ln1_w + DDIM, ln1_b + DDIM, bufA);
      conv_silu_v<<<Tci/4, 256, 0, stream>>>(bufA, conv_w + blk*4*DDIM, conv_b + blk*DDIM, bufB);
      mfma_gate2<<<dim3(8, Tci/128), 256, 0, stream>>>(
          bufB, bufA, Wg2 + (size_t)blk*8*8192, gb + blk*4*DDIM, gates);
      slstm_scan4<<<dim3(nc/16, NHEAD), 256, 0, stream>>>(
          gates, Rgt + (size_t)blk*16*4096, bufB);
      gn_res_ln_v<<<Tci/4, 256, 0, stream>>>(
          bufB, gn_w + blk*DDIM, ln2_w + blk*DDIM, ln2_b + blk*DDIM, h_c, bufA);
      mfma_up_gelu3<<<dim3(6, Tci/256), 256, 0, stream>>>(
          bufA, Wu + (size_t)blk*768*256, up_b + blk*2*UPDIM, gp);
      mfma_gemm2<256,128,4,1,4,8,1,6><<<dim3(2, Tci/256), 256, 0, stream>>>(
          gp, UPDIM, Wd + (size_t)blk*256*384, UPDIM,
          dn_b + blk*DDIM, (void*)h_c, DDIM, 12, 0, 0);
    }

    layernorm_v<<<Tci/4, 256, 0, stream>>>(h_c, post_w, post_b, bufA);
    mfma_gemm2<64,96,2,2,2,3,2,0><<<dim3(1, nc/64, KC_PROJ), 256, 0, stream>>>(
        bufA, NS*DDIM, Wtp, NS*DDIM,
        b_proj, (void*)ptmp, PREDN, KCHUNK_PROJ/32, KCHUNK_PROJ, nc);
    proj_out<<<(nc*PREDN + 255)/256, 256, 0, stream>>>(ptmp, b_proj, out, nc, n0);
  }
}

// Round 11
// 731.878 us; speedup vs baseline: 4.3099x; 1.0385x over previous
//
#include <hip/hip_runtime.h>
#include <stdint.h>

typedef unsigned short u16;
typedef unsigned int   u32;
typedef __attribute__((ext_vector_type(8))) short bf16x8;
typedef __attribute__((ext_vector_type(4))) float f32x4;

#define NS      63
#define NSEQ    1024
#define DDIM    256
#define NHEAD   4
#define DHEAD   64
#define UPDIM   384
#define PREDN   96
#define LLEN    512
#define CCH     32
#define PSIZE   16
#define PSTRIDE 8
#define KC_PROJ 8
#define KCHUNK_PROJ 2016

__device__ __forceinline__ float bf2f(u32 lo16){
  union { u32 i; float f; } v; v.i = lo16 << 16; return v.f;
}
__device__ __forceinline__ float bf2f_hi(u32 u){
  union { u32 i; float f; } v; v.i = u & 0xffff0000u; return v.f;
}
__device__ __forceinline__ u16 f2bf(float f){
  union { u32 i; float f; } v; v.f = f;
  u32 u = v.i; u += 0x7fffu + ((u >> 16) & 1u);
  return (u16)(u >> 16);
}

__device__ __forceinline__ void gload16(const u16* g, u16* lds){
  __builtin_amdgcn_global_load_lds(
      (const __attribute__((address_space(1))) u32*)g,
      (__attribute__((address_space(3))) u32*)lds, 16, 0, 0);
}

template<int N> __device__ __forceinline__ void waitcnt_vm(){
  if constexpr (N == 0) asm volatile("s_waitcnt vmcnt(0)" ::: "memory");
  else if constexpr (N == 4) asm volatile("s_waitcnt vmcnt(4)" ::: "memory");
  else if constexpr (N == 6) asm volatile("s_waitcnt vmcnt(6)" ::: "memory");
}

// bijective XCD swizzle (m204): XCD c = flat&7 gets a contiguous logical range.
// logical tile order: n fastest -> sibling n-tiles of one m-group share an XCD L2.
__device__ __forceinline__ void swz_tile(int &nt, int &mt){
  int gx = gridDim.x, gy = gridDim.y;
  int nwg = gx*gy;
  int flat = blockIdx.y*gx + blockIdx.x;
  int c = flat & 7, s = flat >> 3;
  int q = nwg >> 3, r = nwg & 7;
  int base = c*q + (c < r ? c : r);
  int t = base + s;
  nt = t % gx; mt = t / gx;
}

// ---------------- LDS-tiled transpose: dst[c][r] = bf16(src[r][c]) -----------------
__global__ __launch_bounds__(256) void cvt_transpose_t(
    const float* __restrict__ src, u16* __restrict__ dst, int R, int C){
  __shared__ u16 tile[32][33];
  int rb = blockIdx.x*32, cb = blockIdx.y*32;
  int tx = threadIdx.x & 31, ty = threadIdx.x >> 5;
  #pragma unroll
  for (int i = ty; i < 32; i += 8){
    int r = rb + i, c = cb + tx;
    tile[i][tx] = (r < R && c < C) ? f2bf(src[(size_t)r*C + c]) : (u16)0;
  }
  __syncthreads();
  #pragma unroll
  for (int i = ty; i < 32; i += 8){
    int c = cb + i, r = rb + tx;
    if (c < C && r < R) dst[(size_t)c*R + r] = tile[tx][i];
  }
}

__global__ __launch_bounds__(256) void cvt_gate(
    const float* __restrict__ src, u16* __restrict__ dst){
  int mat = blockIdx.x, t = threadIdx.x;
  const float* s = src + (size_t)mat*4096;
  u16* d = dst + (size_t)mat*4096;
  for (int i = t; i < 4096; i += 256){
    int r = i >> 6, c = i & 63;
    d[c*64 + r] = f2bf(s[i]);
  }
}

// gate weight true-K layout, col order n = e*2+gl: dst[(blk*2+p)*4+hd][n][k]
__global__ __launch_bounds__(256) void cvt_gateW2(
    const float* __restrict__ Wg, u16* __restrict__ dst){
  int mi = blockIdx.x;
  int blk = mi >> 3, p = (mi >> 2) & 1, hd = mi & 3;
  u16* d = dst + (size_t)mi*8192;
  for (int i = threadIdx.x; i < 8192; i += 256){
    int n = i >> 6, k = i & 63;
    int e = n >> 1, gl = n & 1;
    int g = 2*p + gl;
    d[i] = f2bf(Wg[((((size_t)blk*4 + g)*4 + hd)*64 + k)*64 + e]);
  }
}

// ---------------- patch embedding + ln1(blk0), wave = token, vectorized ------------
__global__ __launch_bounds__(256) void patch_embed_ln_v(
    const float* __restrict__ x, const float* __restrict__ Wemb,
    const float* __restrict__ bemb, const float* __restrict__ w1,
    const float* __restrict__ b1, u16* __restrict__ h,
    u16* __restrict__ outA, int t_base){
  int wv = blockIdx.x*4 + (threadIdx.x >> 6);
  int lane = threadIdx.x & 63;
  int tg = t_base + wv;
  int n = tg / NS, s = tg - n*NS;
  int b = n >> 5, c = n & 31;
  int l0 = s * PSTRIDE;
  float4 acc = *(const float4*)(bemb + lane*4);
  #pragma unroll
  for (int p = 0; p < PSIZE; ++p){
    float xv = x[((size_t)b*LLEN + l0 + p)*CCH + c];
    float4 we = *(const float4*)(Wemb + p*DDIM + lane*4);
    acc.x += xv*we.x; acc.y += xv*we.y; acc.z += xv*we.z; acc.w += xv*we.w;
  }
  ushort4 hu; hu.x=f2bf(acc.x); hu.y=f2bf(acc.y); hu.z=f2bf(acc.z); hu.w=f2bf(acc.w);
  *(ushort4*)(h + (size_t)wv*DDIM + lane*4) = hu;
  float s1 = acc.x+acc.y+acc.z+acc.w;
  float s2 = acc.x*acc.x+acc.y*acc.y+acc.z*acc.z+acc.w*acc.w;
  #pragma unroll
  for (int o = 1; o < 64; o <<= 1){ s1 += __shfl_xor(s1,o,64); s2 += __shfl_xor(s2,o,64); }
  float mu = s1*(1.f/DDIM);
  float var = s2*(1.f/DDIM) - mu*mu;
  float rstd = rsqrtf(var + 1e-5f);
  float4 wf = *(const float4*)(w1 + lane*4);
  float4 bf = *(const float4*)(b1 + lane*4);
  ushort4 o4;
  o4.x = f2bf((acc.x-mu)*rstd*wf.x + bf.x);
  o4.y = f2bf((acc.y-mu)*rstd*wf.y + bf.y);
  o4.z = f2bf((acc.z-mu)*rstd*wf.z + bf.z);
  o4.w = f2bf((acc.w-mu)*rstd*wf.w + bf.w);
  *(ushort4*)(outA + (size_t)wv*DDIM + lane*4) = o4;
}

// ---------------- layernorm, wave = token, vectorized ------------------------------
__global__ __launch_bounds__(256) void layernorm_v(
    const u16* __restrict__ in, const float* __restrict__ w,
    const float* __restrict__ b, u16* __restrict__ out){
  int wv = blockIdx.x*4 + (threadIdx.x >> 6);
  int lane = threadIdx.x & 63;
  ushort4 u = *(const ushort4*)(in + (size_t)wv*DDIM + lane*4);
  float v0=bf2f(u.x), v1=bf2f(u.y), v2=bf2f(u.z), v3=bf2f(u.w);
  float s1 = v0+v1+v2+v3, s2 = v0*v0+v1*v1+v2*v2+v3*v3;
  #pragma unroll
  for (int o = 1; o < 64; o <<= 1){ s1 += __shfl_xor(s1,o,64); s2 += __shfl_xor(s2,o,64); }
  float mu = s1*(1.f/DDIM);
  float var = s2*(1.f/DDIM) - mu*mu;
  float rstd = rsqrtf(var + 1e-5f);
  float4 wf = *(const float4*)(w + lane*4);
  float4 bf = *(const float4*)(b + lane*4);
  ushort4 o4;
  o4.x = f2bf((v0-mu)*rstd*wf.x + bf.x);
  o4.y = f2bf((v1-mu)*rstd*wf.y + bf.y);
  o4.z = f2bf((v2-mu)*rstd*wf.z + bf.z);
  o4.w = f2bf((v3-mu)*rstd*wf.w + bf.w);
  *(ushort4*)(out + (size_t)wv*DDIM + lane*4) = o4;
}

// ---------------- fused groupnorm + residual + layernorm, vectorized ---------------
__global__ __launch_bounds__(256) void gn_res_ln_v(
    const u16* __restrict__ y, const float* __restrict__ gnw,
    const float* __restrict__ w2, const float* __restrict__ b2,
    u16* __restrict__ h, u16* __restrict__ outA){
  int wv = blockIdx.x*4 + (threadIdx.x >> 6);
  int lane = threadIdx.x & 63;
  ushort4 u = *(const ushort4*)(y + (size_t)wv*DDIM + lane*4);
  float v0=bf2f(u.x), v1=bf2f(u.y), v2=bf2f(u.z), v3=bf2f(u.w);
  float s1 = v0+v1+v2+v3, s2 = v0*v0+v1*v1+v2*v2+v3*v3;
  #pragma unroll
  for (int o = 1; o < 16; o <<= 1){ s1 += __shfl_xor(s1,o,64); s2 += __shfl_xor(s2,o,64); }
  float mu64 = s1*(1.f/64.f);
  float var64 = s2*(1.f/64.f) - mu64*mu64;
  float rstd64 = rsqrtf(var64 + 1e-5f);
  float4 gw = *(const float4*)(gnw + lane*4);
  ushort4 hu = *(const ushort4*)(h + (size_t)wv*DDIM + lane*4);
  float h0 = bf2f(hu.x) + (v0-mu64)*rstd64*gw.x;
  float h1 = bf2f(hu.y) + (v1-mu64)*rstd64*gw.y;
  float h2 = bf2f(hu.z) + (v2-mu64)*rstd64*gw.z;
  float h3 = bf2f(hu.w) + (v3-mu64)*rstd64*gw.w;
  ushort4 hn; hn.x=f2bf(h0); hn.y=f2bf(h1); hn.z=f2bf(h2); hn.w=f2bf(h3);
  *(ushort4*)(h + (size_t)wv*DDIM + lane*4) = hn;
  float t1 = h0+h1+h2+h3, t2 = h0*h0+h1*h1+h2*h2+h3*h3;
  #pragma unroll
  for (int o = 1; o < 64; o <<= 1){ t1 += __shfl_xor(t1,o,64); t2 += __shfl_xor(t2,o,64); }
  float mu = t1*(1.f/DDIM);
  float var = t2*(1.f/DDIM) - mu*mu;
  float rstd = rsqrtf(var + 1e-5f);
  float4 wf = *(const float4*)(w2 + lane*4);
  float4 bf = *(const float4*)(b2 + lane*4);
  ushort4 o4;
  o4.x = f2bf((h0-mu)*rstd*wf.x + bf.x);
  o4.y = f2bf((h1-mu)*rstd*wf.y + bf.y);
  o4.z = f2bf((h2-mu)*rstd*wf.z + bf.z);
  o4.w = f2bf((h3-mu)*rstd*wf.w + bf.w);
  *(ushort4*)(outA + (size_t)wv*DDIM + lane*4) = o4;
}

// ---------------- causal depthwise conv K=4 + SiLU, vectorized ---------------------
__global__ __launch_bounds__(256) void conv_silu_v(
    const u16* __restrict__ xln, const float* __restrict__ cw,
    const float* __restrict__ cb, u16* __restrict__ xc){
  int wv = blockIdx.x*4 + (threadIdx.x >> 6);
  int lane = threadIdx.x & 63;
  int s = wv % NS;
  float4 acc = *(const float4*)(cb + lane*4);
  #pragma unroll
  for (int k = 0; k < 4; ++k){
    int ss = s + k - 3;
    if (ss >= 0){
      ushort4 xu = *(const ushort4*)(xln + (size_t)(wv + k - 3)*DDIM + lane*4);
      float4 cv = *(const float4*)(cw + k*DDIM + lane*4);
      acc.x += bf2f(xu.x)*cv.x; acc.y += bf2f(xu.y)*cv.y;
      acc.z += bf2f(xu.z)*cv.z; acc.w += bf2f(xu.w)*cv.w;
    }
  }
  ushort4 o4;
  o4.x = f2bf(acc.x/(1.f + __expf(-acc.x)));
  o4.y = f2bf(acc.y/(1.f + __expf(-acc.y)));
  o4.z = f2bf(acc.z/(1.f + __expf(-acc.z)));
  o4.w = f2bf(acc.w/(1.f + __expf(-acc.w)));
  *(ushort4*)(xc + (size_t)wv*DDIM + lane*4) = o4;
}

// ---------------- generic MFMA GEMM (XCD-swizzled, XOR-swizzled LDS) ---------------
// MODE 1: bf16 out += acc + bias (RMW);  MODE 2: fp32 ptmp[(kc*Mtot+row)*ldo+col]=acc
template<int BM,int BN,int WR,int WC,int MR,int NR,int MODE,int VM>
__global__ __launch_bounds__(256) void mfma_gemm2(
    const u16* __restrict__ A, int lda,
    const u16* __restrict__ Wt, int ldwt,
    const float* __restrict__ bias, void* __restrict__ outp, int ldo,
    int ksteps, int kchunk, int Mtot)
{
  constexpr int nA = BM/16, nW = BN/16;
  __shared__ u16 As[2][BM*32];
  __shared__ u16 Ws[2][BN*32];
  const int tid = threadIdx.x;
  const int lane = tid & 63, wid = tid >> 6;
  const int wr = wid / WC, wc = wid % WC;
  const int fr = lane & 15, kb = lane >> 4;
  int nt, mt; swz_tile(nt, mt);
  const int m0 = mt*BM, n0 = nt*BN;
  const int kc = blockIdx.z;
  const int kbeg = kc*kchunk;
  const u16* Ab = A + (size_t)m0*lda + kbeg;
  const u16* Wb = Wt + (size_t)n0*ldwt + kbeg;
  const int lrow = lane >> 2;
  const int lcol = (((lane & 3) ^ (lrow & 3)) * 8);   // source XOR-swizzle
  const int rsw = (kb ^ (fr & 3))*8;                  // read-side XOR

  auto stage = [&](int buf, int ks){
    int k0 = ks*32;
    for (int c = wid; c < nA; c += 4)
      gload16(Ab + (size_t)(c*16 + lrow)*lda + k0 + lcol, &As[buf][c*512]);
    for (int c = wid; c < nW; c += 4)
      gload16(Wb + (size_t)(c*16 + lrow)*ldwt + k0 + lcol, &Ws[buf][c*512]);
  };

  f32x4 acc[MR][NR];
  #pragma unroll
  for (int m=0;m<MR;++m)
    #pragma unroll
    for (int n=0;n<NR;++n) acc[m][n] = (f32x4){0.f,0.f,0.f,0.f};

  stage(0, 0);
  if (VM == 0) __syncthreads();
  int cur = 0;
  for (int ks = 0; ks < ksteps; ++ks){
    if (VM == 0){
      if (ks + 1 < ksteps) stage(cur^1, ks+1);
    } else {
      if (ks + 1 < ksteps){ stage(cur^1, ks+1); waitcnt_vm<VM>(); }
      else waitcnt_vm<0>();
      __builtin_amdgcn_s_barrier();
      asm volatile("" ::: "memory");
    }
    bf16x8 af[MR], wf[NR];
    #pragma unroll
    for (int m=0;m<MR;++m)
      af[m] = *(const bf16x8*)&As[cur][(wr*MR*16 + m*16 + fr)*32 + rsw];
    #pragma unroll
    for (int n=0;n<NR;++n)
      wf[n] = *(const bf16x8*)&Ws[cur][(wc*NR*16 + n*16 + fr)*32 + rsw];
    #pragma unroll
    for (int m=0;m<MR;++m)
      #pragma unroll
      for (int n=0;n<NR;++n)
        acc[m][n] = __builtin_amdgcn_mfma_f32_16x16x32_bf16(af[m], wf[n], acc[m][n], 0,0,0);
    if (VM == 0){
      __syncthreads();
    } else {
      asm volatile("" ::: "memory");
      __builtin_amdgcn_s_barrier();
    }
    cur ^= 1;
  }
  #pragma unroll
  for (int m=0;m<MR;++m){
    int rowb = m0 + wr*MR*16 + m*16 + kb*4;
    #pragma unroll
    for (int n=0;n<NR;++n){
      int col = n0 + wc*NR*16 + n*16 + fr;
      #pragma unroll
      for (int r=0;r<4;++r){
        int row = rowb + r;
        float v = acc[m][n][r];
        if (MODE == 1){
          u16* dst = (u16*)outp + (size_t)row*ldo + col;
          *dst = f2bf(bf2f(*dst) + v + bias[col]);
        } else {
          ((float*)outp)[((size_t)kc*Mtot + row)*ldo + col] = v;
        }
      }
    }
  }
}

// ---------------- gate GEMM, true K=64, swizzled -----------------------------------
__global__ __launch_bounds__(256) void mfma_gate2(
    const u16* __restrict__ xc, const u16* __restrict__ xh,
    const u16* __restrict__ Wg2, const float* __restrict__ gb,
    u16* __restrict__ gates)
{
  __shared__ u16 As[2][128*32];
  __shared__ u16 Ws[2][128*32];
  const int tid = threadIdx.x;
  const int lane = tid & 63, wid = tid >> 6;
  const int wr = wid >> 1, wc = wid & 1;
  const int fr = lane & 15, kb = lane >> 4;
  int nt, mt; swz_tile(nt, mt);
  const int p = nt >> 2, hd = nt & 3;
  const int m0 = mt*128;
  const u16* Ain = (p == 0) ? xc : xh;
  const u16* Wb = Wg2 + (size_t)nt*8192;
  const int lrow = lane >> 2;
  const int lcol = (((lane & 3) ^ (lrow & 3)) * 8);
  const int rsw = (kb ^ (fr & 3))*8;

  auto stage = [&](int buf, int ks){
    int k0 = ks*32;
    for (int c = wid; c < 8; c += 4)
      gload16(Ain + (size_t)(m0 + c*16 + lrow)*DDIM + hd*64 + k0 + lcol, &As[buf][c*512]);
    for (int c = wid; c < 8; c += 4)
      gload16(Wb + (size_t)(c*16 + lrow)*64 + k0 + lcol, &Ws[buf][c*512]);
  };

  f32x4 acc[4][4];
  #pragma unroll
  for (int m=0;m<4;++m)
    #pragma unroll
    for (int n=0;n<4;++n) acc[m][n] = (f32x4){0.f,0.f,0.f,0.f};

  stage(0, 0);
  int cur = 0;
  #pragma unroll
  for (int ks = 0; ks < 2; ++ks){
    if (ks == 0){ stage(1, 1); waitcnt_vm<4>(); }
    else waitcnt_vm<0>();
    __builtin_amdgcn_s_barrier();
    asm volatile("" ::: "memory");
    bf16x8 af[4], wf[4];
    #pragma unroll
    for (int m=0;m<4;++m)
      af[m] = *(const bf16x8*)&As[cur][(wr*64 + m*16 + fr)*32 + rsw];
    #pragma unroll
    for (int n=0;n<4;++n)
      wf[n] = *(const bf16x8*)&Ws[cur][(wc*64 + n*16 + fr)*32 + rsw];
    #pragma unroll
    for (int m=0;m<4;++m)
      #pragma unroll
      for (int n=0;n<4;++n)
        acc[m][n] = __builtin_amdgcn_mfma_f32_16x16x32_bf16(af[m], wf[n], acc[m][n], 0,0,0);
    asm volatile("" ::: "memory");
    __builtin_amdgcn_s_barrier();
    cur ^= 1;
  }
  #pragma unroll
  for (int m=0;m<4;++m){
    int rowb = m0 + wr*64 + m*16 + kb*4;
    #pragma unroll
    for (int n=0;n<4;++n){
      int cl = wc*64 + n*16 + fr;
      int e = cl >> 1, gl = cl & 1;
      float bv = gb[(2*p + gl)*256 + hd*64 + e];
      int phys = hd*256 + p*128 + cl;
      #pragma unroll
      for (int r=0;r<4;++r)
        gates[(size_t)(rowb + r)*1024 + phys] = f2bf(acc[m][n][r] + bv);
    }
  }
}

// ---------------- FFN up + fast gelu*g2, BM=256, swizzled --------------------------
__global__ __launch_bounds__(256) void mfma_up_gelu3(
    const u16* __restrict__ A, const u16* __restrict__ Wt,
    const float* __restrict__ ub, u16* __restrict__ gp)
{
  __shared__ u16 As[2][256*32];
  __shared__ u16 Ws[2][128*32];
  const int tid = threadIdx.x;
  const int lane = tid & 63, wid = tid >> 6;
  const int fr = lane & 15, kb = lane >> 4;
  int nt, mt; swz_tile(nt, mt);
  const int m0 = mt*256, n0 = nt*64;
  const u16* W1 = Wt + (size_t)n0*256;
  const u16* W2 = Wt + (size_t)(384 + n0)*256;
  const int lrow = lane >> 2;
  const int lcol = (((lane & 3) ^ (lrow & 3)) * 8);
  const int rsw = (kb ^ (fr & 3))*8;

  auto stage = [&](int buf, int ks){
    int k0 = ks*32;
    for (int c = wid; c < 16; c += 4)
      gload16(A + (size_t)(m0 + c*16 + lrow)*256 + k0 + lcol, &As[buf][c*512]);
    for (int c = wid; c < 8; c += 4){
      const u16* src = (c < 4) ? (W1 + (size_t)(c*16 + lrow)*256)
                               : (W2 + (size_t)((c-4)*16 + lrow)*256);
      gload16(src + k0 + lcol, &Ws[buf][c*512]);
    }
  };

  f32x4 a1[4][4], a2[4][4];
  #pragma unroll
  for (int m=0;m<4;++m)
    #pragma unroll
    for (int n=0;n<4;++n){ a1[m][n]=(f32x4){0,0,0,0}; a2[m][n]=(f32x4){0,0,0,0}; }

  stage(0, 0);
  int cur = 0;
  #pragma unroll
  for (int ks = 0; ks < 8; ++ks){
    if (ks + 1 < 8){ stage(cur^1, ks+1); waitcnt_vm<6>(); }
    else waitcnt_vm<0>();
    __builtin_amdgcn_s_barrier();
    asm volatile("" ::: "memory");
    bf16x8 af[4], wf1[4], wf2[4];
    #pragma unroll
    for (int m=0;m<4;++m)
      af[m] = *(const bf16x8*)&As[cur][(wid*64 + m*16 + fr)*32 + rsw];
    #pragma unroll
    for (int n=0;n<4;++n){
      wf1[n] = *(const bf16x8*)&Ws[cur][(n*16 + fr)*32 + rsw];
      wf2[n] = *(const bf16x8*)&Ws[cur][(64 + n*16 + fr)*32 + rsw];
    }
    #pragma unroll
    for (int m=0;m<4;++m)
      #pragma unroll
      for (int n=0;n<4;++n){
        a1[m][n] = __builtin_amdgcn_mfma_f32_16x16x32_bf16(af[m], wf1[n], a1[m][n], 0,0,0);
        a2[m][n] = __builtin_amdgcn_mfma_f32_16x16x32_bf16(af[m], wf2[n], a2[m][n], 0,0,0);
      }
    asm volatile("" ::: "memory");
    __builtin_amdgcn_s_barrier();
    cur ^= 1;
  }
  #pragma unroll
  for (int m=0;m<4;++m){
    int rowb = m0 + wid*64 + m*16 + kb*4;
    #pragma unroll
    for (int n=0;n<4;++n){
      int col = n0 + n*16 + fr;
      float b1 = ub[col], b2 = ub[384 + col];
      #pragma unroll
      for (int r=0;r<4;++r){
        float g1 = a1[m][n][r] + b1;
        float g2 = a2[m][n][r] + b2;
        float u  = 0.7978845608028654f*(g1 + 0.044715f*g1*g1*g1);
        float uc = fminf(fmaxf(u, -20.f), 20.f);
        float t2 = __expf(uc + uc);
        float th = (t2 - 1.f)/(t2 + 1.f);
        float ge = 0.5f*g1*(1.f + th);
        gp[(size_t)(rowb + r)*UPDIM + col] = f2bf(ge*g2);
      }
    }
  }
}

// ---------------- sLSTM scan v4 (unchanged) ----------------------------------------
__global__ __launch_bounds__(256) void slstm_scan4(
    const u16* __restrict__ gates, const u16* __restrict__ Rgt,
    u16* __restrict__ y)
{
  __shared__ u16 h_lds[16*72];
  __shared__ float rec_lds[4][16][68];
  const int tid = threadIdx.x;
  const int w = tid >> 6, lane = tid & 63;
  const int hd = blockIdx.y, grp = blockIdx.x;
  const int fr = lane & 15, kb = lane >> 4;
  const int seq0 = grp*16;
  const u32* g32 = (const u32*)gates;

  bf16x8 bfr[4][2];
  {
    const u16* rb = Rgt + (size_t)(w*NHEAD + hd)*4096;
    #pragma unroll
    for (int n=0;n<4;++n)
      #pragma unroll
      for (int ks=0;ks<2;++ks)
        bfr[n][ks] = *(const bf16x8*)(rb + (size_t)(n*16 + fr)*64 + ks*32 + kb*8);
  }
  for (int i = tid; i < 16*72/2; i += 256) ((u32*)h_lds)[i] = 0u;
  float c[4]={0,0,0,0}, nst[4]={0,0,0,0}, m[4]={0,0,0,0};

  size_t gb4[4];
  #pragma unroll
  for (int si=0; si<4; ++si)
    gb4[si] = ((size_t)(seq0 + 4*w + si)*NS)*512 + hd*128 + lane;

  u32 g0[4][2], g1[4][2];
  #pragma unroll
  for (int si=0; si<4; ++si){
    g0[si][0] = g32[gb4[si]];        g0[si][1] = g32[gb4[si] + 64];
    g1[si][0] = g32[gb4[si] + 512];  g1[si][1] = g32[gb4[si] + 576];
  }
  __syncthreads();

  for (int s = 0; s < NS; ++s){
    u32 gn[4][2] = {};
    if (s + 2 < NS){
      #pragma unroll
      for (int si=0; si<4; ++si){
        size_t b2 = gb4[si] + (size_t)(s+2)*512;
        gn[si][0] = g32[b2];
        gn[si][1] = g32[b2 + 64];
      }
    }
    bf16x8 af0 = *(const bf16x8*)&h_lds[fr*72 + kb*8];
    bf16x8 af1 = *(const bf16x8*)&h_lds[fr*72 + 32 + kb*8];
    f32x4 acc[4];
    #pragma unroll
    for (int n=0;n<4;++n){
      acc[n] = (f32x4){0,0,0,0};
      acc[n] = __builtin_amdgcn_mfma_f32_16x16x32_bf16(af0, bfr[n][0], acc[n], 0,0,0);
      acc[n] = __builtin_amdgcn_mfma_f32_16x16x32_bf16(af1, bfr[n][1], acc[n], 0,0,0);
    }
    #pragma unroll
    for (int n=0;n<4;++n)
      #pragma unroll
      for (int r=0;r<4;++r)
        rec_lds[w][kb*4 + r][n*16 + fr] = acc[n][r];
    asm volatile("s_waitcnt lgkmcnt(0)" ::: "memory");
    __builtin_amdgcn_s_barrier();
    #pragma unroll
    for (int si=0; si<4; ++si){
      int sidx = 4*w + si;
      float ip = rec_lds[0][sidx][lane] + bf2f(g0[si][0] & 0xffffu);
      float fp = rec_lds[1][sidx][lane] + bf2f_hi(g0[si][0]);
      float zp = rec_lds[2][sidx][lane] + bf2f(g0[si][1] & 0xffffu);
      float op = rec_lds[3][sidx][lane] + bf2f_hi(g0[si][1]);
      float sp  = __logf(1.f + __expf(-fabsf(fp)));
      float lg  = m[si] + fminf(fp, 0.f) - sp;
      float mn  = fmaxf(ip, lg);
      float iv  = __expf(ip - mn);
      float fv  = __expf(lg - mn);
      float zz  = fminf(fabsf(zp), 15.f);
      float t2  = __expf(zz + zz);
      float tha = (t2 - 1.f)/(t2 + 1.f);
      float th  = (zp >= 0.f) ? tha : -tha;
      c[si]   = fv*c[si] + iv*th;
      nst[si] = fv*nst[si] + iv;
      m[si]   = mn;
      float hv = c[si] * __builtin_amdgcn_rcpf(nst[si]*(1.f + __expf(-op)));
      h_lds[sidx*72 + lane] = f2bf(hv);
      size_t t = (size_t)(seq0 + sidx)*NS + s;
      y[t*DDIM + hd*64 + lane] = f2bf(hv);
    }
    asm volatile("s_waitcnt lgkmcnt(0)" ::: "memory");
    __builtin_amdgcn_s_barrier();
    #pragma unroll
    for (int si=0; si<4; ++si){
      g0[si][0] = g1[si][0]; g0[si][1] = g1[si][1];
      g1[si][0] = gn[si][0]; g1[si][1] = gn[si][1];
    }
  }
}

// ---------------- proj reduce over K-split slices ----------------------------------
__global__ __launch_bounds__(256) void proj_out(
    const float* __restrict__ ptmp, const float* __restrict__ bproj,
    float* __restrict__ out, int Nc, int n0glob){
  int gid = blockIdx.x*256 + threadIdx.x;
  if (gid >= Nc*PREDN) return;
  float acc = 0.f;
  #pragma unroll
  for (int kc = 0; kc < KC_PROJ; ++kc) acc += ptmp[(size_t)kc*Nc*PREDN + gid];
  int nl = gid / PREDN, j = gid - nl*PREDN;
  int n = n0glob + nl;
  out[((size_t)(n >> 5)*PREDN + j)*CCH + (n & 31)] = acc + bproj[j];
}

extern "C" void kernel_launch(void* const* d_in, const int* in_sizes, int n_in,
                              void* d_out, int out_size, void* d_ws, size_t ws_size,
                              hipStream_t stream) {
  const float* x      = (const float*)d_in[0];
  const float* W_emb  = (const float*)d_in[1];
  const float* b_emb  = (const float*)d_in[2];
  const float* ln1_w  = (const float*)d_in[3];
  const float* ln1_b  = (const float*)d_in[4];
  const float* conv_w = (const float*)d_in[5];
  const float* conv_b = (const float*)d_in[6];
  const float* Wg     = (const float*)d_in[7];
  const float* Rg     = (const float*)d_in[8];
  const float* gb     = (const float*)d_in[9];
  const float* gn_w   = (const float*)d_in[10];
  const float* ln2_w  = (const float*)d_in[11];
  const float* ln2_b  = (const float*)d_in[12];
  const float* up_w   = (const float*)d_in[13];
  const float* up_b   = (const float*)d_in[14];
  const float* dn_w   = (const float*)d_in[15];
  const float* dn_b   = (const float*)d_in[16];
  const float* post_w = (const float*)d_in[17];
  const float* post_b = (const float*)d_in[18];
  const float* W_proj = (const float*)d_in[19];
  const float* b_proj = (const float*)d_in[20];
  float* out = (float*)d_out;

  const size_t oWu   = 0;          // [2][768][256] bf16 : 1,572,864
  const size_t oWd   = 1572864;    // [2][256][384] bf16 :   786,432
  const size_t oWg2  = 2359296;    // [2][8][128][64] bf16 :  262,144
  const size_t oRgt  = 2621440;    // [2][16][64][64] bf16 :  524,288
  const size_t oWp   = 3145728;    // [96][16128] bf16 : 3,096,576
  const size_t oChunk = 6242304;
  const size_t per_seq = (size_t)3584*NS;   // 225,792 B
  int Nc = 0;
  const int cands[3] = {1024, 512, 256};
  for (int i = 0; i < 3; ++i)
    if (oChunk + (size_t)cands[i]*per_seq <= ws_size){ Nc = cands[i]; break; }
  if (Nc == 0) return;

  char* wsb = (char*)d_ws;
  u16* Wu   = (u16*)(wsb + oWu);
  u16* Wd   = (u16*)(wsb + oWd);
  u16* Wg2  = (u16*)(wsb + oWg2);
  u16* Rgt  = (u16*)(wsb + oRgt);
  u16* Wtp  = (u16*)(wsb + oWp);

  for (int blk = 0; blk < 2; ++blk){
    cvt_transpose_t<<<dim3(8, 24), 256, 0, stream>>>(
        up_w + (size_t)blk*256*768, Wu + (size_t)blk*768*256, 256, 768);
    cvt_transpose_t<<<dim3(12, 8), 256, 0, stream>>>(
        dn_w + (size_t)blk*384*256, Wd + (size_t)blk*256*384, 384, 256);
  }
  cvt_gateW2<<<16, 256, 0, stream>>>(Wg, Wg2);
  cvt_gate<<<32, 256, 0, stream>>>(Rg, Rgt);
  cvt_transpose_t<<<dim3(504, 3), 256, 0, stream>>>(W_proj, Wtp, 16128, 96);

  for (int n0 = 0; n0 < NSEQ; n0 += Nc){
    const int    nc  = (NSEQ - n0 < Nc) ? (NSEQ - n0) : Nc;
    const size_t Tc  = (size_t)nc * NS;
    char* cb = wsb + oChunk;
    u16*   h_c   = (u16*)cb;                          // Tc*512 B
    u16*   bufA  = (u16*)(cb + Tc*512);               // Tc*512 B
    u16*   bufB  = (u16*)(cb + Tc*1024);              // Tc*512 B
    u16*   gates = (u16*)(cb + Tc*1536);              // Tc*2048 B
    u16*   gp    = gates;                             // reuse (Tc*768 B)
    float* ptmp  = (float*)(cb + Tc*1536 + Tc*1024);  // overlay in gates tail
    const int t_base = n0*NS;
    const int Tci = (int)Tc;

    patch_embed_ln_v<<<Tci/4, 256, 0, stream>>>(
        x, W_emb, b_emb, ln1_w, ln1_b, h_c, bufA, t_base);

    for (int blk = 0; blk < 2; ++blk){
      if (blk == 1)
        layernorm_v<<<Tci/4, 256, 0, stream>>>(h_c, ln1_w + DDIM, ln1_b + DDIM, bufA);
      conv_silu_v<<<Tci/4, 256, 0, stream>>>(bufA, conv_w + blk*4*DDIM, conv_b + blk*DDIM, bufB);
      mfma_gate2<<<dim3(8, Tci/128), 256, 0, stream>>>(
          bufB, bufA, Wg2 + (size_t)blk*8*8192, gb + blk*4*DDIM, gates);
      slstm_scan4<<<dim3(nc/16, NHEAD), 256, 0, stream>>>(
          gates, Rgt + (size_t)blk*16*4096, bufB);
      gn_res_ln_v<<<Tci/4, 256, 0, stream>>>(
          bufB, gn_w + blk*DDIM, ln2_w + blk*DDIM, ln2_b + blk*DDIM, h_c, bufA);
      mfma_up_gelu3<<<dim3(6, Tci/256), 256, 0, stream>>>(
          bufA, Wu + (size_t)blk*768*256, up_b + blk*2*UPDIM, gp);
      mfma_gemm2<256,128,4,1,4,8,1,6><<<dim3(2, Tci/256), 256, 0, stream>>>(
          gp, UPDIM, Wd + (size_t)blk*256*384, UPDIM,
          dn_b + blk*DDIM, (void*)h_c, DDIM, 12, 0, 0);
    }

    layernorm_v<<<Tci/4, 256, 0, stream>>>(h_c, post_w, post_b, bufA);
    mfma_gemm2<64,96,2,2,2,3,2,0><<<dim3(1, nc/64, KC_PROJ), 256, 0, stream>>>(
        bufA, NS*DDIM, Wtp, NS*DDIM,
        b_proj, (void*)ptmp, PREDN, KCHUNK_PROJ/32, KCHUNK_PROJ, nc);
    proj_out<<<(nc*PREDN + 255)/256, 256, 0, stream>>>(ptmp, b_proj, out, nc, n0);
  }
}

// Round 14
// 706.543 us; speedup vs baseline: 4.4645x; 1.0359x over previous
//
#include <hip/hip_runtime.h>
#include <stdint.h>

typedef unsigned short u16;
typedef unsigned int   u32;
typedef __attribute__((ext_vector_type(8))) short bf16x8;
typedef __attribute__((ext_vector_type(4))) float f32x4;

#define NS      63
#define NSEQ    1024
#define DDIM    256
#define NHEAD   4
#define DHEAD   64
#define UPDIM   384
#define PREDN   96
#define LLEN    512
#define CCH     32
#define PSIZE   16
#define PSTRIDE 8
#define KC_PROJ 8
#define KCHUNK_PROJ 2016

__device__ __forceinline__ float bf2f(u32 lo16){
  union { u32 i; float f; } v; v.i = lo16 << 16; return v.f;
}
__device__ __forceinline__ float bf2f_hi(u32 u){
  union { u32 i; float f; } v; v.i = u & 0xffff0000u; return v.f;
}
__device__ __forceinline__ u16 f2bf(float f){
  union { u32 i; float f; } v; v.f = f;
  u32 u = v.i; u += 0x7fffu + ((u >> 16) & 1u);
  return (u16)(u >> 16);
}

__device__ __forceinline__ void gload16(const u16* g, u16* lds){
  __builtin_amdgcn_global_load_lds(
      (const __attribute__((address_space(1))) u32*)g,
      (__attribute__((address_space(3))) u32*)lds, 16, 0, 0);
}

template<int N> __device__ __forceinline__ void waitcnt_vm(){
  if constexpr (N == 0) asm volatile("s_waitcnt vmcnt(0)" ::: "memory");
  else if constexpr (N == 4) asm volatile("s_waitcnt vmcnt(4)" ::: "memory");
  else if constexpr (N == 6) asm volatile("s_waitcnt vmcnt(6)" ::: "memory");
}

// bijective XCD swizzle (m204): XCD c = flat&7 gets a contiguous logical range.
__device__ __forceinline__ void swz_tile(int &nt, int &mt){
  int gx = gridDim.x, gy = gridDim.y;
  int nwg = gx*gy;
  int flat = blockIdx.y*gx + blockIdx.x;
  int c = flat & 7, s = flat >> 3;
  int q = nwg >> 3, r = nwg & 7;
  int base = c*q + (c < r ? c : r);
  int t = base + s;
  nt = t % gx; mt = t / gx;
}

// ---------------- LDS-tiled transpose: dst[c][r] = bf16(src[r][c]) -----------------
__global__ __launch_bounds__(256) void cvt_transpose_t(
    const float* __restrict__ src, u16* __restrict__ dst, int R, int C){
  __shared__ u16 tile[32][33];
  int rb = blockIdx.x*32, cb = blockIdx.y*32;
  int tx = threadIdx.x & 31, ty = threadIdx.x >> 5;
  #pragma unroll
  for (int i = ty; i < 32; i += 8){
    int r = rb + i, c = cb + tx;
    tile[i][tx] = (r < R && c < C) ? f2bf(src[(size_t)r*C + c]) : (u16)0;
  }
  __syncthreads();
  #pragma unroll
  for (int i = ty; i < 32; i += 8){
    int c = cb + i, r = rb + tx;
    if (c < C && r < R) dst[(size_t)c*R + r] = tile[tx][i];
  }
}

__global__ __launch_bounds__(256) void cvt_gate(
    const float* __restrict__ src, u16* __restrict__ dst){
  int mat = blockIdx.x, t = threadIdx.x;
  const float* s = src + (size_t)mat*4096;
  u16* d = dst + (size_t)mat*4096;
  for (int i = t; i < 4096; i += 256){
    int r = i >> 6, c = i & 63;
    d[c*64 + r] = f2bf(s[i]);
  }
}

// gate weight true-K layout, col order n = e*2+gl: dst[(blk*2+p)*4+hd][n][k]
__global__ __launch_bounds__(256) void cvt_gateW2(
    const float* __restrict__ Wg, u16* __restrict__ dst){
  int mi = blockIdx.x;
  int blk = mi >> 3, p = (mi >> 2) & 1, hd = mi & 3;
  u16* d = dst + (size_t)mi*8192;
  for (int i = threadIdx.x; i < 8192; i += 256){
    int n = i >> 6, k = i & 63;
    int e = n >> 1, gl = n & 1;
    int g = 2*p + gl;
    d[i] = f2bf(Wg[((((size_t)blk*4 + g)*4 + hd)*64 + k)*64 + e]);
  }
}

// ---------------- patch embedding + ln1(blk0), wave = token, vectorized ------------
__global__ __launch_bounds__(256) void patch_embed_ln_v(
    const float* __restrict__ x, const float* __restrict__ Wemb,
    const float* __restrict__ bemb, const float* __restrict__ w1,
    const float* __restrict__ b1, u16* __restrict__ h,
    u16* __restrict__ outA, int t_base){
  int wv = blockIdx.x*4 + (threadIdx.x >> 6);
  int lane = threadIdx.x & 63;
  int tg = t_base + wv;
  int n = tg / NS, s = tg - n*NS;
  int b = n >> 5, c = n & 31;
  int l0 = s * PSTRIDE;
  float4 acc = *(const float4*)(bemb + lane*4);
  #pragma unroll
  for (int p = 0; p < PSIZE; ++p){
    float xv = x[((size_t)b*LLEN + l0 + p)*CCH + c];
    float4 we = *(const float4*)(Wemb + p*DDIM + lane*4);
    acc.x += xv*we.x; acc.y += xv*we.y; acc.z += xv*we.z; acc.w += xv*we.w;
  }
  ushort4 hu; hu.x=f2bf(acc.x); hu.y=f2bf(acc.y); hu.z=f2bf(acc.z); hu.w=f2bf(acc.w);
  *(ushort4*)(h + (size_t)wv*DDIM + lane*4) = hu;
  float s1 = acc.x+acc.y+acc.z+acc.w;
  float s2 = acc.x*acc.x+acc.y*acc.y+acc.z*acc.z+acc.w*acc.w;
  #pragma unroll
  for (int o = 1; o < 64; o <<= 1){ s1 += __shfl_xor(s1,o,64); s2 += __shfl_xor(s2,o,64); }
  float mu = s1*(1.f/DDIM);
  float var = s2*(1.f/DDIM) - mu*mu;
  float rstd = rsqrtf(var + 1e-5f);
  float4 wf = *(const float4*)(w1 + lane*4);
  float4 bf = *(const float4*)(b1 + lane*4);
  ushort4 o4;
  o4.x = f2bf((acc.x-mu)*rstd*wf.x + bf.x);
  o4.y = f2bf((acc.y-mu)*rstd*wf.y + bf.y);
  o4.z = f2bf((acc.z-mu)*rstd*wf.z + bf.z);
  o4.w = f2bf((acc.w-mu)*rstd*wf.w + bf.w);
  *(ushort4*)(outA + (size_t)wv*DDIM + lane*4) = o4;
}

// ---------------- layernorm, wave = token, vectorized ------------------------------
__global__ __launch_bounds__(256) void layernorm_v(
    const u16* __restrict__ in, const float* __restrict__ w,
    const float* __restrict__ b, u16* __restrict__ out){
  int wv = blockIdx.x*4 + (threadIdx.x >> 6);
  int lane = threadIdx.x & 63;
  ushort4 u = *(const ushort4*)(in + (size_t)wv*DDIM + lane*4);
  float v0=bf2f(u.x), v1=bf2f(u.y), v2=bf2f(u.z), v3=bf2f(u.w);
  float s1 = v0+v1+v2+v3, s2 = v0*v0+v1*v1+v2*v2+v3*v3;
  #pragma unroll
  for (int o = 1; o < 64; o <<= 1){ s1 += __shfl_xor(s1,o,64); s2 += __shfl_xor(s2,o,64); }
  float mu = s1*(1.f/DDIM);
  float var = s2*(1.f/DDIM) - mu*mu;
  float rstd = rsqrtf(var + 1e-5f);
  float4 wf = *(const float4*)(w + lane*4);
  float4 bf = *(const float4*)(b + lane*4);
  ushort4 o4;
  o4.x = f2bf((v0-mu)*rstd*wf.x + bf.x);
  o4.y = f2bf((v1-mu)*rstd*wf.y + bf.y);
  o4.z = f2bf((v2-mu)*rstd*wf.z + bf.z);
  o4.w = f2bf((v3-mu)*rstd*wf.w + bf.w);
  *(ushort4*)(out + (size_t)wv*DDIM + lane*4) = o4;
}

// ---------------- fused groupnorm + residual + layernorm, vectorized ---------------
__global__ __launch_bounds__(256) void gn_res_ln_v(
    const u16* __restrict__ y, const float* __restrict__ gnw,
    const float* __restrict__ w2, const float* __restrict__ b2,
    u16* __restrict__ h, u16* __restrict__ outA){
  int wv = blockIdx.x*4 + (threadIdx.x >> 6);
  int lane = threadIdx.x & 63;
  ushort4 u = *(const ushort4*)(y + (size_t)wv*DDIM + lane*4);
  float v0=bf2f(u.x), v1=bf2f(u.y), v2=bf2f(u.z), v3=bf2f(u.w);
  float s1 = v0+v1+v2+v3, s2 = v0*v0+v1*v1+v2*v2+v3*v3;
  #pragma unroll
  for (int o = 1; o < 16; o <<= 1){ s1 += __shfl_xor(s1,o,64); s2 += __shfl_xor(s2,o,64); }
  float mu64 = s1*(1.f/64.f);
  float var64 = s2*(1.f/64.f) - mu64*mu64;
  float rstd64 = rsqrtf(var64 + 1e-5f);
  float4 gw = *(const float4*)(gnw + lane*4);
  ushort4 hu = *(const ushort4*)(h + (size_t)wv*DDIM + lane*4);
  float h0 = bf2f(hu.x) + (v0-mu64)*rstd64*gw.x;
  float h1 = bf2f(hu.y) + (v1-mu64)*rstd64*gw.y;
  float h2 = bf2f(hu.z) + (v2-mu64)*rstd64*gw.z;
  float h3 = bf2f(hu.w) + (v3-mu64)*rstd64*gw.w;
  ushort4 hn; hn.x=f2bf(h0); hn.y=f2bf(h1); hn.z=f2bf(h2); hn.w=f2bf(h3);
  *(ushort4*)(h + (size_t)wv*DDIM + lane*4) = hn;
  float t1 = h0+h1+h2+h3, t2 = h0*h0+h1*h1+h2*h2+h3*h3;
  #pragma unroll
  for (int o = 1; o < 64; o <<= 1){ t1 += __shfl_xor(t1,o,64); t2 += __shfl_xor(t2,o,64); }
  float mu = t1*(1.f/DDIM);
  float var = t2*(1.f/DDIM) - mu*mu;
  float rstd = rsqrtf(var + 1e-5f);
  float4 wf = *(const float4*)(w2 + lane*4);
  float4 bf = *(const float4*)(b2 + lane*4);
  ushort4 o4;
  o4.x = f2bf((h0-mu)*rstd*wf.x + bf.x);
  o4.y = f2bf((h1-mu)*rstd*wf.y + bf.y);
  o4.z = f2bf((h2-mu)*rstd*wf.z + bf.z);
  o4.w = f2bf((h3-mu)*rstd*wf.w + bf.w);
  *(ushort4*)(outA + (size_t)wv*DDIM + lane*4) = o4;
}

// ---------------- causal depthwise conv K=4 + SiLU, vectorized ---------------------
__global__ __launch_bounds__(256) void conv_silu_v(
    const u16* __restrict__ xln, const float* __restrict__ cw,
    const float* __restrict__ cb, u16* __restrict__ xc){
  int wv = blockIdx.x*4 + (threadIdx.x >> 6);
  int lane = threadIdx.x & 63;
  int s = wv % NS;
  float4 acc = *(const float4*)(cb + lane*4);
  #pragma unroll
  for (int k = 0; k < 4; ++k){
    int ss = s + k - 3;
    if (ss >= 0){
      ushort4 xu = *(const ushort4*)(xln + (size_t)(wv + k - 3)*DDIM + lane*4);
      float4 cv = *(const float4*)(cw + k*DDIM + lane*4);
      acc.x += bf2f(xu.x)*cv.x; acc.y += bf2f(xu.y)*cv.y;
      acc.z += bf2f(xu.z)*cv.z; acc.w += bf2f(xu.w)*cv.w;
    }
  }
  ushort4 o4;
  o4.x = f2bf(acc.x/(1.f + __expf(-acc.x)));
  o4.y = f2bf(acc.y/(1.f + __expf(-acc.y)));
  o4.z = f2bf(acc.z/(1.f + __expf(-acc.z)));
  o4.w = f2bf(acc.w/(1.f + __expf(-acc.w)));
  *(ushort4*)(xc + (size_t)wv*DDIM + lane*4) = o4;
}

// ---------------- generic MFMA GEMM (XCD-swizzled, XOR-swizzled LDS) ---------------
template<int BM,int BN,int WR,int WC,int MR,int NR,int MODE,int VM>
__global__ __launch_bounds__(256) void mfma_gemm2(
    const u16* __restrict__ A, int lda,
    const u16* __restrict__ Wt, int ldwt,
    const float* __restrict__ bias, void* __restrict__ outp, int ldo,
    int ksteps, int kchunk, int Mtot)
{
  constexpr int nA = BM/16, nW = BN/16;
  __shared__ u16 As[2][BM*32];
  __shared__ u16 Ws[2][BN*32];
  const int tid = threadIdx.x;
  const int lane = tid & 63, wid = tid >> 6;
  const int wr = wid / WC, wc = wid % WC;
  const int fr = lane & 15, kb = lane >> 4;
  int nt, mt; swz_tile(nt, mt);
  const int m0 = mt*BM, n0 = nt*BN;
  const int kc = blockIdx.z;
  const int kbeg = kc*kchunk;
  const u16* Ab = A + (size_t)m0*lda + kbeg;
  const u16* Wb = Wt + (size_t)n0*ldwt + kbeg;
  const int lrow = lane >> 2;
  const int lcol = (((lane & 3) ^ (lrow & 3)) * 8);   // source XOR-swizzle
  const int rsw = (kb ^ (fr & 3))*8;                  // read-side XOR

  auto stage = [&](int buf, int ks){
    int k0 = ks*32;
    for (int c = wid; c < nA; c += 4)
      gload16(Ab + (size_t)(c*16 + lrow)*lda + k0 + lcol, &As[buf][c*512]);
    for (int c = wid; c < nW; c += 4)
      gload16(Wb + (size_t)(c*16 + lrow)*ldwt + k0 + lcol, &Ws[buf][c*512]);
  };

  f32x4 acc[MR][NR];
  #pragma unroll
  for (int m=0;m<MR;++m)
    #pragma unroll
    for (int n=0;n<NR;++n) acc[m][n] = (f32x4){0.f,0.f,0.f,0.f};

  stage(0, 0);
  if (VM == 0) __syncthreads();
  int cur = 0;
  for (int ks = 0; ks < ksteps; ++ks){
    if (VM == 0){
      if (ks + 1 < ksteps) stage(cur^1, ks+1);
    } else {
      if (ks + 1 < ksteps){ stage(cur^1, ks+1); waitcnt_vm<VM>(); }
      else waitcnt_vm<0>();
      __builtin_amdgcn_s_barrier();
      asm volatile("" ::: "memory");
    }
    bf16x8 af[MR], wf[NR];
    #pragma unroll
    for (int m=0;m<MR;++m)
      af[m] = *(const bf16x8*)&As[cur][(wr*MR*16 + m*16 + fr)*32 + rsw];
    #pragma unroll
    for (int n=0;n<NR;++n)
      wf[n] = *(const bf16x8*)&Ws[cur][(wc*NR*16 + n*16 + fr)*32 + rsw];
    #pragma unroll
    for (int m=0;m<MR;++m)
      #pragma unroll
      for (int n=0;n<NR;++n)
        acc[m][n] = __builtin_amdgcn_mfma_f32_16x16x32_bf16(af[m], wf[n], acc[m][n], 0,0,0);
    if (VM == 0){
      __syncthreads();
    } else {
      asm volatile("" ::: "memory");
      __builtin_amdgcn_s_barrier();
    }
    cur ^= 1;
  }
  #pragma unroll
  for (int m=0;m<MR;++m){
    int rowb = m0 + wr*MR*16 + m*16 + kb*4;
    #pragma unroll
    for (int n=0;n<NR;++n){
      int col = n0 + wc*NR*16 + n*16 + fr;
      #pragma unroll
      for (int r=0;r<4;++r){
        int row = rowb + r;
        float v = acc[m][n][r];
        if (MODE == 1){
          u16* dst = (u16*)outp + (size_t)row*ldo + col;
          *dst = f2bf(bf2f(*dst) + v + bias[col]);
        } else {
          ((float*)outp)[((size_t)kc*Mtot + row)*ldo + col] = v;
        }
      }
    }
  }
}

// ---------------- gate GEMM, true K=64, swizzled -----------------------------------
__global__ __launch_bounds__(256) void mfma_gate2(
    const u16* __restrict__ xc, const u16* __restrict__ xh,
    const u16* __restrict__ Wg2, const float* __restrict__ gb,
    u16* __restrict__ gates)
{
  __shared__ u16 As[2][128*32];
  __shared__ u16 Ws[2][128*32];
  const int tid = threadIdx.x;
  const int lane = tid & 63, wid = tid >> 6;
  const int wr = wid >> 1, wc = wid & 1;
  const int fr = lane & 15, kb = lane >> 4;
  int nt, mt; swz_tile(nt, mt);
  const int p = nt >> 2, hd = nt & 3;
  const int m0 = mt*128;
  const u16* Ain = (p == 0) ? xc : xh;
  const u16* Wb = Wg2 + (size_t)nt*8192;
  const int lrow = lane >> 2;
  const int lcol = (((lane & 3) ^ (lrow & 3)) * 8);
  const int rsw = (kb ^ (fr & 3))*8;

  auto stage = [&](int buf, int ks){
    int k0 = ks*32;
    for (int c = wid; c < 8; c += 4)
      gload16(Ain + (size_t)(m0 + c*16 + lrow)*DDIM + hd*64 + k0 + lcol, &As[buf][c*512]);
    for (int c = wid; c < 8; c += 4)
      gload16(Wb + (size_t)(c*16 + lrow)*64 + k0 + lcol, &Ws[buf][c*512]);
  };

  f32x4 acc[4][4];
  #pragma unroll
  for (int m=0;m<4;++m)
    #pragma unroll
    for (int n=0;n<4;++n) acc[m][n] = (f32x4){0.f,0.f,0.f,0.f};

  stage(0, 0);
  int cur = 0;
  #pragma unroll
  for (int ks = 0; ks < 2; ++ks){
    if (ks == 0){ stage(1, 1); waitcnt_vm<4>(); }
    else waitcnt_vm<0>();
    __builtin_amdgcn_s_barrier();
    asm volatile("" ::: "memory");
    bf16x8 af[4], wf[4];
    #pragma unroll
    for (int m=0;m<4;++m)
      af[m] = *(const bf16x8*)&As[cur][(wr*64 + m*16 + fr)*32 + rsw];
    #pragma unroll
    for (int n=0;n<4;++n)
      wf[n] = *(const bf16x8*)&Ws[cur][(wc*64 + n*16 + fr)*32 + rsw];
    #pragma unroll
    for (int m=0;m<4;++m)
      #pragma unroll
      for (int n=0;n<4;++n)
        acc[m][n] = __builtin_amdgcn_mfma_f32_16x16x32_bf16(af[m], wf[n], acc[m][n], 0,0,0);
    asm volatile("" ::: "memory");
    __builtin_amdgcn_s_barrier();
    cur ^= 1;
  }
  #pragma unroll
  for (int m=0;m<4;++m){
    int rowb = m0 + wr*64 + m*16 + kb*4;
    #pragma unroll
    for (int n=0;n<4;++n){
      int cl = wc*64 + n*16 + fr;
      int e = cl >> 1, gl = cl & 1;
      float bv = gb[(2*p + gl)*256 + hd*64 + e];
      int phys = hd*256 + p*128 + cl;
      #pragma unroll
      for (int r=0;r<4;++r)
        gates[(size_t)(rowb + r)*1024 + phys] = f2bf(acc[m][n][r] + bv);
    }
  }
}

// ---------------- FFN up + fast gelu*g2, BM=256, swizzled --------------------------
__global__ __launch_bounds__(256) void mfma_up_gelu3(
    const u16* __restrict__ A, const u16* __restrict__ Wt,
    const float* __restrict__ ub, u16* __restrict__ gp)
{
  __shared__ u16 As[2][256*32];
  __shared__ u16 Ws[2][128*32];
  const int tid = threadIdx.x;
  const int lane = tid & 63, wid = tid >> 6;
  const int fr = lane & 15, kb = lane >> 4;
  int nt, mt; swz_tile(nt, mt);
  const int m0 = mt*256, n0 = nt*64;
  const u16* W1 = Wt + (size_t)n0*256;
  const u16* W2 = Wt + (size_t)(384 + n0)*256;
  const int lrow = lane >> 2;
  const int lcol = (((lane & 3) ^ (lrow & 3)) * 8);
  const int rsw = (kb ^ (fr & 3))*8;

  auto stage = [&](int buf, int ks){
    int k0 = ks*32;
    for (int c = wid; c < 16; c += 4)
      gload16(A + (size_t)(m0 + c*16 + lrow)*256 + k0 + lcol, &As[buf][c*512]);
    for (int c = wid; c < 8; c += 4){
      const u16* src = (c < 4) ? (W1 + (size_t)(c*16 + lrow)*256)
                               : (W2 + (size_t)((c-4)*16 + lrow)*256);
      gload16(src + k0 + lcol, &Ws[buf][c*512]);
    }
  };

  f32x4 a1[4][4], a2[4][4];
  #pragma unroll
  for (int m=0;m<4;++m)
    #pragma unroll
    for (int n=0;n<4;++n){ a1[m][n]=(f32x4){0,0,0,0}; a2[m][n]=(f32x4){0,0,0,0}; }

  stage(0, 0);
  int cur = 0;
  #pragma unroll
  for (int ks = 0; ks < 8; ++ks){
    if (ks + 1 < 8){ stage(cur^1, ks+1); waitcnt_vm<6>(); }
    else waitcnt_vm<0>();
    __builtin_amdgcn_s_barrier();
    asm volatile("" ::: "memory");
    bf16x8 af[4], wf1[4], wf2[4];
    #pragma unroll
    for (int m=0;m<4;++m)
      af[m] = *(const bf16x8*)&As[cur][(wid*64 + m*16 + fr)*32 + rsw];
    #pragma unroll
    for (int n=0;n<4;++n){
      wf1[n] = *(const bf16x8*)&Ws[cur][(n*16 + fr)*32 + rsw];
      wf2[n] = *(const bf16x8*)&Ws[cur][(64 + n*16 + fr)*32 + rsw];
    }
    #pragma unroll
    for (int m=0;m<4;++m)
      #pragma unroll
      for (int n=0;n<4;++n){
        a1[m][n] = __builtin_amdgcn_mfma_f32_16x16x32_bf16(af[m], wf1[n], a1[m][n], 0,0,0);
        a2[m][n] = __builtin_amdgcn_mfma_f32_16x16x32_bf16(af[m], wf2[n], a2[m][n], 0,0,0);
      }
    asm volatile("" ::: "memory");
    __builtin_amdgcn_s_barrier();
    cur ^= 1;
  }
  #pragma unroll
  for (int m=0;m<4;++m){
    int rowb = m0 + wid*64 + m*16 + kb*4;
    #pragma unroll
    for (int n=0;n<4;++n){
      int col = n0 + n*16 + fr;
      float b1 = ub[col], b2 = ub[384 + col];
      #pragma unroll
      for (int r=0;r<4;++r){
        float g1 = a1[m][n][r] + b1;
        float g2 = a2[m][n][r] + b2;
        float u  = 0.7978845608028654f*(g1 + 0.044715f*g1*g1*g1);
        float uc = fminf(fmaxf(u, -20.f), 20.f);
        float t2 = __expf(uc + uc);
        float th = (t2 - 1.f)/(t2 + 1.f);
        float ge = 0.5f*g1*(1.f + th);
        gp[(size_t)(rowb + r)*UPDIM + col] = f2bf(ge*g2);
      }
    }
  }
}

// ---------------- sLSTM scan v5: 4 seqs/block, 4 blocks/CU for latency hiding ------
// Each wave = one gate in MFMA phase; elementwise handles seq sidx = w.
__global__ __launch_bounds__(256) void slstm_scan5(
    const u16* __restrict__ gates, const u16* __restrict__ Rgt,
    u16* __restrict__ y)
{
  __shared__ u16 h_lds[16*72];          // rows 0..3 live, 4..15 stay zero
  __shared__ float rec_lds[4][4][68];   // [gate][seq][e]
  const int tid = threadIdx.x;
  const int w = tid >> 6, lane = tid & 63;
  const int hd = blockIdx.y, grp = blockIdx.x;
  const int fr = lane & 15, kb = lane >> 4;
  const int seq0 = grp*4;
  const u32* g32 = (const u32*)gates;

  bf16x8 bfr[4][2];
  {
    const u16* rb = Rgt + (size_t)(w*NHEAD + hd)*4096;
    #pragma unroll
    for (int n=0;n<4;++n)
      #pragma unroll
      for (int ks=0;ks<2;++ks)
        bfr[n][ks] = *(const bf16x8*)(rb + (size_t)(n*16 + fr)*64 + ks*32 + kb*8);
  }
  for (int i = tid; i < 16*72/2; i += 256) ((u32*)h_lds)[i] = 0u;
  float c = 0.f, nst = 0.f, m = 0.f;

  const size_t gb = ((size_t)(seq0 + w)*NS)*512 + hd*128 + lane;
  u32 g0[2], g1[2];
  g0[0] = g32[gb];        g0[1] = g32[gb + 64];
  g1[0] = g32[gb + 512];  g1[1] = g32[gb + 576];
  __syncthreads();

  for (int s = 0; s < NS; ++s){
    u32 gn[2] = {0u, 0u};
    if (s + 2 < NS){
      size_t b2 = gb + (size_t)(s+2)*512;
      gn[0] = g32[b2];
      gn[1] = g32[b2 + 64];
    }
    // MFMA: rec[gate w] = H[4(16)][64] @ Rg[w][64][64]
    bf16x8 af0 = *(const bf16x8*)&h_lds[fr*72 + kb*8];
    bf16x8 af1 = *(const bf16x8*)&h_lds[fr*72 + 32 + kb*8];
    f32x4 acc[4];
    #pragma unroll
    for (int n=0;n<4;++n){
      acc[n] = (f32x4){0,0,0,0};
      acc[n] = __builtin_amdgcn_mfma_f32_16x16x32_bf16(af0, bfr[n][0], acc[n], 0,0,0);
      acc[n] = __builtin_amdgcn_mfma_f32_16x16x32_bf16(af1, bfr[n][1], acc[n], 0,0,0);
    }
    if (kb == 0){
      #pragma unroll
      for (int n=0;n<4;++n)
        #pragma unroll
        for (int r=0;r<4;++r)
          rec_lds[w][r][n*16 + fr] = acc[n][r];
    }
    asm volatile("s_waitcnt lgkmcnt(0)" ::: "memory");
    __builtin_amdgcn_s_barrier();
    // elementwise: wave w owns seq sidx = w, lane = e
    {
      float ip = rec_lds[0][w][lane] + bf2f(g0[0] & 0xffffu);
      float fp = rec_lds[1][w][lane] + bf2f_hi(g0[0]);
      float zp = rec_lds[2][w][lane] + bf2f(g0[1] & 0xffffu);
      float op = rec_lds[3][w][lane] + bf2f_hi(g0[1]);
      float sp  = __logf(1.f + __expf(-fabsf(fp)));
      float lg  = m + fminf(fp, 0.f) - sp;
      float mn  = fmaxf(ip, lg);
      float iv  = __expf(ip - mn);
      float fv  = __expf(lg - mn);
      float zz  = fminf(fabsf(zp), 15.f);
      float t2  = __expf(zz + zz);
      float tha = (t2 - 1.f)/(t2 + 1.f);
      float th  = (zp >= 0.f) ? tha : -tha;
      c   = fv*c + iv*th;
      nst = fv*nst + iv;
      m   = mn;
      float hv = c * __builtin_amdgcn_rcpf(nst*(1.f + __expf(-op)));
      h_lds[w*72 + lane] = f2bf(hv);
      size_t t = (size_t)(seq0 + w)*NS + s;
      y[t*DDIM + hd*64 + lane] = f2bf(hv);
    }
    asm volatile("s_waitcnt lgkmcnt(0)" ::: "memory");
    __builtin_amdgcn_s_barrier();
    g0[0] = g1[0]; g0[1] = g1[1];
    g1[0] = gn[0]; g1[1] = gn[1];
  }
}

// ---------------- proj reduce over K-split slices ----------------------------------
__global__ __launch_bounds__(256) void proj_out(
    const float* __restrict__ ptmp, const float* __restrict__ bproj,
    float* __restrict__ out, int Nc, int n0glob){
  int gid = blockIdx.x*256 + threadIdx.x;
  if (gid >= Nc*PREDN) return;
  float acc = 0.f;
  #pragma unroll
  for (int kc = 0; kc < KC_PROJ; ++kc) acc += ptmp[(size_t)kc*Nc*PREDN + gid];
  int nl = gid / PREDN, j = gid - nl*PREDN;
  int n = n0glob + nl;
  out[((size_t)(n >> 5)*PREDN + j)*CCH + (n & 31)] = acc + bproj[j];
}

extern "C" void kernel_launch(void* const* d_in, const int* in_sizes, int n_in,
                              void* d_out, int out_size, void* d_ws, size_t ws_size,
                              hipStream_t stream) {
  const float* x      = (const float*)d_in[0];
  const float* W_emb  = (const float*)d_in[1];
  const float* b_emb  = (const float*)d_in[2];
  const float* ln1_w  = (const float*)d_in[3];
  const float* ln1_b  = (const float*)d_in[4];
  const float* conv_w = (const float*)d_in[5];
  const float* conv_b = (const float*)d_in[6];
  const float* Wg     = (const float*)d_in[7];
  const float* Rg     = (const float*)d_in[8];
  const float* gb     = (const float*)d_in[9];
  const float* gn_w   = (const float*)d_in[10];
  const float* ln2_w  = (const float*)d_in[11];
  const float* ln2_b  = (const float*)d_in[12];
  const float* up_w   = (const float*)d_in[13];
  const float* up_b   = (const float*)d_in[14];
  const float* dn_w   = (const float*)d_in[15];
  const float* dn_b   = (const float*)d_in[16];
  const float* post_w = (const float*)d_in[17];
  const float* post_b = (const float*)d_in[18];
  const float* W_proj = (const float*)d_in[19];
  const float* b_proj = (const float*)d_in[20];
  float* out = (float*)d_out;

  const size_t oWu   = 0;          // [2][768][256] bf16 : 1,572,864
  const size_t oWd   = 1572864;    // [2][256][384] bf16 :   786,432
  const size_t oWg2  = 2359296;    // [2][8][128][64] bf16 :  262,144
  const size_t oRgt  = 2621440;    // [2][16][64][64] bf16 :  524,288
  const size_t oWp   = 3145728;    // [96][16128] bf16 : 3,096,576
  const size_t oChunk = 6242304;
  const size_t per_seq = (size_t)3584*NS;   // 225,792 B
  int Nc = 0;
  const int cands[3] = {1024, 512, 256};
  for (int i = 0; i < 3; ++i)
    if (oChunk + (size_t)cands[i]*per_seq <= ws_size){ Nc = cands[i]; break; }
  if (Nc == 0) return;

  char* wsb = (char*)d_ws;
  u16* Wu   = (u16*)(wsb + oWu);
  u16* Wd   = (u16*)(wsb + oWd);
  u16* Wg2  = (u16*)(wsb + oWg2);
  u16* Rgt  = (u16*)(wsb + oRgt);
  u16* Wtp  = (u16*)(wsb + oWp);

  for (int blk = 0; blk < 2; ++blk){
    cvt_transpose_t<<<dim3(8, 24), 256, 0, stream>>>(
        up_w + (size_t)blk*256*768, Wu + (size_t)blk*768*256, 256, 768);
    cvt_transpose_t<<<dim3(12, 8), 256, 0, stream>>>(
        dn_w + (size_t)blk*384*256, Wd + (size_t)blk*256*384, 384, 256);
  }
  cvt_gateW2<<<16, 256, 0, stream>>>(Wg, Wg2);
  cvt_gate<<<32, 256, 0, stream>>>(Rg, Rgt);
  cvt_transpose_t<<<dim3(504, 3), 256, 0, stream>>>(W_proj, Wtp, 16128, 96);

  for (int n0 = 0; n0 < NSEQ; n0 += Nc){
    const int    nc  = (NSEQ - n0 < Nc) ? (NSEQ - n0) : Nc;
    const size_t Tc  = (size_t)nc * NS;
    char* cb = wsb + oChunk;
    u16*   h_c   = (u16*)cb;                          // Tc*512 B
    u16*   bufA  = (u16*)(cb + Tc*512);               // Tc*512 B
    u16*   bufB  = (u16*)(cb + Tc*1024);              // Tc*512 B
    u16*   gates = (u16*)(cb + Tc*1536);              // Tc*2048 B
    u16*   gp    = gates;                             // reuse (Tc*768 B)
    float* ptmp  = (float*)(cb + Tc*1536 + Tc*1024);  // overlay in gates tail
    const int t_base = n0*NS;
    const int Tci = (int)Tc;

    patch_embed_ln_v<<<Tci/4, 256, 0, stream>>>(
        x, W_emb, b_emb, ln1_w, ln1_b, h_c, bufA, t_base);

    for (int blk = 0; blk < 2; ++blk){
      if (blk == 1)
        layernorm_v<<<Tci/4, 256, 0, stream>>>(h_c, ln1_w + DDIM, ln1_b + DDIM, bufA);
      conv_silu_v<<<Tci/4, 256, 0, stream>>>(bufA, conv_w + blk*4*DDIM, conv_b + blk*DDIM, bufB);
      mfma_gate2<<<dim3(8, Tci/128), 256, 0, stream>>>(
          bufB, bufA, Wg2 + (size_t)blk*8*8192, gb + blk*4*DDIM, gates);
      slstm_scan5<<<dim3(nc/4, NHEAD), 256, 0, stream>>>(
          gates, Rgt + (size_t)blk*16*4096, bufB);
      gn_res_ln_v<<<Tci/4, 256, 0, stream>>>(
          bufB, gn_w + blk*DDIM, ln2_w + blk*DDIM, ln2_b + blk*DDIM, h_c, bufA);
      mfma_up_gelu3<<<dim3(6, Tci/256), 256, 0, stream>>>(
          bufA, Wu + (size_t)blk*768*256, up_b + blk*2*UPDIM, gp);
      mfma_gemm2<256,128,4,1,4,8,1,6><<<dim3(2, Tci/256), 256, 0, stream>>>(
          gp, UPDIM, Wd + (size_t)blk*256*384, UPDIM,
          dn_b + blk*DDIM, (void*)h_c, DDIM, 12, 0, 0);
    }

    layernorm_v<<<Tci/4, 256, 0, stream>>>(h_c, post_w, post_b, bufA);
    mfma_gemm2<64,96,2,2,2,3,2,0><<<dim3(1, nc/64, KC_PROJ), 256, 0, stream>>>(
        bufA, NS*DDIM, Wtp, NS*DDIM,
        b_proj, (void*)ptmp, PREDN, KCHUNK_PROJ/32, KCHUNK_PROJ, nc);
    proj_out<<<(nc*PREDN + 255)/256, 256, 0, stream>>>(ptmp, b_proj, out, nc, n0);
  }
}

// Round 15
// 649.707 us; speedup vs baseline: 4.8550x; 1.0875x over previous
//
#include <hip/hip_runtime.h>
#include <stdint.h>

typedef unsigned short u16;
typedef unsigned int   u32;
typedef __attribute__((ext_vector_type(8))) short bf16x8;
typedef __attribute__((ext_vector_type(4))) float f32x4;

#define NS      63
#define NSEQ    1024
#define DDIM    256
#define NHEAD   4
#define DHEAD   64
#define UPDIM   384
#define PREDN   96
#define LLEN    512
#define CCH     32
#define PSIZE   16
#define PSTRIDE 8
#define KC_PROJ 8
#define KCHUNK_PROJ 2016

__device__ __forceinline__ float bf2f(u32 lo16){
  union { u32 i; float f; } v; v.i = lo16 << 16; return v.f;
}
__device__ __forceinline__ float bf2f_hi(u32 u){
  union { u32 i; float f; } v; v.i = u & 0xffff0000u; return v.f;
}
__device__ __forceinline__ u16 f2bf(float f){
  union { u32 i; float f; } v; v.f = f;
  u32 u = v.i; u += 0x7fffu + ((u >> 16) & 1u);
  return (u16)(u >> 16);
}

__device__ __forceinline__ void gload16(const u16* g, u16* lds){
  __builtin_amdgcn_global_load_lds(
      (const __attribute__((address_space(1))) u32*)g,
      (__attribute__((address_space(3))) u32*)lds, 16, 0, 0);
}

template<int N> __device__ __forceinline__ void waitcnt_vm(){
  if constexpr (N == 0) asm volatile("s_waitcnt vmcnt(0)" ::: "memory");
  else if constexpr (N == 4) asm volatile("s_waitcnt vmcnt(4)" ::: "memory");
  else if constexpr (N == 6) asm volatile("s_waitcnt vmcnt(6)" ::: "memory");
}

// bijective XCD swizzle (m204): XCD c = flat&7 gets a contiguous logical range.
__device__ __forceinline__ void swz_tile(int &nt, int &mt){
  int gx = gridDim.x, gy = gridDim.y;
  int nwg = gx*gy;
  int flat = blockIdx.y*gx + blockIdx.x;
  int c = flat & 7, s = flat >> 3;
  int q = nwg >> 3, r = nwg & 7;
  int base = c*q + (c < r ? c : r);
  int t = base + s;
  nt = t % gx; mt = t / gx;
}

// ---------------- LDS-tiled transpose: dst[c][r] = bf16(src[r][c]) -----------------
__global__ __launch_bounds__(256) void cvt_transpose_t(
    const float* __restrict__ src, u16* __restrict__ dst, int R, int C){
  __shared__ u16 tile[32][33];
  int rb = blockIdx.x*32, cb = blockIdx.y*32;
  int tx = threadIdx.x & 31, ty = threadIdx.x >> 5;
  #pragma unroll
  for (int i = ty; i < 32; i += 8){
    int r = rb + i, c = cb + tx;
    tile[i][tx] = (r < R && c < C) ? f2bf(src[(size_t)r*C + c]) : (u16)0;
  }
  __syncthreads();
  #pragma unroll
  for (int i = ty; i < 32; i += 8){
    int c = cb + i, r = rb + tx;
    if (c < C && r < R) dst[(size_t)c*R + r] = tile[tx][i];
  }
}

__global__ __launch_bounds__(256) void cvt_gate(
    const float* __restrict__ src, u16* __restrict__ dst){
  int mat = blockIdx.x, t = threadIdx.x;
  const float* s = src + (size_t)mat*4096;
  u16* d = dst + (size_t)mat*4096;
  for (int i = t; i < 4096; i += 256){
    int r = i >> 6, c = i & 63;
    d[c*64 + r] = f2bf(s[i]);
  }
}

// gate weight true-K layout, col order n = e*2+gl: dst[(blk*2+p)*4+hd][n][k]
__global__ __launch_bounds__(256) void cvt_gateW2(
    const float* __restrict__ Wg, u16* __restrict__ dst){
  int mi = blockIdx.x;
  int blk = mi >> 3, p = (mi >> 2) & 1, hd = mi & 3;
  u16* d = dst + (size_t)mi*8192;
  for (int i = threadIdx.x; i < 8192; i += 256){
    int n = i >> 6, k = i & 63;
    int e = n >> 1, gl = n & 1;
    int g = 2*p + gl;
    d[i] = f2bf(Wg[((((size_t)blk*4 + g)*4 + hd)*64 + k)*64 + e]);
  }
}

// ---------------- patch embedding + ln1(blk0), wave = token, vectorized ------------
__global__ __launch_bounds__(256) void patch_embed_ln_v(
    const float* __restrict__ x, const float* __restrict__ Wemb,
    const float* __restrict__ bemb, const float* __restrict__ w1,
    const float* __restrict__ b1, u16* __restrict__ h,
    u16* __restrict__ outA, int t_base){
  int wv = blockIdx.x*4 + (threadIdx.x >> 6);
  int lane = threadIdx.x & 63;
  int tg = t_base + wv;
  int n = tg / NS, s = tg - n*NS;
  int b = n >> 5, c = n & 31;
  int l0 = s * PSTRIDE;
  float4 acc = *(const float4*)(bemb + lane*4);
  #pragma unroll
  for (int p = 0; p < PSIZE; ++p){
    float xv = x[((size_t)b*LLEN + l0 + p)*CCH + c];
    float4 we = *(const float4*)(Wemb + p*DDIM + lane*4);
    acc.x += xv*we.x; acc.y += xv*we.y; acc.z += xv*we.z; acc.w += xv*we.w;
  }
  ushort4 hu; hu.x=f2bf(acc.x); hu.y=f2bf(acc.y); hu.z=f2bf(acc.z); hu.w=f2bf(acc.w);
  *(ushort4*)(h + (size_t)wv*DDIM + lane*4) = hu;
  float s1 = acc.x+acc.y+acc.z+acc.w;
  float s2 = acc.x*acc.x+acc.y*acc.y+acc.z*acc.z+acc.w*acc.w;
  #pragma unroll
  for (int o = 1; o < 64; o <<= 1){ s1 += __shfl_xor(s1,o,64); s2 += __shfl_xor(s2,o,64); }
  float mu = s1*(1.f/DDIM);
  float var = s2*(1.f/DDIM) - mu*mu;
  float rstd = rsqrtf(var + 1e-5f);
  float4 wf = *(const float4*)(w1 + lane*4);
  float4 bf = *(const float4*)(b1 + lane*4);
  ushort4 o4;
  o4.x = f2bf((acc.x-mu)*rstd*wf.x + bf.x);
  o4.y = f2bf((acc.y-mu)*rstd*wf.y + bf.y);
  o4.z = f2bf((acc.z-mu)*rstd*wf.z + bf.z);
  o4.w = f2bf((acc.w-mu)*rstd*wf.w + bf.w);
  *(ushort4*)(outA + (size_t)wv*DDIM + lane*4) = o4;
}

// ---------------- layernorm, wave = token, vectorized ------------------------------
__global__ __launch_bounds__(256) void layernorm_v(
    const u16* __restrict__ in, const float* __restrict__ w,
    const float* __restrict__ b, u16* __restrict__ out){
  int wv = blockIdx.x*4 + (threadIdx.x >> 6);
  int lane = threadIdx.x & 63;
  ushort4 u = *(const ushort4*)(in + (size_t)wv*DDIM + lane*4);
  float v0=bf2f(u.x), v1=bf2f(u.y), v2=bf2f(u.z), v3=bf2f(u.w);
  float s1 = v0+v1+v2+v3, s2 = v0*v0+v1*v1+v2*v2+v3*v3;
  #pragma unroll
  for (int o = 1; o < 64; o <<= 1){ s1 += __shfl_xor(s1,o,64); s2 += __shfl_xor(s2,o,64); }
  float mu = s1*(1.f/DDIM);
  float var = s2*(1.f/DDIM) - mu*mu;
  float rstd = rsqrtf(var + 1e-5f);
  float4 wf = *(const float4*)(w + lane*4);
  float4 bf = *(const float4*)(b + lane*4);
  ushort4 o4;
  o4.x = f2bf((v0-mu)*rstd*wf.x + bf.x);
  o4.y = f2bf((v1-mu)*rstd*wf.y + bf.y);
  o4.z = f2bf((v2-mu)*rstd*wf.z + bf.z);
  o4.w = f2bf((v3-mu)*rstd*wf.w + bf.w);
  *(ushort4*)(out + (size_t)wv*DDIM + lane*4) = o4;
}

// ---------------- fused groupnorm + residual + layernorm, vectorized ---------------
__global__ __launch_bounds__(256) void gn_res_ln_v(
    const u16* __restrict__ y, const float* __restrict__ gnw,
    const float* __restrict__ w2, const float* __restrict__ b2,
    u16* __restrict__ h, u16* __restrict__ outA){
  int wv = blockIdx.x*4 + (threadIdx.x >> 6);
  int lane = threadIdx.x & 63;
  ushort4 u = *(const ushort4*)(y + (size_t)wv*DDIM + lane*4);
  float v0=bf2f(u.x), v1=bf2f(u.y), v2=bf2f(u.z), v3=bf2f(u.w);
  float s1 = v0+v1+v2+v3, s2 = v0*v0+v1*v1+v2*v2+v3*v3;
  #pragma unroll
  for (int o = 1; o < 16; o <<= 1){ s1 += __shfl_xor(s1,o,64); s2 += __shfl_xor(s2,o,64); }
  float mu64 = s1*(1.f/64.f);
  float var64 = s2*(1.f/64.f) - mu64*mu64;
  float rstd64 = rsqrtf(var64 + 1e-5f);
  float4 gw = *(const float4*)(gnw + lane*4);
  ushort4 hu = *(const ushort4*)(h + (size_t)wv*DDIM + lane*4);
  float h0 = bf2f(hu.x) + (v0-mu64)*rstd64*gw.x;
  float h1 = bf2f(hu.y) + (v1-mu64)*rstd64*gw.y;
  float h2 = bf2f(hu.z) + (v2-mu64)*rstd64*gw.z;
  float h3 = bf2f(hu.w) + (v3-mu64)*rstd64*gw.w;
  ushort4 hn; hn.x=f2bf(h0); hn.y=f2bf(h1); hn.z=f2bf(h2); hn.w=f2bf(h3);
  *(ushort4*)(h + (size_t)wv*DDIM + lane*4) = hn;
  float t1 = h0+h1+h2+h3, t2 = h0*h0+h1*h1+h2*h2+h3*h3;
  #pragma unroll
  for (int o = 1; o < 64; o <<= 1){ t1 += __shfl_xor(t1,o,64); t2 += __shfl_xor(t2,o,64); }
  float mu = t1*(1.f/DDIM);
  float var = t2*(1.f/DDIM) - mu*mu;
  float rstd = rsqrtf(var + 1e-5f);
  float4 wf = *(const float4*)(w2 + lane*4);
  float4 bf = *(const float4*)(b2 + lane*4);
  ushort4 o4;
  o4.x = f2bf((h0-mu)*rstd*wf.x + bf.x);
  o4.y = f2bf((h1-mu)*rstd*wf.y + bf.y);
  o4.z = f2bf((h2-mu)*rstd*wf.z + bf.z);
  o4.w = f2bf((h3-mu)*rstd*wf.w + bf.w);
  *(ushort4*)(outA + (size_t)wv*DDIM + lane*4) = o4;
}

// ---------------- causal depthwise conv K=4 + SiLU, vectorized ---------------------
__global__ __launch_bounds__(256) void conv_silu_v(
    const u16* __restrict__ xln, const float* __restrict__ cw,
    const float* __restrict__ cb, u16* __restrict__ xc){
  int wv = blockIdx.x*4 + (threadIdx.x >> 6);
  int lane = threadIdx.x & 63;
  int s = wv % NS;
  float4 acc = *(const float4*)(cb + lane*4);
  #pragma unroll
  for (int k = 0; k < 4; ++k){
    int ss = s + k - 3;
    if (ss >= 0){
      ushort4 xu = *(const ushort4*)(xln + (size_t)(wv + k - 3)*DDIM + lane*4);
      float4 cv = *(const float4*)(cw + k*DDIM + lane*4);
      acc.x += bf2f(xu.x)*cv.x; acc.y += bf2f(xu.y)*cv.y;
      acc.z += bf2f(xu.z)*cv.z; acc.w += bf2f(xu.w)*cv.w;
    }
  }
  ushort4 o4;
  o4.x = f2bf(acc.x/(1.f + __expf(-acc.x)));
  o4.y = f2bf(acc.y/(1.f + __expf(-acc.y)));
  o4.z = f2bf(acc.z/(1.f + __expf(-acc.z)));
  o4.w = f2bf(acc.w/(1.f + __expf(-acc.w)));
  *(ushort4*)(xc + (size_t)wv*DDIM + lane*4) = o4;
}

// ---------------- generic MFMA GEMM (XCD-swizzled) ---------------------------------
template<int BM,int BN,int WR,int WC,int MR,int NR,int MODE,int VM>
__global__ __launch_bounds__(256) void mfma_gemm2(
    const u16* __restrict__ A, int lda,
    const u16* __restrict__ Wt, int ldwt,
    const float* __restrict__ bias, void* __restrict__ outp, int ldo,
    int ksteps, int kchunk, int Mtot)
{
  constexpr int nA = BM/16, nW = BN/16;
  __shared__ u16 As[2][BM*32];
  __shared__ u16 Ws[2][BN*32];
  const int tid = threadIdx.x;
  const int lane = tid & 63, wid = tid >> 6;
  const int wr = wid / WC, wc = wid % WC;
  const int fr = lane & 15, kb = lane >> 4;
  int nt, mt; swz_tile(nt, mt);
  const int m0 = mt*BM, n0 = nt*BN;
  const int kc = blockIdx.z;
  const int kbeg = kc*kchunk;
  const u16* Ab = A + (size_t)m0*lda + kbeg;
  const u16* Wb = Wt + (size_t)n0*ldwt + kbeg;
  const int lrow = lane >> 2, lcol = (lane & 3)*8;

  auto stage = [&](int buf, int ks){
    int k0 = ks*32;
    for (int c = wid; c < nA; c += 4)
      gload16(Ab + (size_t)(c*16 + lrow)*lda + k0 + lcol, &As[buf][c*512]);
    for (int c = wid; c < nW; c += 4)
      gload16(Wb + (size_t)(c*16 + lrow)*ldwt + k0 + lcol, &Ws[buf][c*512]);
  };

  f32x4 acc[MR][NR];
  #pragma unroll
  for (int m=0;m<MR;++m)
    #pragma unroll
    for (int n=0;n<NR;++n) acc[m][n] = (f32x4){0.f,0.f,0.f,0.f};

  stage(0, 0);
  if (VM == 0) __syncthreads();
  int cur = 0;
  for (int ks = 0; ks < ksteps; ++ks){
    if (VM == 0){
      if (ks + 1 < ksteps) stage(cur^1, ks+1);
    } else {
      if (ks + 1 < ksteps){ stage(cur^1, ks+1); waitcnt_vm<VM>(); }
      else waitcnt_vm<0>();
      __builtin_amdgcn_s_barrier();
      asm volatile("" ::: "memory");
    }
    bf16x8 af[MR], wf[NR];
    #pragma unroll
    for (int m=0;m<MR;++m)
      af[m] = *(const bf16x8*)&As[cur][(wr*MR*16 + m*16 + fr)*32 + kb*8];
    #pragma unroll
    for (int n=0;n<NR;++n)
      wf[n] = *(const bf16x8*)&Ws[cur][(wc*NR*16 + n*16 + fr)*32 + kb*8];
    #pragma unroll
    for (int m=0;m<MR;++m)
      #pragma unroll
      for (int n=0;n<NR;++n)
        acc[m][n] = __builtin_amdgcn_mfma_f32_16x16x32_bf16(af[m], wf[n], acc[m][n], 0,0,0);
    if (VM == 0){
      __syncthreads();
    } else {
      asm volatile("" ::: "memory");
      __builtin_amdgcn_s_barrier();
    }
    cur ^= 1;
  }
  #pragma unroll
  for (int m=0;m<MR;++m){
    int rowb = m0 + wr*MR*16 + m*16 + kb*4;
    #pragma unroll
    for (int n=0;n<NR;++n){
      int col = n0 + wc*NR*16 + n*16 + fr;
      #pragma unroll
      for (int r=0;r<4;++r){
        int row = rowb + r;
        float v = acc[m][n][r];
        if (MODE == 1){
          u16* dst = (u16*)outp + (size_t)row*ldo + col;
          *dst = f2bf(bf2f(*dst) + v + bias[col]);
        } else {
          ((float*)outp)[((size_t)kc*Mtot + row)*ldo + col] = v;
        }
      }
    }
  }
}

// ---------------- gate GEMM, true K=64 ---------------------------------------------
__global__ __launch_bounds__(256) void mfma_gate2(
    const u16* __restrict__ xc, const u16* __restrict__ xh,
    const u16* __restrict__ Wg2, const float* __restrict__ gb,
    u16* __restrict__ gates)
{
  __shared__ u16 As[2][128*32];
  __shared__ u16 Ws[2][128*32];
  const int tid = threadIdx.x;
  const int lane = tid & 63, wid = tid >> 6;
  const int wr = wid >> 1, wc = wid & 1;
  const int fr = lane & 15, kb = lane >> 4;
  int nt, mt; swz_tile(nt, mt);
  const int p = nt >> 2, hd = nt & 3;
  const int m0 = mt*128;
  const u16* Ain = (p == 0) ? xc : xh;
  const u16* Wb = Wg2 + (size_t)nt*8192;
  const int lrow = lane >> 2, lcol = (lane & 3)*8;

  auto stage = [&](int buf, int ks){
    int k0 = ks*32;
    for (int c = wid; c < 8; c += 4)
      gload16(Ain + (size_t)(m0 + c*16 + lrow)*DDIM + hd*64 + k0 + lcol, &As[buf][c*512]);
    for (int c = wid; c < 8; c += 4)
      gload16(Wb + (size_t)(c*16 + lrow)*64 + k0 + lcol, &Ws[buf][c*512]);
  };

  f32x4 acc[4][4];
  #pragma unroll
  for (int m=0;m<4;++m)
    #pragma unroll
    for (int n=0;n<4;++n) acc[m][n] = (f32x4){0.f,0.f,0.f,0.f};

  stage(0, 0);
  int cur = 0;
  #pragma unroll
  for (int ks = 0; ks < 2; ++ks){
    if (ks == 0){ stage(1, 1); waitcnt_vm<4>(); }
    else waitcnt_vm<0>();
    __builtin_amdgcn_s_barrier();
    asm volatile("" ::: "memory");
    bf16x8 af[4], wf[4];
    #pragma unroll
    for (int m=0;m<4;++m)
      af[m] = *(const bf16x8*)&As[cur][(wr*64 + m*16 + fr)*32 + kb*8];
    #pragma unroll
    for (int n=0;n<4;++n)
      wf[n] = *(const bf16x8*)&Ws[cur][(wc*64 + n*16 + fr)*32 + kb*8];
    #pragma unroll
    for (int m=0;m<4;++m)
      #pragma unroll
      for (int n=0;n<4;++n)
        acc[m][n] = __builtin_amdgcn_mfma_f32_16x16x32_bf16(af[m], wf[n], acc[m][n], 0,0,0);
    asm volatile("" ::: "memory");
    __builtin_amdgcn_s_barrier();
    cur ^= 1;
  }
  #pragma unroll
  for (int m=0;m<4;++m){
    int rowb = m0 + wr*64 + m*16 + kb*4;
    #pragma unroll
    for (int n=0;n<4;++n){
      int cl = wc*64 + n*16 + fr;
      int e = cl >> 1, gl = cl & 1;
      float bv = gb[(2*p + gl)*256 + hd*64 + e];
      int phys = hd*256 + p*128 + cl;
      #pragma unroll
      for (int r=0;r<4;++r)
        gates[(size_t)(rowb + r)*1024 + phys] = f2bf(acc[m][n][r] + bv);
    }
  }
}

// ---------------- FFN up + fast gelu*g2, BM=128 (more TLP) -------------------------
__global__ __launch_bounds__(256) void mfma_up_gelu4(
    const u16* __restrict__ A, const u16* __restrict__ Wt,
    const float* __restrict__ ub, u16* __restrict__ gp)
{
  __shared__ u16 As[2][128*32];
  __shared__ u16 Ws[2][128*32];   // rows 0-63: g1 slice; rows 64-127: g2 slice
  const int tid = threadIdx.x;
  const int lane = tid & 63, wid = tid >> 6;
  const int fr = lane & 15, kb = lane >> 4;
  int nt, mt; swz_tile(nt, mt);
  const int m0 = mt*128, n0 = nt*64;
  const u16* W1 = Wt + (size_t)n0*256;
  const u16* W2 = Wt + (size_t)(384 + n0)*256;
  const int lrow = lane >> 2, lcol = (lane & 3)*8;

  auto stage = [&](int buf, int ks){
    int k0 = ks*32;
    for (int c = wid; c < 8; c += 4)
      gload16(A + (size_t)(m0 + c*16 + lrow)*256 + k0 + lcol, &As[buf][c*512]);
    for (int c = wid; c < 8; c += 4){
      const u16* src = (c < 4) ? (W1 + (size_t)(c*16 + lrow)*256)
                               : (W2 + (size_t)((c-4)*16 + lrow)*256);
      gload16(src + k0 + lcol, &Ws[buf][c*512]);
    }
  };

  f32x4 a1[2][4], a2[2][4];
  #pragma unroll
  for (int m=0;m<2;++m)
    #pragma unroll
    for (int n=0;n<4;++n){ a1[m][n]=(f32x4){0,0,0,0}; a2[m][n]=(f32x4){0,0,0,0}; }

  stage(0, 0);
  int cur = 0;
  #pragma unroll
  for (int ks = 0; ks < 8; ++ks){
    if (ks + 1 < 8){ stage(cur^1, ks+1); waitcnt_vm<4>(); }
    else waitcnt_vm<0>();
    __builtin_amdgcn_s_barrier();
    asm volatile("" ::: "memory");
    bf16x8 af[2], wf1[4], wf2[4];
    #pragma unroll
    for (int m=0;m<2;++m)
      af[m] = *(const bf16x8*)&As[cur][(wid*32 + m*16 + fr)*32 + kb*8];
    #pragma unroll
    for (int n=0;n<4;++n){
      wf1[n] = *(const bf16x8*)&Ws[cur][(n*16 + fr)*32 + kb*8];
      wf2[n] = *(const bf16x8*)&Ws[cur][(64 + n*16 + fr)*32 + kb*8];
    }
    #pragma unroll
    for (int m=0;m<2;++m)
      #pragma unroll
      for (int n=0;n<4;++n){
        a1[m][n] = __builtin_amdgcn_mfma_f32_16x16x32_bf16(af[m], wf1[n], a1[m][n], 0,0,0);
        a2[m][n] = __builtin_amdgcn_mfma_f32_16x16x32_bf16(af[m], wf2[n], a2[m][n], 0,0,0);
      }
    asm volatile("" ::: "memory");
    __builtin_amdgcn_s_barrier();
    cur ^= 1;
  }
  #pragma unroll
  for (int m=0;m<2;++m){
    int rowb = m0 + wid*32 + m*16 + kb*4;
    #pragma unroll
    for (int n=0;n<4;++n){
      int col = n0 + n*16 + fr;
      float b1 = ub[col], b2 = ub[384 + col];
      #pragma unroll
      for (int r=0;r<4;++r){
        float g1 = a1[m][n][r] + b1;
        float g2 = a2[m][n][r] + b2;
        float u  = 0.7978845608028654f*(g1 + 0.044715f*g1*g1*g1);
        float uc = fminf(fmaxf(u, -20.f), 20.f);
        float t2 = __expf(uc + uc);
        float th = (t2 - 1.f)/(t2 + 1.f);
        float ge = 0.5f*g1*(1.f + th);
        gp[(size_t)(rowb + r)*UPDIM + col] = f2bf(ge*g2);
      }
    }
  }
}

// ---------------- sLSTM scan v5: 4 seqs/block, 4 blocks/CU -------------------------
__global__ __launch_bounds__(256) void slstm_scan5(
    const u16* __restrict__ gates, const u16* __restrict__ Rgt,
    u16* __restrict__ y)
{
  __shared__ u16 h_lds[16*72];
  __shared__ float rec_lds[4][4][68];
  const int tid = threadIdx.x;
  const int w = tid >> 6, lane = tid & 63;
  const int hd = blockIdx.y, grp = blockIdx.x;
  const int fr = lane & 15, kb = lane >> 4;
  const int seq0 = grp*4;
  const u32* g32 = (const u32*)gates;

  bf16x8 bfr[4][2];
  {
    const u16* rb = Rgt + (size_t)(w*NHEAD + hd)*4096;
    #pragma unroll
    for (int n=0;n<4;++n)
      #pragma unroll
      for (int ks=0;ks<2;++ks)
        bfr[n][ks] = *(const bf16x8*)(rb + (size_t)(n*16 + fr)*64 + ks*32 + kb*8);
  }
  for (int i = tid; i < 16*72/2; i += 256) ((u32*)h_lds)[i] = 0u;
  float c = 0.f, nst = 0.f, m = 0.f;

  const size_t gb = ((size_t)(seq0 + w)*NS)*512 + hd*128 + lane;
  u32 g0[2], g1[2];
  g0[0] = g32[gb];        g0[1] = g32[gb + 64];
  g1[0] = g32[gb + 512];  g1[1] = g32[gb + 576];
  __syncthreads();

  for (int s = 0; s < NS; ++s){
    u32 gn[2] = {0u, 0u};
    if (s + 2 < NS){
      size_t b2 = gb + (size_t)(s+2)*512;
      gn[0] = g32[b2];
      gn[1] = g32[b2 + 64];
    }
    bf16x8 af0 = *(const bf16x8*)&h_lds[fr*72 + kb*8];
    bf16x8 af1 = *(const bf16x8*)&h_lds[fr*72 + 32 + kb*8];
    f32x4 acc[4];
    #pragma unroll
    for (int n=0;n<4;++n){
      acc[n] = (f32x4){0,0,0,0};
      acc[n] = __builtin_amdgcn_mfma_f32_16x16x32_bf16(af0, bfr[n][0], acc[n], 0,0,0);
      acc[n] = __builtin_amdgcn_mfma_f32_16x16x32_bf16(af1, bfr[n][1], acc[n], 0,0,0);
    }
    if (kb == 0){
      #pragma unroll
      for (int n=0;n<4;++n)
        #pragma unroll
        for (int r=0;r<4;++r)
          rec_lds[w][r][n*16 + fr] = acc[n][r];
    }
    asm volatile("s_waitcnt lgkmcnt(0)" ::: "memory");
    __builtin_amdgcn_s_barrier();
    {
      float ip = rec_lds[0][w][lane] + bf2f(g0[0] & 0xffffu);
      float fp = rec_lds[1][w][lane] + bf2f_hi(g0[0]);
      float zp = rec_lds[2][w][lane] + bf2f(g0[1] & 0xffffu);
      float op = rec_lds[3][w][lane] + bf2f_hi(g0[1]);
      float sp  = __logf(1.f + __expf(-fabsf(fp)));
      float lg  = m + fminf(fp, 0.f) - sp;
      float mn  = fmaxf(ip, lg);
      float iv  = __expf(ip - mn);
      float fv  = __expf(lg - mn);
      float zz  = fminf(fabsf(zp), 15.f);
      float t2  = __expf(zz + zz);
      float tha = (t2 - 1.f)/(t2 + 1.f);
      float th  = (zp >= 0.f) ? tha : -tha;
      c   = fv*c + iv*th;
      nst = fv*nst + iv;
      m   = mn;
      float hv = c * __builtin_amdgcn_rcpf(nst*(1.f + __expf(-op)));
      h_lds[w*72 + lane] = f2bf(hv);
      size_t t = (size_t)(seq0 + w)*NS + s;
      y[t*DDIM + hd*64 + lane] = f2bf(hv);
    }
    asm volatile("s_waitcnt lgkmcnt(0)" ::: "memory");
    __builtin_amdgcn_s_barrier();
    g0[0] = g1[0]; g0[1] = g1[1];
    g1[0] = gn[0]; g1[1] = gn[1];
  }
}

// ---------------- proj reduce over K-split slices ----------------------------------
__global__ __launch_bounds__(256) void proj_out(
    const float* __restrict__ ptmp, const float* __restrict__ bproj,
    float* __restrict__ out, int Nc, int n0glob){
  int gid = blockIdx.x*256 + threadIdx.x;
  if (gid >= Nc*PREDN) return;
  float acc = 0.f;
  #pragma unroll
  for (int kc = 0; kc < KC_PROJ; ++kc) acc += ptmp[(size_t)kc*Nc*PREDN + gid];
  int nl = gid / PREDN, j = gid - nl*PREDN;
  int n = n0glob + nl;
  out[((size_t)(n >> 5)*PREDN + j)*CCH + (n & 31)] = acc + bproj[j];
}

extern "C" void kernel_launch(void* const* d_in, const int* in_sizes, int n_in,
                              void* d_out, int out_size, void* d_ws, size_t ws_size,
                              hipStream_t stream) {
  const float* x      = (const float*)d_in[0];
  const float* W_emb  = (const float*)d_in[1];
  const float* b_emb  = (const float*)d_in[2];
  const float* ln1_w  = (const float*)d_in[3];
  const float* ln1_b  = (const float*)d_in[4];
  const float* conv_w = (const float*)d_in[5];
  const float* conv_b = (const float*)d_in[6];
  const float* Wg     = (const float*)d_in[7];
  const float* Rg     = (const float*)d_in[8];
  const float* gb     = (const float*)d_in[9];
  const float* gn_w   = (const float*)d_in[10];
  const float* ln2_w  = (const float*)d_in[11];
  const float* ln2_b  = (const float*)d_in[12];
  const float* up_w   = (const float*)d_in[13];
  const float* up_b   = (const float*)d_in[14];
  const float* dn_w   = (const float*)d_in[15];
  const float* dn_b   = (const float*)d_in[16];
  const float* post_w = (const float*)d_in[17];
  const float* post_b = (const float*)d_in[18];
  const float* W_proj = (const float*)d_in[19];
  const float* b_proj = (const float*)d_in[20];
  float* out = (float*)d_out;

  const size_t oWu   = 0;          // [2][768][256] bf16 : 1,572,864
  const size_t oWd   = 1572864;    // [2][256][384] bf16 :   786,432
  const size_t oWg2  = 2359296;    // [2][8][128][64] bf16 :  262,144
  const size_t oRgt  = 2621440;    // [2][16][64][64] bf16 :  524,288
  const size_t oWp   = 3145728;    // [96][16128] bf16 : 3,096,576
  const size_t oChunk = 6242304;
  const size_t per_seq = (size_t)3584*NS;   // 225,792 B
  int Nc = 0;
  const int cands[3] = {1024, 512, 256};
  for (int i = 0; i < 3; ++i)
    if (oChunk + (size_t)cands[i]*per_seq <= ws_size){ Nc = cands[i]; break; }
  if (Nc == 0) return;

  char* wsb = (char*)d_ws;
  u16* Wu   = (u16*)(wsb + oWu);
  u16* Wd   = (u16*)(wsb + oWd);
  u16* Wg2  = (u16*)(wsb + oWg2);
  u16* Rgt  = (u16*)(wsb + oRgt);
  u16* Wtp  = (u16*)(wsb + oWp);

  for (int blk = 0; blk < 2; ++blk){
    cvt_transpose_t<<<dim3(8, 24), 256, 0, stream>>>(
        up_w + (size_t)blk*256*768, Wu + (size_t)blk*768*256, 256, 768);
    cvt_transpose_t<<<dim3(12, 8), 256, 0, stream>>>(
        dn_w + (size_t)blk*384*256, Wd + (size_t)blk*256*384, 384, 256);
  }
  cvt_gateW2<<<16, 256, 0, stream>>>(Wg, Wg2);
  cvt_gate<<<32, 256, 0, stream>>>(Rg, Rgt);
  cvt_transpose_t<<<dim3(504, 3), 256, 0, stream>>>(W_proj, Wtp, 16128, 96);

  for (int n0 = 0; n0 < NSEQ; n0 += Nc){
    const int    nc  = (NSEQ - n0 < Nc) ? (NSEQ - n0) : Nc;
    const size_t Tc  = (size_t)nc * NS;
    char* cb = wsb + oChunk;
    u16*   h_c   = (u16*)cb;                          // Tc*512 B
    u16*   bufA  = (u16*)(cb + Tc*512);               // Tc*512 B
    u16*   bufB  = (u16*)(cb + Tc*1024);              // Tc*512 B
    u16*   gates = (u16*)(cb + Tc*1536);              // Tc*2048 B
    u16*   gp    = gates;                             // reuse (Tc*768 B)
    float* ptmp  = (float*)(cb + Tc*1536 + Tc*1024);  // overlay in gates tail
    const int t_base = n0*NS;
    const int Tci = (int)Tc;

    patch_embed_ln_v<<<Tci/4, 256, 0, stream>>>(
        x, W_emb, b_emb, ln1_w, ln1_b, h_c, bufA, t_base);

    for (int blk = 0; blk < 2; ++blk){
      if (blk == 1)
        layernorm_v<<<Tci/4, 256, 0, stream>>>(h_c, ln1_w + DDIM, ln1_b + DDIM, bufA);
      conv_silu_v<<<Tci/4, 256, 0, stream>>>(bufA, conv_w + blk*4*DDIM, conv_b + blk*DDIM, bufB);
      mfma_gate2<<<dim3(8, Tci/128), 256, 0, stream>>>(
          bufB, bufA, Wg2 + (size_t)blk*8*8192, gb + blk*4*DDIM, gates);
      slstm_scan5<<<dim3(nc/4, NHEAD), 256, 0, stream>>>(
          gates, Rgt + (size_t)blk*16*4096, bufB);
      gn_res_ln_v<<<Tci/4, 256, 0, stream>>>(
          bufB, gn_w + blk*DDIM, ln2_w + blk*DDIM, ln2_b + blk*DDIM, h_c, bufA);
      mfma_up_gelu4<<<dim3(6, Tci/128), 256, 0, stream>>>(
          bufA, Wu + (size_t)blk*768*256, up_b + blk*2*UPDIM, gp);
      mfma_gemm2<128,128,2,2,4,4,1,4><<<dim3(2, Tci/128), 256, 0, stream>>>(
          gp, UPDIM, Wd + (size_t)blk*256*384, UPDIM,
          dn_b + blk*DDIM, (void*)h_c, DDIM, 12, 0, 0);
    }

    layernorm_v<<<Tci/4, 256, 0, stream>>>(h_c, post_w, post_b, bufA);
    mfma_gemm2<64,96,2,2,2,3,2,0><<<dim3(1, nc/64, KC_PROJ), 256, 0, stream>>>(
        bufA, NS*DDIM, Wtp, NS*DDIM,
        b_proj, (void*)ptmp, PREDN, KCHUNK_PROJ/32, KCHUNK_PROJ, nc);
    proj_out<<<(nc*PREDN + 255)/256, 256, 0, stream>>>(ptmp, b_proj, out, nc, n0);
  }
}